// Round 1
// baseline (2001.787 us; speedup 1.0000x reference)
//
#include <hip/hip_runtime.h>
#include <cstddef>
#include <cstdint>

#define NH 16
#define HD 64
#define NSEQ 1024
#define NB 4
#define DM 1024
#define SCALE 0.125f   // 64^-0.5

// ---------------- generic tiled f32 GEMM: C[M,N] = A[M,K] @ B[K,N] -------------
__global__ __launch_bounds__(256) void gemm_f32(const float* __restrict__ A,
                                                const float* __restrict__ B,
                                                float* __restrict__ C,
                                                int M, int K, int N) {
    __shared__ float As[16][65];  // [kk][m]
    __shared__ float Bs[16][65];  // [kk][n]
    const int bx = blockIdx.x;    // N tile
    const int by = blockIdx.y;    // M tile
    const int tid = threadIdx.x;
    const int tx = tid & 15;      // col group (4 cols)
    const int ty = tid >> 4;      // row group (4 rows)
    const int row0 = by * 64, col0 = bx * 64;

    float acc[4][4];
#pragma unroll
    for (int i = 0; i < 4; ++i)
#pragma unroll
        for (int j = 0; j < 4; ++j) acc[i][j] = 0.0f;

    for (int k0 = 0; k0 < K; k0 += 16) {
        // A tile: 64 rows x 16 k. thread: r = tid>>2, kk0 = (tid&3)*4
        {
            const int r = tid >> 2;
            const int kk = (tid & 3) * 4;
            float4 v = *(const float4*)(A + (size_t)(row0 + r) * K + k0 + kk);
            As[kk + 0][r] = v.x; As[kk + 1][r] = v.y;
            As[kk + 2][r] = v.z; As[kk + 3][r] = v.w;
        }
        // B tile: 16 k x 64 cols. thread: kk = tid>>4, c = (tid&15)*4
        {
            const int kk = tid >> 4;
            const int c = (tid & 15) * 4;
            float4 v = *(const float4*)(B + (size_t)(k0 + kk) * N + col0 + c);
            Bs[kk][c + 0] = v.x; Bs[kk][c + 1] = v.y;
            Bs[kk][c + 2] = v.z; Bs[kk][c + 3] = v.w;
        }
        __syncthreads();
#pragma unroll
        for (int kk = 0; kk < 16; ++kk) {
            float a[4], b[4];
#pragma unroll
            for (int i = 0; i < 4; ++i) a[i] = As[kk][ty * 4 + i];
#pragma unroll
            for (int j = 0; j < 4; ++j) b[j] = Bs[kk][tx * 4 + j];
#pragma unroll
            for (int i = 0; i < 4; ++i)
#pragma unroll
                for (int j = 0; j < 4; ++j) acc[i][j] += a[i] * b[j];
        }
        __syncthreads();
    }
#pragma unroll
    for (int i = 0; i < 4; ++i) {
        float4 v = make_float4(acc[i][0], acc[i][1], acc[i][2], acc[i][3]);
        *(float4*)(C + (size_t)(row0 + ty * 4 + i) * N + col0 + tx * 4) = v;
    }
}

// -------- gamma: loggam[row,h] = log(sigmoid(X[row]·Wg[:,h])^(1/20) + 1e-8) ----
__global__ __launch_bounds__(256) void gamma_kernel(const float* __restrict__ X,
                                                    const float* __restrict__ Wg,
                                                    float* __restrict__ loggam) {
    const int row = blockIdx.x;          // b*N + n
    const int tid = threadIdx.x;
    const int h = tid & 15;
    const int g = tid >> 4;              // 16 k-chunks
    const float* x = X + (size_t)row * DM;
    float sum = 0.0f;
    for (int kk = g; kk < DM; kk += 16) sum += x[kk] * Wg[(size_t)kk * NH + h];
    __shared__ float red[256];
    red[tid] = sum;
    __syncthreads();
    for (int s = 128; s >= 16; s >>= 1) {
        if (tid < s) red[tid] += red[tid + s];
        __syncthreads();
    }
    if (tid < 16) {
        float d = red[tid];
        float sig = 1.0f / (1.0f + expf(-d));
        float gam = powf(sig, 1.0f / 20.0f);
        loggam[(size_t)row * NH + tid] = logf(gam + 1e-8f);
    }
}

// -------- cumsum over n per (b,h), in place ----------
__global__ void scan_kernel(float* __restrict__ lg) {
    const int idx = threadIdx.x;      // 0..63 = b*16+h
    const int b = idx >> 4, h = idx & 15;
    float acc = 0.0f;
    float* p = lg + (size_t)b * NSEQ * NH + h;
    for (int n = 0; n < NSEQ; ++n) {
        acc += p[(size_t)n * NH];
        p[(size_t)n * NH] = acc;
    }
}

// -------- xPos RoPE in place on q (off 0) and k (off 1024) in qkv buffer ------
__global__ __launch_bounds__(256) void rope_kernel(float* __restrict__ qkv,
                                                   const float* __restrict__ ts) {
    const int gid = blockIdx.x * 256 + threadIdx.x; // pair index
    const int i = gid & 31;                         // freq index
    const int rest = gid >> 5;
    const int h = rest & 15;
    const int bn = rest >> 4;                       // b*N+n
    const float t = ts[bn];
    const float inv_freq = powf(10000.0f, -(float)(2 * i) / 64.0f);
    const float ang = t * inv_freq;
    const float s = sinf(ang), c = cosf(ang);
    const float sv = ((float)(2 * i) + 0.4f * 64.0f) / (1.4f * 64.0f);
    const float scale = powf(sv, t / 512.0f);
    const size_t base = (size_t)bn * 3072 + h * HD + 2 * i;
    float q0 = qkv[base], q1 = qkv[base + 1];
    qkv[base]     = (q0 * c - q1 * s) * scale;
    qkv[base + 1] = (q1 * c + q0 * s) * scale;
    float k0 = qkv[base + 1024], k1 = qkv[base + 1025];
    const float iscale = 1.0f / scale;
    qkv[base + 1024] = (k0 * c - k1 * s) * iscale;
    qkv[base + 1025] = (k1 * c + k0 * s) * iscale;
}

// -------- causal decay attention, 64x64 tiles --------------
__global__ __launch_bounds__(256) void attn_kernel(const float* __restrict__ qkv,
                                                   const float* __restrict__ logb,
                                                   float* __restrict__ O) {
    const int nt = blockIdx.x;        // n tile (16)
    const int bh = blockIdx.y;        // b*16+h (64)
    const int b = bh >> 4, h = bh & 15;
    const int tid = threadIdx.x;
    __shared__ float qs[64][65];
    __shared__ float ks[64][65];      // reused to hold S after phase A
    __shared__ float vs[64][65];
    __shared__ float lbn[64], lbm[64];
    const int n0 = nt * 64;
    const int r = tid >> 2;           // row in tile
    const int q4 = tid & 3;           // quarter

    // load q tile
    {
        const int c0 = q4 * 16;
        const float* src = qkv + ((size_t)(b * NSEQ + n0 + r) * 3072) + h * HD + c0;
#pragma unroll
        for (int j = 0; j < 16; j += 4) {
            float4 v = *(const float4*)(src + j);
            qs[r][c0 + j] = v.x; qs[r][c0 + j + 1] = v.y;
            qs[r][c0 + j + 2] = v.z; qs[r][c0 + j + 3] = v.w;
        }
    }
    if (tid < 64) lbn[tid] = logb[((size_t)(b * NSEQ + n0 + tid)) * NH + h];

    float acc[16];
#pragma unroll
    for (int j = 0; j < 16; ++j) acc[j] = 0.0f;

    for (int mt = 0; mt <= nt; ++mt) {
        const int m0 = mt * 64;
        __syncthreads();   // protect ks(S)/vs from previous iteration
        {
            const int c0 = q4 * 16;
            const float* srck = qkv + ((size_t)(b * NSEQ + m0 + r) * 3072) + 1024 + h * HD + c0;
            const float* srcv = srck + 1024;
#pragma unroll
            for (int j = 0; j < 16; j += 4) {
                float4 v = *(const float4*)(srck + j);
                ks[r][c0 + j] = v.x; ks[r][c0 + j + 1] = v.y;
                ks[r][c0 + j + 2] = v.z; ks[r][c0 + j + 3] = v.w;
                float4 w = *(const float4*)(srcv + j);
                vs[r][c0 + j] = w.x; vs[r][c0 + j + 1] = w.y;
                vs[r][c0 + j + 2] = w.z; vs[r][c0 + j + 3] = w.w;
            }
        }
        if (tid < 64) lbm[tid] = logb[((size_t)(b * NSEQ + m0 + tid)) * NH + h];
        __syncthreads();

        // phase A: s[j] = S[r][q4*16+j]
        float s[16];
#pragma unroll
        for (int j = 0; j < 16; ++j) {
            const int m = q4 * 16 + j;
            float dot = 0.0f;
#pragma unroll
            for (int kk = 0; kk < 64; ++kk) dot += qs[r][kk] * ks[m][kk];
            const float ld = lbn[r] - lbm[m];
            const bool valid = (n0 + r) >= (m0 + m);
            s[j] = valid ? dot * SCALE * expf(fmaxf(ld, -80.0f)) : 0.0f;
        }
        __syncthreads();
#pragma unroll
        for (int j = 0; j < 16; ++j) ks[r][q4 * 16 + j] = s[j];
        __syncthreads();

        // phase B: acc[j] (cols q4*16+j) += sum_m S[r][m] * v[m][c]
#pragma unroll
        for (int m = 0; m < 64; ++m) {
            const float sv = ks[r][m];
#pragma unroll
            for (int j = 0; j < 16; ++j) acc[j] += sv * vs[m][q4 * 16 + j];
        }
    }
    // write O in (B, N, H*64) layout
    {
        float* dst = O + ((size_t)(b * NSEQ + n0 + r) * DM) + h * HD + q4 * 16;
#pragma unroll
        for (int j = 0; j < 16; j += 4) {
            float4 v = make_float4(acc[j], acc[j + 1], acc[j + 2], acc[j + 3]);
            *(float4*)(dst + j) = v;
        }
    }
}

// -------- groupnorm stats per (b,h) over N x 64 ----------
__global__ __launch_bounds__(256) void gn_stats(const float* __restrict__ O,
                                                float* __restrict__ stats) {
    const int bh = blockIdx.x;
    const int b = bh >> 4, h = bh & 15;
    const int tid = threadIdx.x;
    float sum = 0.0f, ssq = 0.0f;
    for (int idx = tid; idx < NSEQ * HD; idx += 256) {
        const int n = idx >> 6, d = idx & 63;
        float v = O[((size_t)(b * NSEQ + n) * DM) + h * HD + d];
        sum += v; ssq += v * v;
    }
    __shared__ float rs[256], rq[256];
    rs[tid] = sum; rq[tid] = ssq;
    __syncthreads();
    for (int s = 128; s > 0; s >>= 1) {
        if (tid < s) { rs[tid] += rs[tid + s]; rq[tid] += rq[tid + s]; }
        __syncthreads();
    }
    if (tid == 0) {
        const float inv = 1.0f / (NSEQ * HD);
        float mu = rs[0] * inv;
        float var = rq[0] * inv - mu * mu;
        stats[bh * 2] = mu;
        stats[bh * 2 + 1] = rsqrtf(var + 1e-5f);
    }
}

// -------- fused silu(X@Wgated) * groupnorm(O), in place on G ----------
__global__ __launch_bounds__(256) void gate_kernel(float* __restrict__ G,
                                                   const float* __restrict__ O,
                                                   const float* __restrict__ stats) {
    const size_t i = (size_t)blockIdx.x * 256 + threadIdx.x;
    const int col = (int)(i & 1023);
    const int h = col >> 6;
    const int bn = (int)(i >> 10);
    const int b = bn >> 10;
    const float mu = stats[(b * NH + h) * 2];
    const float rstd = stats[(b * NH + h) * 2 + 1];
    const float g = G[i];
    const float silu = g / (1.0f + expf(-g));
    G[i] = silu * (O[i] - mu) * rstd;
}

extern "C" void kernel_launch(void* const* d_in, const int* in_sizes, int n_in,
                              void* d_out, int out_size, void* d_ws, size_t ws_size,
                              hipStream_t stream) {
    const float* X       = (const float*)d_in[0];
    const float* ts      = (const float*)d_in[1];
    const float* W_qkv   = (const float*)d_in[2];
    const float* W_gamma = (const float*)d_in[3];
    const float* W_gated = (const float*)d_in[4];
    const float* W_out   = (const float*)d_in[5];
    float* out = (float*)d_out;

    float* ws    = (float*)d_ws;
    float* qkv   = ws;                     // 4*1024*3072 = 12582912 floats
    float* logb  = qkv + 12582912;         // 4*1024*16   = 65536
    float* Oatt  = logb + 65536;           // 4*1024*1024 = 4194304
    float* stats = Oatt + 4194304;         // 128
    float* G     = qkv;                    // alias: qkv is dead after attention

    const int M = NB * NSEQ;               // 4096

    gemm_f32<<<dim3(3072 / 64, M / 64), 256, 0, stream>>>(X, W_qkv, qkv, M, DM, 3072);
    gamma_kernel<<<M, 256, 0, stream>>>(X, W_gamma, logb);
    scan_kernel<<<1, 64, 0, stream>>>(logb);
    rope_kernel<<<(M * NH * 32) / 256, 256, 0, stream>>>(qkv, ts);
    attn_kernel<<<dim3(NSEQ / 64, NB * NH), 256, 0, stream>>>(qkv, logb, Oatt);
    gn_stats<<<NB * NH, 256, 0, stream>>>(Oatt, stats);
    gemm_f32<<<dim3(DM / 64, M / 64), 256, 0, stream>>>(X, W_gated, G, M, DM, DM);
    gate_kernel<<<(M * DM) / 256, 256, 0, stream>>>(G, Oatt, stats);
    gemm_f32<<<dim3(DM / 64, M / 64), 256, 0, stream>>>(G, W_out, out, M, DM, DM);
}

// Round 2
// 967.259 us; speedup vs baseline: 2.0695x; 2.0695x over previous
//
#include <hip/hip_runtime.h>
#include <cstddef>
#include <cstdint>

#define NH 16
#define HD 64
#define NSEQ 1024
#define NB 4
#define DM 1024
#define SCALE 0.125f   // 64^-0.5

// ---------------- tiled f32 GEMM: C[M,N] = A[M,K] @ B[K,N], 128x128x16 -------
__global__ __launch_bounds__(256) void gemm_f32(const float* __restrict__ A,
                                                const float* __restrict__ B,
                                                float* __restrict__ C,
                                                int M, int K, int N) {
    __shared__ float As[16][132];  // [kk][m]  (transposed A tile)
    __shared__ float Bs[16][132];  // [kk][n]
    const int tid = threadIdx.x;
    const int tx = tid & 15;       // col group
    const int ty = tid >> 4;       // row group
    const int row0 = blockIdx.y * 128, col0 = blockIdx.x * 128;

    float acc[8][8];
#pragma unroll
    for (int i = 0; i < 8; ++i)
#pragma unroll
        for (int j = 0; j < 8; ++j) acc[i][j] = 0.0f;

    for (int k0 = 0; k0 < K; k0 += 16) {
        // A tile: 128 rows x 16 k. thread: r = tid>>1, kk0 = (tid&1)*8
        {
            const int r = tid >> 1;
            const int kk0 = (tid & 1) * 8;
            const float* src = A + (size_t)(row0 + r) * K + k0 + kk0;
            float4 v0 = *(const float4*)(src);
            float4 v1 = *(const float4*)(src + 4);
            As[kk0 + 0][r] = v0.x; As[kk0 + 1][r] = v0.y;
            As[kk0 + 2][r] = v0.z; As[kk0 + 3][r] = v0.w;
            As[kk0 + 4][r] = v1.x; As[kk0 + 5][r] = v1.y;
            As[kk0 + 6][r] = v1.z; As[kk0 + 7][r] = v1.w;
        }
        // B tile: 16 k x 128 cols. thread: kk = tid>>4, n0 = (tid&15)*8
        {
            const int kk = tid >> 4;
            const int n0 = (tid & 15) * 8;
            const float* src = B + (size_t)(k0 + kk) * N + col0 + n0;
            *(float4*)&Bs[kk][n0]     = *(const float4*)(src);
            *(float4*)&Bs[kk][n0 + 4] = *(const float4*)(src + 4);
        }
        __syncthreads();
#pragma unroll
        for (int kk = 0; kk < 16; ++kk) {
            float4 a0 = *(const float4*)&As[kk][ty * 4];
            float4 a1 = *(const float4*)&As[kk][64 + ty * 4];
            float4 b0 = *(const float4*)&Bs[kk][tx * 4];
            float4 b1 = *(const float4*)&Bs[kk][64 + tx * 4];
            const float av[8] = {a0.x, a0.y, a0.z, a0.w, a1.x, a1.y, a1.z, a1.w};
            const float bv[8] = {b0.x, b0.y, b0.z, b0.w, b1.x, b1.y, b1.z, b1.w};
#pragma unroll
            for (int i = 0; i < 8; ++i)
#pragma unroll
                for (int j = 0; j < 8; ++j) acc[i][j] += av[i] * bv[j];
        }
        __syncthreads();
    }
#pragma unroll
    for (int ih = 0; ih < 2; ++ih)
#pragma unroll
        for (int i = 0; i < 4; ++i) {
            const int r = row0 + ih * 64 + ty * 4 + i;
#pragma unroll
            for (int jh = 0; jh < 2; ++jh) {
                float4 v = make_float4(acc[ih * 4 + i][jh * 4 + 0], acc[ih * 4 + i][jh * 4 + 1],
                                       acc[ih * 4 + i][jh * 4 + 2], acc[ih * 4 + i][jh * 4 + 3]);
                *(float4*)(C + (size_t)r * N + col0 + jh * 64 + tx * 4) = v;
            }
        }
}

// -------- gamma: loggam[row,h] = log(sigmoid(X[row]·Wg[:,h])^(1/20) + 1e-8) ----
__global__ __launch_bounds__(256) void gamma_kernel(const float* __restrict__ X,
                                                    const float* __restrict__ Wg,
                                                    float* __restrict__ loggam) {
    const int row = blockIdx.x;          // b*N + n
    const int tid = threadIdx.x;
    const int h = tid & 15;
    const int g = tid >> 4;              // 16 k-chunks
    const float* x = X + (size_t)row * DM;
    float sum = 0.0f;
    for (int kk = g; kk < DM; kk += 16) sum += x[kk] * Wg[(size_t)kk * NH + h];
    __shared__ float red[256];
    red[tid] = sum;
    __syncthreads();
    for (int s = 128; s >= 16; s >>= 1) {
        if (tid < s) red[tid] += red[tid + s];
        __syncthreads();
    }
    if (tid < 16) {
        float d = red[tid];
        float sig = 1.0f / (1.0f + expf(-d));
        float gam = powf(sig, 1.0f / 20.0f);
        loggam[(size_t)row * NH + tid] = logf(gam + 1e-8f);
    }
}

// -------- parallel cumsum over n per (b,h), one wave per (b,h) ----------
__global__ __launch_bounds__(256) void scan_kernel(float* __restrict__ lg) {
    const int wave = threadIdx.x >> 6;
    const int lane = threadIdx.x & 63;
    const int bh = blockIdx.x * 4 + wave;   // 64 total
    const int b = bh >> 4, h = bh & 15;
    float* p = lg + (size_t)b * NSEQ * NH + h;
    const int n0 = lane * 16;
    float v[16];
    float s = 0.0f;
#pragma unroll
    for (int j = 0; j < 16; ++j) { v[j] = p[(size_t)(n0 + j) * NH]; s += v[j]; }
    float sc = s;
#pragma unroll
    for (int off = 1; off < 64; off <<= 1) {
        float o = __shfl_up(sc, off, 64);
        if (lane >= off) sc += o;
    }
    float acc = sc - s;   // exclusive prefix
#pragma unroll
    for (int j = 0; j < 16; ++j) { acc += v[j]; p[(size_t)(n0 + j) * NH] = acc; }
}

// -------- xPos RoPE in place on q (off 0) and k (off 1024) in qkv buffer ------
__global__ __launch_bounds__(256) void rope_kernel(float* __restrict__ qkv,
                                                   const float* __restrict__ ts) {
    const int gid = blockIdx.x * 256 + threadIdx.x; // pair index
    const int i = gid & 31;                         // freq index
    const int rest = gid >> 5;
    const int h = rest & 15;
    const int bn = rest >> 4;                       // b*N+n
    const float t = ts[bn];
    const float inv_freq = powf(10000.0f, -(float)(2 * i) / 64.0f);
    const float ang = t * inv_freq;
    const float s = sinf(ang), c = cosf(ang);
    const float sv = ((float)(2 * i) + 0.4f * 64.0f) / (1.4f * 64.0f);
    const float scale = powf(sv, t / 512.0f);
    const size_t base = (size_t)bn * 3072 + h * HD + 2 * i;
    float q0 = qkv[base], q1 = qkv[base + 1];
    qkv[base]     = (q0 * c - q1 * s) * scale;
    qkv[base + 1] = (q1 * c + q0 * s) * scale;
    float k0 = qkv[base + 1024], k1 = qkv[base + 1025];
    const float iscale = 1.0f / scale;
    qkv[base + 1024] = (k0 * c - k1 * s) * iscale;
    qkv[base + 1025] = (k1 * c + k0 * s) * iscale;
}

// -------- causal decay attention, 64x64 tiles, 4x4 register-blocked ----------
__global__ __launch_bounds__(256) void attn_kernel(const float* __restrict__ qkv,
                                                   const float* __restrict__ logb,
                                                   float* __restrict__ O) {
    const int nt = blockIdx.x;        // n tile (16)
    const int bh = blockIdx.y;        // b*16+h (64)
    const int b = bh >> 4, h = bh & 15;
    const int tid = threadIdx.x;
    const int tx = tid & 15;          // S col group / O col group
    const int ty = tid >> 4;          // S row group / O row group
    __shared__ float qT[64][68];      // qT[d][r]
    __shared__ float kT[64][68];      // phase A: kT[d][m]; then sT[m][r]
    __shared__ float vs[64][68];      // vs[m][d]
    __shared__ float lbn[64], lbm[64];
    const int n0 = nt * 64;
    const int lr = tid >> 2;          // load row
    const int ld0 = (tid & 3) * 16;   // load d start

    // load q tile transposed (once)
    {
        const float* src = qkv + ((size_t)(b * NSEQ + n0 + lr) * 3072) + h * HD + ld0;
#pragma unroll
        for (int j = 0; j < 16; j += 4) {
            float4 v = *(const float4*)(src + j);
            qT[ld0 + j + 0][lr] = v.x; qT[ld0 + j + 1][lr] = v.y;
            qT[ld0 + j + 2][lr] = v.z; qT[ld0 + j + 3][lr] = v.w;
        }
    }
    if (tid < 64) lbn[tid] = logb[((size_t)(b * NSEQ + n0 + tid)) * NH + h];

    float out[4][4];
#pragma unroll
    for (int i = 0; i < 4; ++i)
#pragma unroll
        for (int j = 0; j < 4; ++j) out[i][j] = 0.0f;

    for (int mt = 0; mt <= nt; ++mt) {
        const int m0 = mt * 64;
        __syncthreads();   // kT/vs free from previous phase B (also covers q store on iter 0)
        {
            const float* srck = qkv + ((size_t)(b * NSEQ + m0 + lr) * 3072) + 1024 + h * HD + ld0;
            const float* srcv = srck + 1024;
#pragma unroll
            for (int j = 0; j < 16; j += 4) {
                float4 v = *(const float4*)(srck + j);
                kT[ld0 + j + 0][lr] = v.x; kT[ld0 + j + 1][lr] = v.y;
                kT[ld0 + j + 2][lr] = v.z; kT[ld0 + j + 3][lr] = v.w;
                float4 w = *(const float4*)(srcv + j);
                *(float4*)&vs[lr][ld0 + j] = w;
            }
        }
        if (tid < 64) lbm[tid] = logb[((size_t)(b * NSEQ + m0 + tid)) * NH + h];
        __syncthreads();

        // phase A: S[r][m] = sum_d q[r][d]*k[m][d], r=ty*4+i, m=tx*4+j
        float acc[4][4];
#pragma unroll
        for (int i = 0; i < 4; ++i)
#pragma unroll
            for (int j = 0; j < 4; ++j) acc[i][j] = 0.0f;
#pragma unroll 8
        for (int d = 0; d < 64; ++d) {
            float4 a = *(const float4*)&qT[d][ty * 4];
            float4 bq = *(const float4*)&kT[d][tx * 4];
            const float av[4] = {a.x, a.y, a.z, a.w};
            const float bv[4] = {bq.x, bq.y, bq.z, bq.w};
#pragma unroll
            for (int i = 0; i < 4; ++i)
#pragma unroll
                for (int j = 0; j < 4; ++j) acc[i][j] += av[i] * bv[j];
        }
        // decay + causal mask
        const bool diag = (mt == nt);
#pragma unroll
        for (int i = 0; i < 4; ++i) {
            const float ln = lbn[ty * 4 + i];
#pragma unroll
            for (int j = 0; j < 4; ++j) {
                const int m = tx * 4 + j;
                float dec = __expf(fmaxf(ln - lbm[m], -80.0f));
                float sv = acc[i][j] * SCALE * dec;
                if (diag && (ty * 4 + i) < m) sv = 0.0f;
                acc[i][j] = sv;
            }
        }
        __syncthreads();  // everyone done reading kT
        // store S transposed: sT[m][r] = S[r][m]  (into kT)
#pragma unroll
        for (int j = 0; j < 4; ++j) {
            float4 v = make_float4(acc[0][j], acc[1][j], acc[2][j], acc[3][j]);
            *(float4*)&kT[tx * 4 + j][ty * 4] = v;
        }
        __syncthreads();

        // phase B: out[i][j] += sum_m S[r][m] * v[m][c], c=tx*4+j
#pragma unroll 8
        for (int m = 0; m < 64; ++m) {
            float4 a = *(const float4*)&kT[m][ty * 4];
            float4 bv4 = *(const float4*)&vs[m][tx * 4];
            const float av[4] = {a.x, a.y, a.z, a.w};
            const float bv[4] = {bv4.x, bv4.y, bv4.z, bv4.w};
#pragma unroll
            for (int i = 0; i < 4; ++i)
#pragma unroll
                for (int j = 0; j < 4; ++j) out[i][j] += av[i] * bv[j];
        }
    }
    // write O in (B, N, H*64) layout
#pragma unroll
    for (int i = 0; i < 4; ++i) {
        float* dst = O + ((size_t)(b * NSEQ + n0 + ty * 4 + i) * DM) + h * HD + tx * 4;
        *(float4*)dst = make_float4(out[i][0], out[i][1], out[i][2], out[i][3]);
    }
}

// -------- groupnorm stats per (b,h) over N x 64 ----------
__global__ __launch_bounds__(256) void gn_stats(const float* __restrict__ O,
                                                float* __restrict__ stats) {
    const int bh = blockIdx.x;
    const int b = bh >> 4, h = bh & 15;
    const int tid = threadIdx.x;
    float sum = 0.0f, ssq = 0.0f;
    for (int idx = tid; idx < NSEQ * HD; idx += 256) {
        const int n = idx >> 6, d = idx & 63;
        float v = O[((size_t)(b * NSEQ + n) * DM) + h * HD + d];
        sum += v; ssq += v * v;
    }
    __shared__ float rs[256], rq[256];
    rs[tid] = sum; rq[tid] = ssq;
    __syncthreads();
    for (int s = 128; s > 0; s >>= 1) {
        if (tid < s) { rs[tid] += rs[tid + s]; rq[tid] += rq[tid + s]; }
        __syncthreads();
    }
    if (tid == 0) {
        const float inv = 1.0f / (NSEQ * HD);
        float mu = rs[0] * inv;
        float var = rq[0] * inv - mu * mu;
        stats[bh * 2] = mu;
        stats[bh * 2 + 1] = rsqrtf(var + 1e-5f);
    }
}

// -------- fused silu(X@Wgated) * groupnorm(O), in place on G ----------
__global__ __launch_bounds__(256) void gate_kernel(float* __restrict__ G,
                                                   const float* __restrict__ O,
                                                   const float* __restrict__ stats) {
    const size_t i = (size_t)blockIdx.x * 256 + threadIdx.x;
    const int col = (int)(i & 1023);
    const int h = col >> 6;
    const int bn = (int)(i >> 10);
    const int b = bn >> 10;
    const float mu = stats[(b * NH + h) * 2];
    const float rstd = stats[(b * NH + h) * 2 + 1];
    const float g = G[i];
    const float silu = g / (1.0f + expf(-g));
    G[i] = silu * (O[i] - mu) * rstd;
}

extern "C" void kernel_launch(void* const* d_in, const int* in_sizes, int n_in,
                              void* d_out, int out_size, void* d_ws, size_t ws_size,
                              hipStream_t stream) {
    const float* X       = (const float*)d_in[0];
    const float* ts      = (const float*)d_in[1];
    const float* W_qkv   = (const float*)d_in[2];
    const float* W_gamma = (const float*)d_in[3];
    const float* W_gated = (const float*)d_in[4];
    const float* W_out   = (const float*)d_in[5];
    float* out = (float*)d_out;

    float* ws    = (float*)d_ws;
    float* qkv   = ws;                     // 4*1024*3072 floats
    float* logb  = qkv + 12582912;         // 4*1024*16
    float* Oatt  = logb + 65536;           // 4*1024*1024
    float* stats = Oatt + 4194304;         // 128
    float* G     = qkv;                    // alias: qkv dead after attention

    const int M = NB * NSEQ;               // 4096

    gemm_f32<<<dim3(3072 / 128, M / 128), 256, 0, stream>>>(X, W_qkv, qkv, M, DM, 3072);
    gamma_kernel<<<M, 256, 0, stream>>>(X, W_gamma, logb);
    scan_kernel<<<16, 256, 0, stream>>>(logb);
    rope_kernel<<<(M * NH * 32) / 256, 256, 0, stream>>>(qkv, ts);
    attn_kernel<<<dim3(NSEQ / 64, NB * NH), 256, 0, stream>>>(qkv, logb, Oatt);
    gn_stats<<<NB * NH, 256, 0, stream>>>(Oatt, stats);
    gemm_f32<<<dim3(DM / 128, M / 128), 256, 0, stream>>>(X, W_gated, G, M, DM, DM);
    gate_kernel<<<(M * DM) / 256, 256, 0, stream>>>(G, Oatt, stats);
    gemm_f32<<<dim3(DM / 128, M / 128), 256, 0, stream>>>(G, W_out, out, M, DM, DM);
}

// Round 3
// 358.667 us; speedup vs baseline: 5.5812x; 2.6968x over previous
//
#include <hip/hip_runtime.h>
#include <cstddef>
#include <cstdint>

#define NH 16
#define HD 64
#define NSEQ 1024
#define NB 4
#define DM 1024
#define SCALE 0.125f   // 64^-0.5

typedef __attribute__((ext_vector_type(8))) short v8s;   // 8 bf16
typedef __attribute__((ext_vector_type(4))) float v4f;   // 4 f32

__device__ inline short f2bf(float x) {
    union { float f; unsigned u; } v; v.f = x;
    unsigned r = v.u + 0x7FFF + ((v.u >> 16) & 1);
    return (short)(r >> 16);
}

// ---------- convert f32 rows -> bf16 (same layout) ----------
__global__ __launch_bounds__(256) void convert_rows(const float* __restrict__ X,
                                                    short* __restrict__ Xb) {
    const size_t i = ((size_t)blockIdx.x * 256 + threadIdx.x) * 4;
    float4 v = *(const float4*)(X + i);
    *(short4*)(Xb + i) = make_short4(f2bf(v.x), f2bf(v.y), f2bf(v.z), f2bf(v.w));
}

// ---------- transpose-convert: W f32 [K][N] -> Wt bf16 [N][K] ----------
__global__ __launch_bounds__(256) void tconv(const float* __restrict__ W,
                                             short* __restrict__ Wt,
                                             int K, int N) {
    __shared__ float tile[32][33];
    const int kt = blockIdx.y * 32, nt = blockIdx.x * 32;
    const int t = threadIdx.x;
    const int r = t >> 3, c0 = (t & 7) * 4;
    float4 v = *(const float4*)(W + (size_t)(kt + r) * N + nt + c0);
    tile[r][c0] = v.x; tile[r][c0 + 1] = v.y; tile[r][c0 + 2] = v.z; tile[r][c0 + 3] = v.w;
    __syncthreads();
    *(short4*)(Wt + (size_t)(nt + r) * K + kt + c0) =
        make_short4(f2bf(tile[c0][r]), f2bf(tile[c0 + 1][r]),
                    f2bf(tile[c0 + 2][r]), f2bf(tile[c0 + 3][r]));
}

// ---------- bf16 MFMA GEMM: C[M][N] = A[M][K] @ Bt[N][K]^T, 128x128xK ----------
__global__ __launch_bounds__(256) void gemm_bt(const short* __restrict__ A,
                                               const short* __restrict__ Bt,
                                               float* __restrict__ C,
                                               int M, int N, int K) {
    __shared__ short As[128 * 32];
    __shared__ short Bs[128 * 32];
    const int tid = threadIdx.x;
    const int w = tid >> 6, l = tid & 63;
    const int wr = w >> 1, wc = w & 1;           // 2x2 wave grid, 64x64 each
    const int row0 = blockIdx.y * 128, col0 = blockIdx.x * 128;

    v4f acc[4][4];
#pragma unroll
    for (int i = 0; i < 4; ++i)
#pragma unroll
        for (int j = 0; j < 4; ++j) acc[i][j] = (v4f){0.f, 0.f, 0.f, 0.f};

    const int c0 = tid, c1 = tid + 256;          // chunk ids (512 of 16B per matrix)
    for (int k0 = 0; k0 < K; k0 += 32) {
        __syncthreads();  // previous fragment reads done before overwrite
        {
            v8s va0 = *(const v8s*)(A + (size_t)(row0 + (c0 >> 2)) * K + k0 + (c0 & 3) * 8);
            v8s va1 = *(const v8s*)(A + (size_t)(row0 + (c1 >> 2)) * K + k0 + (c1 & 3) * 8);
            v8s vb0 = *(const v8s*)(Bt + (size_t)(col0 + (c0 >> 2)) * K + k0 + (c0 & 3) * 8);
            v8s vb1 = *(const v8s*)(Bt + (size_t)(col0 + (c1 >> 2)) * K + k0 + (c1 & 3) * 8);
            int a0 = ((c0 >> 2) * 64 + (c0 & 3) * 16) ^ (((c0 >> 2) & 7) << 4);
            int a1 = ((c1 >> 2) * 64 + (c1 & 3) * 16) ^ (((c1 >> 2) & 7) << 4);
            *(v8s*)((char*)As + a0) = va0;
            *(v8s*)((char*)As + a1) = va1;
            *(v8s*)((char*)Bs + a0) = vb0;
            *(v8s*)((char*)Bs + a1) = vb1;
        }
        __syncthreads();
        v8s af[4], bfr[4];
#pragma unroll
        for (int i = 0; i < 4; ++i) {
            const int ra = wr * 64 + i * 16 + (l & 15);
            af[i] = *(const v8s*)((char*)As + ((ra * 64 + (l >> 4) * 16) ^ ((ra & 7) << 4)));
            const int rb = wc * 64 + i * 16 + (l & 15);
            bfr[i] = *(const v8s*)((char*)Bs + ((rb * 64 + (l >> 4) * 16) ^ ((rb & 7) << 4)));
        }
#pragma unroll
        for (int i = 0; i < 4; ++i)
#pragma unroll
            for (int j = 0; j < 4; ++j)
                acc[i][j] = __builtin_amdgcn_mfma_f32_16x16x32_bf16(af[i], bfr[j], acc[i][j], 0, 0, 0);
    }
#pragma unroll
    for (int i = 0; i < 4; ++i)
#pragma unroll
        for (int j = 0; j < 4; ++j) {
            const int r0 = row0 + wr * 64 + i * 16 + (l >> 4) * 4;
            const int cc = col0 + wc * 64 + j * 16 + (l & 15);
#pragma unroll
            for (int t2 = 0; t2 < 4; ++t2)
                C[(size_t)(r0 + t2) * N + cc] = acc[i][j][t2];
        }
}

// -------- gamma: loggam[row,h] = log(sigmoid(X[row]·Wg[:,h])^(1/20) + 1e-8) ----
__global__ __launch_bounds__(256) void gamma_kernel(const float* __restrict__ X,
                                                    const float* __restrict__ Wg,
                                                    float* __restrict__ loggam) {
    const int row = blockIdx.x;
    const int tid = threadIdx.x;
    const int h = tid & 15;
    const int g = tid >> 4;
    const float* x = X + (size_t)row * DM;
    float sum = 0.0f;
    for (int kk = g; kk < DM; kk += 16) sum += x[kk] * Wg[(size_t)kk * NH + h];
    __shared__ float red[256];
    red[tid] = sum;
    __syncthreads();
    for (int s = 128; s >= 16; s >>= 1) {
        if (tid < s) red[tid] += red[tid + s];
        __syncthreads();
    }
    if (tid < 16) {
        float d = red[tid];
        float sig = 1.0f / (1.0f + expf(-d));
        float gam = powf(sig, 1.0f / 20.0f);
        loggam[(size_t)row * NH + tid] = logf(gam + 1e-8f);
    }
}

// -------- parallel cumsum over n per (b,h), one wave per (b,h) ----------
__global__ __launch_bounds__(256) void scan_kernel(float* __restrict__ lg) {
    const int wave = threadIdx.x >> 6;
    const int lane = threadIdx.x & 63;
    const int bh = blockIdx.x * 4 + wave;
    const int b = bh >> 4, h = bh & 15;
    float* p = lg + (size_t)b * NSEQ * NH + h;
    const int n0 = lane * 16;
    float v[16];
    float s = 0.0f;
#pragma unroll
    for (int j = 0; j < 16; ++j) { v[j] = p[(size_t)(n0 + j) * NH]; s += v[j]; }
    float sc = s;
#pragma unroll
    for (int off = 1; off < 64; off <<= 1) {
        float o = __shfl_up(sc, off, 64);
        if (lane >= off) sc += o;
    }
    float acc = sc - s;
#pragma unroll
    for (int j = 0; j < 16; ++j) { acc += v[j]; p[(size_t)(n0 + j) * NH] = acc; }
}

// -------- xPos RoPE in place on q,k (f32 qkv) ------
__global__ __launch_bounds__(256) void rope_kernel(float* __restrict__ qkv,
                                                   const float* __restrict__ ts) {
    const int gid = blockIdx.x * 256 + threadIdx.x;
    const int i = gid & 31;
    const int rest = gid >> 5;
    const int h = rest & 15;
    const int bn = rest >> 4;
    const float t = ts[bn];
    const float inv_freq = powf(10000.0f, -(float)(2 * i) / 64.0f);
    const float ang = t * inv_freq;
    const float s = sinf(ang), c = cosf(ang);
    const float sv = ((float)(2 * i) + 0.4f * 64.0f) / (1.4f * 64.0f);
    const float scale = powf(sv, t / 512.0f);
    const size_t base = (size_t)bn * 3072 + h * HD + 2 * i;
    float q0 = qkv[base], q1 = qkv[base + 1];
    qkv[base]     = (q0 * c - q1 * s) * scale;
    qkv[base + 1] = (q1 * c + q0 * s) * scale;
    float k0 = qkv[base + 1024], k1 = qkv[base + 1025];
    const float iscale = 1.0f / scale;
    qkv[base + 1024] = (k0 * c - k1 * s) * iscale;
    qkv[base + 1025] = (k1 * c + k0 * s) * iscale;
}

// -------- MFMA causal decay attention, 64x64 tiles, 4 waves ----------
__global__ __launch_bounds__(256) void attn_mfma(const float* __restrict__ qkv,
                                                 const float* __restrict__ logb,
                                                 float* __restrict__ O) {
    const int nt = blockIdx.x;
    const int bh = blockIdx.y;
    const int b = bh >> 4, h = bh & 15;
    const int tid = threadIdx.x;
    const int w = tid >> 6, l = tid & 63;
    const int n0 = nt * 64;
    __shared__ short Qs[64 * 64];
    __shared__ short Ks[64 * 64];
    __shared__ short Vt[64 * 64];
    __shared__ short Ps[64 * 64];
    __shared__ float lbn[64], lbm[64];

    // stage Q: lane handles q-row l, d columns w*16..w*16+15
    {
        const float* src = qkv + (size_t)(b * NSEQ + n0 + l) * 3072 + h * HD + w * 16;
        short tq[16] __attribute__((aligned(16)));
#pragma unroll
        for (int j = 0; j < 16; j += 4) {
            float4 v = *(const float4*)(src + j);
            tq[j] = f2bf(v.x); tq[j + 1] = f2bf(v.y); tq[j + 2] = f2bf(v.z); tq[j + 3] = f2bf(v.w);
        }
#pragma unroll
        for (int c = 0; c < 16; c += 8) {
            int addr = (l * 128 + (w * 16 + c) * 2) ^ ((l & 7) << 4);
            *(v8s*)((char*)Qs + addr) = *(v8s*)&tq[c];
        }
    }
    if (tid < 64) lbn[tid] = logb[(size_t)(b * NSEQ + n0 + tid) * NH + h];

    v4f oacc[4];
#pragma unroll
    for (int i = 0; i < 4; ++i) oacc[i] = (v4f){0.f, 0.f, 0.f, 0.f};

    for (int mt = 0; mt <= nt; ++mt) {
        const int m0 = mt * 64;
        __syncthreads();   // prior-iter reads (and initial Q/lbn writes) complete
        {
            const float* srck = qkv + (size_t)(b * NSEQ + m0 + l) * 3072 + 1024 + h * HD + w * 16;
            const float* srcv = srck + 1024;
            short tk[16] __attribute__((aligned(16)));
#pragma unroll
            for (int j = 0; j < 16; j += 4) {
                float4 v = *(const float4*)(srck + j);
                tk[j] = f2bf(v.x); tk[j + 1] = f2bf(v.y); tk[j + 2] = f2bf(v.z); tk[j + 3] = f2bf(v.w);
            }
#pragma unroll
            for (int c = 0; c < 16; c += 8) {
                int addr = (l * 128 + (w * 16 + c) * 2) ^ ((l & 7) << 4);
                *(v8s*)((char*)Ks + addr) = *(v8s*)&tk[c];
            }
#pragma unroll
            for (int j = 0; j < 16; j += 4) {
                float4 v = *(const float4*)(srcv + j);
                const int d = w * 16 + j;
                *(short*)((char*)Vt + (((d + 0) * 128 + l * 2) ^ (((d + 0) & 7) << 4))) = f2bf(v.x);
                *(short*)((char*)Vt + (((d + 1) * 128 + l * 2) ^ (((d + 1) & 7) << 4))) = f2bf(v.y);
                *(short*)((char*)Vt + (((d + 2) * 128 + l * 2) ^ (((d + 2) & 7) << 4))) = f2bf(v.z);
                *(short*)((char*)Vt + (((d + 3) * 128 + l * 2) ^ (((d + 3) & 7) << 4))) = f2bf(v.w);
            }
        }
        if (tid < 64) lbm[tid] = logb[(size_t)(b * NSEQ + m0 + tid) * NH + h];
        __syncthreads();

        // QK^T for this wave's 16 q-rows
        v8s aq[2];
#pragma unroll
        for (int kc = 0; kc < 2; ++kc) {
            const int r = w * 16 + (l & 15);
            aq[kc] = *(const v8s*)((char*)Qs +
                        ((r * 128 + (kc * 32 + (l >> 4) * 8) * 2) ^ ((r & 7) << 4)));
        }
        v4f sfr[4];
#pragma unroll
        for (int i = 0; i < 4; ++i) sfr[i] = (v4f){0.f, 0.f, 0.f, 0.f};
#pragma unroll
        for (int mtile = 0; mtile < 4; ++mtile) {
#pragma unroll
            for (int kc = 0; kc < 2; ++kc) {
                const int m = mtile * 16 + (l & 15);
                v8s bk = *(const v8s*)((char*)Ks +
                            ((m * 128 + (kc * 32 + (l >> 4) * 8) * 2) ^ ((m & 7) << 4)));
                sfr[mtile] = __builtin_amdgcn_mfma_f32_16x16x32_bf16(aq[kc], bk, sfr[mtile], 0, 0, 0);
            }
        }
        // decay + mask + bf16 convert + store P (wave-local rows)
        const bool diag = (mt == nt);
#pragma unroll
        for (int mtile = 0; mtile < 4; ++mtile) {
            const int m = mtile * 16 + (l & 15);
            const float lm = lbm[m];
#pragma unroll
            for (int t2 = 0; t2 < 4; ++t2) {
                const int r = w * 16 + (l >> 4) * 4 + t2;
                float dec = __expf(fmaxf(lbn[r] - lm, -80.0f));
                float sv = sfr[mtile][t2] * SCALE * dec;
                if (diag && (r < m)) sv = 0.0f;
                *(short*)((char*)Ps + ((r * 128 + m * 2) ^ ((r & 7) << 4))) = f2bf(sv);
            }
        }
        // PV: O[q][d] += P[q][m] V[m][d]  (A=Ps rows of this wave, B=Vt)
#pragma unroll
        for (int kc = 0; kc < 2; ++kc) {
            const int r = w * 16 + (l & 15);
            v8s ap = *(const v8s*)((char*)Ps +
                        ((r * 128 + (kc * 32 + (l >> 4) * 8) * 2) ^ ((r & 7) << 4)));
#pragma unroll
            for (int dt = 0; dt < 4; ++dt) {
                const int d = dt * 16 + (l & 15);
                v8s bv = *(const v8s*)((char*)Vt +
                            ((d * 128 + (kc * 32 + (l >> 4) * 8) * 2) ^ ((d & 7) << 4)));
                oacc[dt] = __builtin_amdgcn_mfma_f32_16x16x32_bf16(ap, bv, oacc[dt], 0, 0, 0);
            }
        }
    }
    // write O (B, N, H*HD)
#pragma unroll
    for (int dt = 0; dt < 4; ++dt) {
        const int col = h * HD + dt * 16 + (l & 15);
        const int r0 = n0 + w * 16 + (l >> 4) * 4;
#pragma unroll
        for (int t2 = 0; t2 < 4; ++t2)
            O[(size_t)(b * NSEQ + r0 + t2) * DM + col] = oacc[dt][t2];
    }
}

// -------- groupnorm stats per (b,h) over N x 64 ----------
__global__ __launch_bounds__(256) void gn_stats(const float* __restrict__ O,
                                                float* __restrict__ stats) {
    const int bh = blockIdx.x;
    const int b = bh >> 4, h = bh & 15;
    const int tid = threadIdx.x;
    float sum = 0.0f, ssq = 0.0f;
    for (int idx = tid; idx < NSEQ * HD; idx += 256) {
        const int n = idx >> 6, d = idx & 63;
        float v = O[((size_t)(b * NSEQ + n) * DM) + h * HD + d];
        sum += v; ssq += v * v;
    }
    __shared__ float rs[256], rq[256];
    rs[tid] = sum; rq[tid] = ssq;
    __syncthreads();
    for (int s = 128; s > 0; s >>= 1) {
        if (tid < s) { rs[tid] += rs[tid + s]; rq[tid] += rq[tid + s]; }
        __syncthreads();
    }
    if (tid == 0) {
        const float inv = 1.0f / (NSEQ * HD);
        float mu = rs[0] * inv;
        float var = rq[0] * inv - mu * mu;
        stats[bh * 2] = mu;
        stats[bh * 2 + 1] = rsqrtf(var + 1e-5f);
    }
}

// -------- fused silu(G) * groupnorm(O) -> bf16 Gb ----------
__global__ __launch_bounds__(256) void gate_kernel(const float* __restrict__ G,
                                                   const float* __restrict__ O,
                                                   const float* __restrict__ stats,
                                                   short* __restrict__ Gb) {
    const size_t i = (size_t)blockIdx.x * 256 + threadIdx.x;
    const int col = (int)(i & 1023);
    const int h = col >> 6;
    const int b = (int)(i >> 20);
    const float mu = stats[(b * NH + h) * 2];
    const float rstd = stats[(b * NH + h) * 2 + 1];
    const float g = G[i];
    const float silu = g / (1.0f + expf(-g));
    Gb[i] = f2bf(silu * (O[i] - mu) * rstd);
}

extern "C" void kernel_launch(void* const* d_in, const int* in_sizes, int n_in,
                              void* d_out, int out_size, void* d_ws, size_t ws_size,
                              hipStream_t stream) {
    const float* X       = (const float*)d_in[0];
    const float* ts      = (const float*)d_in[1];
    const float* W_qkv   = (const float*)d_in[2];
    const float* W_gamma = (const float*)d_in[3];
    const float* W_gated = (const float*)d_in[4];
    const float* W_out   = (const float*)d_in[5];
    float* out = (float*)d_out;

    float* ws    = (float*)d_ws;
    float* qkv   = ws;                         // 12,582,912 f32
    float* logb  = qkv + 12582912;             // 65,536 f32
    float* Oatt  = logb + 65536;               // 4,194,304 f32
    float* stats = Oatt + 4194304;             // 128 f32
    short* Xb    = (short*)(stats + 128);      // 4,194,304 bf16
    short* Wtq   = Xb + 4194304;               // 3,145,728 bf16
    short* Wtg   = Wtq + 3145728;              // 1,048,576 bf16
    short* Wto   = Wtg + 1048576;              // 1,048,576 bf16
    float* Gf    = qkv;                        // alias: qkv dead after attn
    short* Gb    = Xb;                         // alias: Xb dead after gated GEMM

    const int M = NB * NSEQ;                   // 4096

    convert_rows<<<4096, 256, 0, stream>>>(X, Xb);
    tconv<<<dim3(3072 / 32, 1024 / 32), 256, 0, stream>>>(W_qkv, Wtq, 1024, 3072);
    tconv<<<dim3(1024 / 32, 1024 / 32), 256, 0, stream>>>(W_gated, Wtg, 1024, 1024);
    tconv<<<dim3(1024 / 32, 1024 / 32), 256, 0, stream>>>(W_out, Wto, 1024, 1024);

    gemm_bt<<<dim3(3072 / 128, M / 128), 256, 0, stream>>>(Xb, Wtq, qkv, M, 3072, 1024);
    gamma_kernel<<<M, 256, 0, stream>>>(X, W_gamma, logb);
    scan_kernel<<<16, 256, 0, stream>>>(logb);
    rope_kernel<<<(M * NH * 32) / 256, 256, 0, stream>>>(qkv, ts);
    attn_mfma<<<dim3(NSEQ / 64, NB * NH), 256, 0, stream>>>(qkv, logb, Oatt);
    gn_stats<<<NB * NH, 256, 0, stream>>>(Oatt, stats);
    gemm_bt<<<dim3(DM / 128, M / 128), 256, 0, stream>>>(Xb, Wtg, Gf, M, DM, 1024);
    gate_kernel<<<(M * DM) / 256, 256, 0, stream>>>(Gf, Oatt, stats, Gb);
    gemm_bt<<<dim3(DM / 128, M / 128), 256, 0, stream>>>(Gb, Wto, out, M, DM, 1024);
}

// Round 5
// 285.383 us; speedup vs baseline: 7.0144x; 1.2568x over previous
//
#include <hip/hip_runtime.h>
#include <cstddef>
#include <cstdint>

#define NH 16
#define HD 64
#define NSEQ 1024
#define NB 4
#define DM 1024
#define SCALE 0.125f   // 64^-0.5

typedef __attribute__((ext_vector_type(8))) short v8s;   // 8 bf16
typedef __attribute__((ext_vector_type(4))) float v4f;   // 4 f32

__device__ __forceinline__ short f2bf(float x) {
    union { float f; unsigned u; } v; v.f = x;
    unsigned r = v.u + 0x7FFF + ((v.u >> 16) & 1);
    return (short)(r >> 16);
}
__device__ __forceinline__ float bf2f(short x) {
    union { unsigned u; float f; } v; v.u = ((unsigned)(unsigned short)x) << 16;
    return v.f;
}
__device__ __forceinline__ void gload16(const void* g, void* l) {
    __builtin_amdgcn_global_load_lds(
        (const __attribute__((address_space(1))) void*)g,
        (__attribute__((address_space(3))) void*)l, 16, 0, 0);
}
// GEMM tile swizzle: 128 rows x 32 k bf16, row = 64B. XOR bits 4-5 with row bits 1-2.
__device__ __forceinline__ int gswz(int r, int kbyte) {
    return (r * 64 + kbyte) ^ (((r >> 1) & 3) << 4);
}
// attn tile swizzle: 64 rows x 64 cols bf16, row = 128B. XOR bits 4-6 with row bits 0-2.
__device__ __forceinline__ int aswz(int r, int byte) {
    return (r * 128 + byte) ^ ((r & 7) << 4);
}

// ---------- X f32 row-major -> Xb bf16 tiled-swizzled [rt][kt][128x32] ----------
__global__ __launch_bounds__(256) void convert_rows(const float* __restrict__ X,
                                                    short* __restrict__ Xb, int K) {
    const int kt = blockIdx.x, rt = blockIdx.y;
    const int t = threadIdx.x;
    const int rloc = t >> 1, kb0 = (t & 1) * 16;   // 16 elements
    const float* src = X + (size_t)(rt * 128 + rloc) * K + kt * 32 + kb0;
    short o[16] __attribute__((aligned(16)));
#pragma unroll
    for (int j = 0; j < 16; j += 4) {
        float4 v = *(const float4*)(src + j);
        o[j] = f2bf(v.x); o[j + 1] = f2bf(v.y); o[j + 2] = f2bf(v.z); o[j + 3] = f2bf(v.w);
    }
    char* base = (char*)(Xb + ((size_t)rt * (K >> 5) + kt) * 4096);
#pragma unroll
    for (int c = 0; c < 2; ++c)
        *(v8s*)(base + gswz(rloc, kb0 * 2 + c * 16)) = *(v8s*)&o[c * 8];
}

// ---------- W f32 [K][N] -> Bt bf16 tiled-swizzled [ct][kt][128x32] (transposed) ----
__global__ __launch_bounds__(256) void tconv(const float* __restrict__ W,
                                             short* __restrict__ Bt,
                                             int K, int N) {
    __shared__ short lsm[32][136];
    const int ct = blockIdx.x, kt = blockIdx.y;
    const int t = threadIdx.x;
    {
        const int kk = t >> 3, nn0 = (t & 7) * 16;
        const float* src = W + (size_t)(kt * 32 + kk) * N + ct * 128 + nn0;
#pragma unroll
        for (int j = 0; j < 16; j += 4) {
            float4 v = *(const float4*)(src + j);
            lsm[kk][nn0 + j] = f2bf(v.x); lsm[kk][nn0 + j + 1] = f2bf(v.y);
            lsm[kk][nn0 + j + 2] = f2bf(v.z); lsm[kk][nn0 + j + 3] = f2bf(v.w);
        }
    }
    __syncthreads();
    const int rloc = t >> 1, kb0 = (t & 1) * 16;
    short o[16] __attribute__((aligned(16)));
#pragma unroll
    for (int j = 0; j < 16; ++j) o[j] = lsm[kb0 + j][rloc];
    char* base = (char*)(Bt + ((size_t)ct * (K >> 5) + kt) * 4096);
#pragma unroll
    for (int c = 0; c < 2; ++c)
        *(v8s*)(base + gswz(rloc, kb0 * 2 + c * 16)) = *(v8s*)&o[c * 8];
}

// ---------- bf16 MFMA GEMM on tiled inputs: C[M][N] = A @ B^T, K=1024 ----------
template<bool BF16OUT>
__global__ __launch_bounds__(256) void gemm_tt(const short* __restrict__ A,
                                               const short* __restrict__ B,
                                               void* __restrict__ C, int N) {
    __shared__ short As[4096];
    __shared__ short Bs[4096];
    const int tid = threadIdx.x;
    const int w = tid >> 6, l = tid & 63;
    const int wr = w >> 1, wc = w & 1;
    const int rt = blockIdx.y, ct = blockIdx.x;
    const char* Abase = (const char*)A + ((size_t)rt * 32) * 8192;
    const char* Bbase = (const char*)B + ((size_t)ct * 32) * 8192;

    v4f acc[4][4];
#pragma unroll
    for (int i = 0; i < 4; ++i)
#pragma unroll
        for (int j = 0; j < 4; ++j) acc[i][j] = (v4f){0.f, 0.f, 0.f, 0.f};

    for (int kt = 0; kt < 32; ++kt) {
        __syncthreads();
#pragma unroll
        for (int i = 0; i < 2; ++i) {
            const int c = w * 2 + i;
            gload16(Abase + (size_t)kt * 8192 + c * 1024 + l * 16, (char*)As + c * 1024);
            gload16(Bbase + (size_t)kt * 8192 + c * 1024 + l * 16, (char*)Bs + c * 1024);
        }
        __syncthreads();
        v8s af[4], bfr[4];
#pragma unroll
        for (int i = 0; i < 4; ++i) {
            const int ra = wr * 64 + i * 16 + (l & 15);
            af[i] = *(const v8s*)((char*)As + gswz(ra, (l >> 4) * 16));
            const int rb = wc * 64 + i * 16 + (l & 15);
            bfr[i] = *(const v8s*)((char*)Bs + gswz(rb, (l >> 4) * 16));
        }
#pragma unroll
        for (int i = 0; i < 4; ++i)
#pragma unroll
            for (int j = 0; j < 4; ++j)
                acc[i][j] = __builtin_amdgcn_mfma_f32_16x16x32_bf16(af[i], bfr[j], acc[i][j], 0, 0, 0);
    }
#pragma unroll
    for (int i = 0; i < 4; ++i)
#pragma unroll
        for (int j = 0; j < 4; ++j) {
            const int r0 = rt * 128 + wr * 64 + i * 16 + (l >> 4) * 4;
            const int cc = ct * 128 + wc * 64 + j * 16 + (l & 15);
#pragma unroll
            for (int t2 = 0; t2 < 4; ++t2) {
                if (BF16OUT) ((short*)C)[(size_t)(r0 + t2) * N + cc] = f2bf(acc[i][j][t2]);
                else         ((float*)C)[(size_t)(r0 + t2) * N + cc] = acc[i][j][t2];
            }
        }
}

// -------- gamma: loggam[row,h] = log(sigmoid(X[row]·Wg[:,h])^(1/20) + 1e-8) ----
__global__ __launch_bounds__(256) void gamma_kernel(const float* __restrict__ X,
                                                    const float* __restrict__ Wg,
                                                    float* __restrict__ loggam) {
    const int row = blockIdx.x;
    const int tid = threadIdx.x;
    const int h = tid & 15;
    const int g = tid >> 4;
    const float* x = X + (size_t)row * DM;
    float sum = 0.0f;
    for (int kk = g; kk < DM; kk += 16) sum += x[kk] * Wg[(size_t)kk * NH + h];
    __shared__ float red[256];
    red[tid] = sum;
    __syncthreads();
    for (int s = 128; s >= 16; s >>= 1) {
        if (tid < s) red[tid] += red[tid + s];
        __syncthreads();
    }
    if (tid < 16) {
        float d = red[tid];
        float sig = 1.0f / (1.0f + expf(-d));
        float gam = powf(sig, 1.0f / 20.0f);
        loggam[(size_t)row * NH + tid] = logf(gam + 1e-8f);
    }
}

// -------- parallel cumsum over n per (b,h) ----------
__global__ __launch_bounds__(256) void scan_kernel(float* __restrict__ lg) {
    const int wave = threadIdx.x >> 6;
    const int lane = threadIdx.x & 63;
    const int bh = blockIdx.x * 4 + wave;
    const int b = bh >> 4, h = bh & 15;
    float* p = lg + (size_t)b * NSEQ * NH + h;
    const int n0 = lane * 16;
    float v[16];
    float s = 0.0f;
#pragma unroll
    for (int j = 0; j < 16; ++j) { v[j] = p[(size_t)(n0 + j) * NH]; s += v[j]; }
    float sc = s;
#pragma unroll
    for (int off = 1; off < 64; off <<= 1) {
        float o = __shfl_up(sc, off, 64);
        if (lane >= off) sc += o;
    }
    float acc = sc - s;
#pragma unroll
    for (int j = 0; j < 16; ++j) { acc += v[j]; p[(size_t)(n0 + j) * NH] = acc; }
}

// ---- prep: qkvb bf16 -> RoPE'd Q/K + V^T as pre-swizzled 64x64 tiles per (bh,nt) ----
__global__ __launch_bounds__(256) void prep(const short* __restrict__ qkvb,
                                            const float* __restrict__ ts,
                                            short* __restrict__ Qb,
                                            short* __restrict__ Kb,
                                            short* __restrict__ Vtb) {
    __shared__ short vsm[64][72];
    const int tile = blockIdx.x, bh = blockIdx.y;
    const int b = bh >> 4, h = bh & 15;
    const int t = threadIdx.x;
    const int rloc = t >> 2, d0 = (t & 3) * 16;
    const int row = b * NSEQ + tile * 64 + rloc;
    const short* src = qkvb + (size_t)row * 3072 + h * HD;
    const size_t tb = ((size_t)bh * 16 + tile) * 4096;   // elements

    float qa[16], ka[16];
    {
        v8s q0 = *(const v8s*)(src + d0), q1 = *(const v8s*)(src + d0 + 8);
        v8s k0 = *(const v8s*)(src + 1024 + d0), k1 = *(const v8s*)(src + 1024 + d0 + 8);
#pragma unroll
        for (int j = 0; j < 8; ++j) {
            qa[j] = bf2f(q0[j]); qa[j + 8] = bf2f(q1[j]);
            ka[j] = bf2f(k0[j]); ka[j + 8] = bf2f(k1[j]);
        }
    }
    const float tv = ts[row];
    short qo[16] __attribute__((aligned(16)));
    short ko[16] __attribute__((aligned(16)));
#pragma unroll
    for (int j = 0; j < 8; ++j) {
        const int i = (d0 >> 1) + j;
        const float inv_freq = exp2f(-0.4152410119f * (float)i);
        const float ang = tv * inv_freq;
        const float s = sinf(ang), c = cosf(ang);
        const float sv = ((float)(2 * i) + 25.6f) * (1.0f / 89.6f);
        const float e = log2f(sv) * tv * (1.0f / 512.0f);
        const float sc = exp2f(e), isc = exp2f(-e);
        qo[2 * j]     = f2bf((qa[2 * j] * c - qa[2 * j + 1] * s) * sc);
        qo[2 * j + 1] = f2bf((qa[2 * j + 1] * c + qa[2 * j] * s) * sc);
        ko[2 * j]     = f2bf((ka[2 * j] * c - ka[2 * j + 1] * s) * isc);
        ko[2 * j + 1] = f2bf((ka[2 * j + 1] * c + ka[2 * j] * s) * isc);
    }
#pragma unroll
    for (int c = 0; c < 2; ++c) {
        *(v8s*)((char*)(Qb + tb) + aswz(rloc, d0 * 2 + c * 16)) = *(v8s*)&qo[c * 8];
        *(v8s*)((char*)(Kb + tb) + aswz(rloc, d0 * 2 + c * 16)) = *(v8s*)&ko[c * 8];
    }
    // V: already bf16, just transpose through LDS
    {
        v8s v0 = *(const v8s*)(src + 2048 + d0), v1 = *(const v8s*)(src + 2048 + d0 + 8);
        *(short4*)&vsm[rloc][d0]      = *(short4*)&v0;
        *(short4*)&vsm[rloc][d0 + 4]  = *((short4*)&v0 + 1);
        *(short4*)&vsm[rloc][d0 + 8]  = *(short4*)&v1;
        *(short4*)&vsm[rloc][d0 + 12] = *((short4*)&v1 + 1);
    }
    __syncthreads();
    {
        const int d = t >> 2, m0 = (t & 3) * 16;
        short vt[16] __attribute__((aligned(16)));
#pragma unroll
        for (int j = 0; j < 16; ++j) vt[j] = vsm[m0 + j][d];
#pragma unroll
        for (int c = 0; c < 2; ++c)
            *(v8s*)((char*)(Vtb + tb) + aswz(d, m0 * 2 + c * 16)) = *(v8s*)&vt[c * 8];
    }
}

// -------- attn v2: QBLK=128, Q in regs, K/Vt via global_load_lds, P via LDS ------
__global__ __launch_bounds__(256) void attn2(const short* __restrict__ Qb,
                                             const short* __restrict__ Kb,
                                             const short* __restrict__ Vtb,
                                             const float* __restrict__ logb,
                                             float* __restrict__ O) {
    __shared__ short Ks[4096];
    __shared__ short Vts[4096];
    __shared__ short Ps[8192];     // also Q staging at start (16KB)
    __shared__ float lbn[128], lbm[64];
    const int blk = blockIdx.x, bh = blockIdx.y;
    const int b = bh >> 4, h = bh & 15;
    const int tid = threadIdx.x;
    const int w = tid >> 6, l = tid & 63;
    const int n0 = blk * 128;
    const int NT = 2 * blk + 2;

    // stage the two Q tiles (16KB) into Ps
#pragma unroll
    for (int i = 0; i < 4; ++i) {
        const int c = w * 4 + i;
        gload16((const char*)Qb + ((size_t)bh * 16 + 2 * blk) * 8192 + c * 1024 + l * 16,
                (char*)Ps + c * 1024);
    }
    if (tid < 128) lbn[tid] = logb[(size_t)(b * NSEQ + n0 + tid) * NH + h];
    __syncthreads();

    v8s aq[2][2];
#pragma unroll
    for (int rg = 0; rg < 2; ++rg)
#pragma unroll
        for (int kc = 0; kc < 2; ++kc) {
            const int r = w * 32 + rg * 16 + (l & 15);
            aq[rg][kc] = *(const v8s*)((char*)Ps + (r >> 6) * 8192 +
                                       aswz(r & 63, kc * 64 + (l >> 4) * 16));
        }

    v4f oacc[2][4];
#pragma unroll
    for (int rg = 0; rg < 2; ++rg)
#pragma unroll
        for (int dt = 0; dt < 4; ++dt) oacc[rg][dt] = (v4f){0.f, 0.f, 0.f, 0.f};

    for (int mt = 0; mt < NT; ++mt) {
        const int m0 = mt * 64;
        __syncthreads();   // all waves done with prev tile compute (and Q frags read)
#pragma unroll
        for (int i = 0; i < 2; ++i) {
            const int c = w * 2 + i;
            gload16((const char*)Kb + ((size_t)bh * 16 + mt) * 8192 + c * 1024 + l * 16,
                    (char*)Ks + c * 1024);
            gload16((const char*)Vtb + ((size_t)bh * 16 + mt) * 8192 + c * 1024 + l * 16,
                    (char*)Vts + c * 1024);
        }
        if (tid < 64) lbm[tid] = logb[(size_t)(b * NSEQ + m0 + tid) * NH + h];
        __syncthreads();   // staging landed

        const bool active = (m0 <= n0 + w * 32 + 31);
        if (active) {
            // QK^T
            v4f sfr[2][4];
#pragma unroll
            for (int rg = 0; rg < 2; ++rg)
#pragma unroll
                for (int m4 = 0; m4 < 4; ++m4) sfr[rg][m4] = (v4f){0.f, 0.f, 0.f, 0.f};
#pragma unroll
            for (int m4 = 0; m4 < 4; ++m4) {
#pragma unroll
                for (int kc = 0; kc < 2; ++kc) {
                    const int m = m4 * 16 + (l & 15);
                    v8s bk = *(const v8s*)((char*)Ks + aswz(m, kc * 64 + (l >> 4) * 16));
#pragma unroll
                    for (int rg = 0; rg < 2; ++rg)
                        sfr[rg][m4] = __builtin_amdgcn_mfma_f32_16x16x32_bf16(aq[rg][kc], bk, sfr[rg][m4], 0, 0, 0);
                }
            }
            // decay + mask + store P
            const bool needMask = (m0 + 63) > (n0 + w * 32);
#pragma unroll
            for (int rg = 0; rg < 2; ++rg)
#pragma unroll
                for (int m4 = 0; m4 < 4; ++m4) {
                    const int m = m4 * 16 + (l & 15);
                    const float lm = lbm[m];
#pragma unroll
                    for (int t2 = 0; t2 < 4; ++t2) {
                        const int r = w * 32 + rg * 16 + (l >> 4) * 4 + t2;
                        float dec = __expf(fmaxf(lbn[r] - lm, -80.0f));
                        float sval = sfr[rg][m4][t2] * SCALE * dec;
                        if (needMask && (n0 + r) < (m0 + m)) sval = 0.0f;
                        *(short*)((char*)Ps + aswz(r, m * 2)) = f2bf(sval);
                    }
                }
            asm volatile("s_waitcnt lgkmcnt(0)" ::: "memory");
            __builtin_amdgcn_sched_barrier(0);
            // PV
#pragma unroll
            for (int kc = 0; kc < 2; ++kc) {
                v8s ap[2];
#pragma unroll
                for (int rg = 0; rg < 2; ++rg) {
                    const int r = w * 32 + rg * 16 + (l & 15);
                    ap[rg] = *(const v8s*)((char*)Ps + aswz(r, kc * 64 + (l >> 4) * 16));
                }
#pragma unroll
                for (int dt = 0; dt < 4; ++dt) {
                    const int d = dt * 16 + (l & 15);
                    v8s bv = *(const v8s*)((char*)Vts + aswz(d, kc * 64 + (l >> 4) * 16));
#pragma unroll
                    for (int rg = 0; rg < 2; ++rg)
                        oacc[rg][dt] = __builtin_amdgcn_mfma_f32_16x16x32_bf16(ap[rg], bv, oacc[rg][dt], 0, 0, 0);
                }
            }
        }
    }
    // epilogue
#pragma unroll
    for (int rg = 0; rg < 2; ++rg)
#pragma unroll
        for (int dt = 0; dt < 4; ++dt) {
            const int col = h * HD + dt * 16 + (l & 15);
            const int r0 = n0 + w * 32 + rg * 16 + (l >> 4) * 4;
#pragma unroll
            for (int t2 = 0; t2 < 4; ++t2)
                O[(size_t)(b * NSEQ + r0 + t2) * DM + col] = oacc[rg][dt][t2];
        }
}

// -------- groupnorm stats per (b,h) over N x 64 ----------
__global__ __launch_bounds__(256) void gn_stats(const float* __restrict__ O,
                                                float* __restrict__ stats) {
    const int bh = blockIdx.x;
    const int b = bh >> 4, h = bh & 15;
    const int tid = threadIdx.x;
    float sum = 0.0f, ssq = 0.0f;
    for (int idx = tid; idx < NSEQ * HD; idx += 256) {
        const int n = idx >> 6, d = idx & 63;
        float v = O[((size_t)(b * NSEQ + n) * DM) + h * HD + d];
        sum += v; ssq += v * v;
    }
    __shared__ float rs[256], rq[256];
    rs[tid] = sum; rq[tid] = ssq;
    __syncthreads();
    for (int s = 128; s > 0; s >>= 1) {
        if (tid < s) { rs[tid] += rs[tid + s]; rq[tid] += rq[tid + s]; }
        __syncthreads();
    }
    if (tid == 0) {
        const float inv = 1.0f / (NSEQ * HD);
        float mu = rs[0] * inv;
        float var = rq[0] * inv - mu * mu;
        stats[bh * 2] = mu;
        stats[bh * 2 + 1] = rsqrtf(var + 1e-5f);
    }
}

// -------- fused silu(Gfb) * groupnorm(O) -> Gb (tiled-swizzled bf16) ----------
__global__ __launch_bounds__(256) void gate_kernel(const short* __restrict__ Gfb,
                                                   const float* __restrict__ O,
                                                   const float* __restrict__ stats,
                                                   short* __restrict__ Gb) {
    const size_t i4 = ((size_t)blockIdx.x * 256 + threadIdx.x) * 4;
    const int row = (int)(i4 >> 10);
    const int col = (int)(i4 & 1023);
    const int h = col >> 6;
    const int b = row >> 10;
    const float mu = stats[(b * NH + h) * 2];
    const float rstd = stats[(b * NH + h) * 2 + 1];
    short4 gv = *(const short4*)(Gfb + i4);
    float4 ov = *(const float4*)(O + i4);
    const float gs[4] = {bf2f(gv.x), bf2f(gv.y), bf2f(gv.z), bf2f(gv.w)};
    const float os[4] = {ov.x, ov.y, ov.z, ov.w};
    short o[4];
#pragma unroll
    for (int j = 0; j < 4; ++j) {
        const float g = gs[j];
        const float silu = g / (1.0f + __expf(-g));
        o[j] = f2bf(silu * (os[j] - mu) * rstd);
    }
    const int rt = row >> 7, rloc = row & 127;
    const int kt = col >> 5, kloc = col & 31;
    char* base = (char*)(Gb + ((size_t)rt * 32 + kt) * 4096);
    *(short4*)(base + gswz(rloc, kloc * 2)) = *(short4*)o;
}

extern "C" void kernel_launch(void* const* d_in, const int* in_sizes, int n_in,
                              void* d_out, int out_size, void* d_ws, size_t ws_size,
                              hipStream_t stream) {
    const float* X       = (const float*)d_in[0];
    const float* ts      = (const float*)d_in[1];
    const float* W_qkv   = (const float*)d_in[2];
    const float* W_gamma = (const float*)d_in[3];
    const float* W_gated = (const float*)d_in[4];
    const float* W_out   = (const float*)d_in[5];
    float* out = (float*)d_out;

    char* ws = (char*)d_ws;
    short* qkvb = (short*)ws;                          // 12,582,912 sh (24MB)
    float* logb = (float*)(ws + 25165824);             // 65,536 f32
    float* Oatt = (float*)(ws + 25427968);             // 4,194,304 f32
    float* stats = (float*)(ws + 42205184);            // 128 f32
    short* Xb   = (short*)(ws + 42205696);             // 4,194,304 sh (tiled)
    short* Wtq  = (short*)(ws + 50594304);             // 3,145,728 sh
    short* Wtg  = (short*)(ws + 56885760);             // 1,048,576 sh
    short* Wto  = (short*)(ws + 58982912);             // 1,048,576 sh
    short* Qb   = (short*)(ws + 61080064);             // 4,194,304 sh
    short* Kb   = (short*)(ws + 69468672);             // 4,194,304 sh
    short* Vtb  = (short*)(ws + 77857280);             // 4,194,304 sh
    short* Gfb  = qkvb;                                // alias (dead after prep)
    short* Gb   = Xb;                                  // alias (dead after gemm#2)

    convert_rows<<<dim3(32, 32), 256, 0, stream>>>(X, Xb, 1024);
    tconv<<<dim3(24, 32), 256, 0, stream>>>(W_qkv, Wtq, 1024, 3072);
    tconv<<<dim3(8, 32), 256, 0, stream>>>(W_gated, Wtg, 1024, 1024);
    tconv<<<dim3(8, 32), 256, 0, stream>>>(W_out, Wto, 1024, 1024);

    gemm_tt<true><<<dim3(24, 32), 256, 0, stream>>>(Xb, Wtq, qkvb, 3072);
    gamma_kernel<<<NB * NSEQ, 256, 0, stream>>>(X, W_gamma, logb);
    scan_kernel<<<16, 256, 0, stream>>>(logb);
    prep<<<dim3(16, 64), 256, 0, stream>>>(qkvb, ts, Qb, Kb, Vtb);
    attn2<<<dim3(8, 64), 256, 0, stream>>>(Qb, Kb, Vtb, logb, Oatt);
    gn_stats<<<64, 256, 0, stream>>>(Oatt, stats);
    gemm_tt<true><<<dim3(8, 32), 256, 0, stream>>>(Xb, Wtg, Gfb, 1024);
    gate_kernel<<<4096, 256, 0, stream>>>(Gfb, Oatt, stats, Gb);
    gemm_tt<false><<<dim3(8, 32), 256, 0, stream>>>(Gb, Wto, out, 1024);
}

// Round 6
// 209.389 us; speedup vs baseline: 9.5601x; 1.3629x over previous
//
#include <hip/hip_runtime.h>
#include <cstddef>
#include <cstdint>

#define NH 16
#define HD 64
#define NSEQ 1024
#define NB 4
#define DM 1024
#define SCALE 0.125f   // 64^-0.5

typedef __attribute__((ext_vector_type(8))) short v8s;   // 8 bf16
typedef __attribute__((ext_vector_type(4))) float v4f;   // 4 f32

__device__ __forceinline__ short f2bf(float x) {
    union { float f; unsigned u; } v; v.f = x;
    unsigned r = v.u + 0x7FFF + ((v.u >> 16) & 1);
    return (short)(r >> 16);
}
__device__ __forceinline__ float bf2f(short x) {
    union { unsigned u; float f; } v; v.u = ((unsigned)(unsigned short)x) << 16;
    return v.f;
}
__device__ __forceinline__ void gload16(const void* g, void* l) {
    __builtin_amdgcn_global_load_lds(
        (const __attribute__((address_space(1))) void*)g,
        (__attribute__((address_space(3))) void*)l, 16, 0, 0);
}
// GEMM tile swizzle: 128 rows x 32 k bf16, row = 64B. XOR bits 4-5 with row bits 1-2.
__device__ __forceinline__ int gswz(int r, int kbyte) {
    return (r * 64 + kbyte) ^ (((r >> 1) & 3) << 4);
}
// attn tile swizzle: 64 rows x 64 cols bf16, row = 128B. XOR bits 4-6 with row bits 0-2.
__device__ __forceinline__ int aswz(int r, int byte) {
    return (r * 128 + byte) ^ ((r & 7) << 4);
}

// ---------- X f32 row-major -> Xb bf16 tiled-swizzled [rt][kt][128x32] ----------
__global__ __launch_bounds__(256) void convert_rows(const float* __restrict__ X,
                                                    short* __restrict__ Xb, int K) {
    const int kt = blockIdx.x, rt = blockIdx.y;
    const int t = threadIdx.x;
    const int rloc = t >> 1, kb0 = (t & 1) * 16;   // 16 elements
    const float* src = X + (size_t)(rt * 128 + rloc) * K + kt * 32 + kb0;
    short o[16] __attribute__((aligned(16)));
#pragma unroll
    for (int j = 0; j < 16; j += 4) {
        float4 v = *(const float4*)(src + j);
        o[j] = f2bf(v.x); o[j + 1] = f2bf(v.y); o[j + 2] = f2bf(v.z); o[j + 3] = f2bf(v.w);
    }
    char* base = (char*)(Xb + ((size_t)rt * (K >> 5) + kt) * 4096);
#pragma unroll
    for (int c = 0; c < 2; ++c)
        *(v8s*)(base + gswz(rloc, kb0 * 2 + c * 16)) = *(v8s*)&o[c * 8];
}

// ---------- W f32 [K][N] -> Bt bf16 tiled-swizzled [ct][kt][128x32] (transposed) ----
__global__ __launch_bounds__(256) void tconv(const float* __restrict__ W,
                                             short* __restrict__ Bt,
                                             int K, int N) {
    __shared__ short lsm[32][136];
    const int ct = blockIdx.x, kt = blockIdx.y;
    const int t = threadIdx.x;
    {
        const int kk = t >> 3, nn0 = (t & 7) * 16;
        const float* src = W + (size_t)(kt * 32 + kk) * N + ct * 128 + nn0;
#pragma unroll
        for (int j = 0; j < 16; j += 4) {
            float4 v = *(const float4*)(src + j);
            lsm[kk][nn0 + j] = f2bf(v.x); lsm[kk][nn0 + j + 1] = f2bf(v.y);
            lsm[kk][nn0 + j + 2] = f2bf(v.z); lsm[kk][nn0 + j + 3] = f2bf(v.w);
        }
    }
    __syncthreads();
    const int rloc = t >> 1, kb0 = (t & 1) * 16;
    short o[16] __attribute__((aligned(16)));
#pragma unroll
    for (int j = 0; j < 16; ++j) o[j] = lsm[kb0 + j][rloc];
    char* base = (char*)(Bt + ((size_t)ct * (K >> 5) + kt) * 4096);
#pragma unroll
    for (int c = 0; c < 2; ++c)
        *(v8s*)(base + gswz(rloc, kb0 * 2 + c * 16)) = *(v8s*)&o[c * 8];
}

// ---------- bf16 MFMA GEMM on tiled inputs: C[M][N] = A @ B^T, K=1024 ----------
template<bool BF16OUT>
__global__ __launch_bounds__(256) void gemm_tt(const short* __restrict__ A,
                                               const short* __restrict__ B,
                                               void* __restrict__ C, int N) {
    __shared__ short As[4096];
    __shared__ short Bs[4096];
    const int tid = threadIdx.x;
    const int w = tid >> 6, l = tid & 63;
    const int wr = w >> 1, wc = w & 1;
    const int rt = blockIdx.y, ct = blockIdx.x;
    const char* Abase = (const char*)A + ((size_t)rt * 32) * 8192;
    const char* Bbase = (const char*)B + ((size_t)ct * 32) * 8192;

    v4f acc[4][4];
#pragma unroll
    for (int i = 0; i < 4; ++i)
#pragma unroll
        for (int j = 0; j < 4; ++j) acc[i][j] = (v4f){0.f, 0.f, 0.f, 0.f};

    for (int kt = 0; kt < 32; ++kt) {
        __syncthreads();
#pragma unroll
        for (int i = 0; i < 2; ++i) {
            const int c = w * 2 + i;
            gload16(Abase + (size_t)kt * 8192 + c * 1024 + l * 16, (char*)As + c * 1024);
            gload16(Bbase + (size_t)kt * 8192 + c * 1024 + l * 16, (char*)Bs + c * 1024);
        }
        __syncthreads();
        v8s af[4], bfr[4];
#pragma unroll
        for (int i = 0; i < 4; ++i) {
            const int ra = wr * 64 + i * 16 + (l & 15);
            af[i] = *(const v8s*)((char*)As + gswz(ra, (l >> 4) * 16));
            const int rb = wc * 64 + i * 16 + (l & 15);
            bfr[i] = *(const v8s*)((char*)Bs + gswz(rb, (l >> 4) * 16));
        }
#pragma unroll
        for (int i = 0; i < 4; ++i)
#pragma unroll
            for (int j = 0; j < 4; ++j)
                acc[i][j] = __builtin_amdgcn_mfma_f32_16x16x32_bf16(af[i], bfr[j], acc[i][j], 0, 0, 0);
    }
#pragma unroll
    for (int i = 0; i < 4; ++i)
#pragma unroll
        for (int j = 0; j < 4; ++j) {
            const int r0 = rt * 128 + wr * 64 + i * 16 + (l >> 4) * 4;
            const int cc = ct * 128 + wc * 64 + j * 16 + (l & 15);
#pragma unroll
            for (int t2 = 0; t2 < 4; ++t2) {
                if (BF16OUT) ((short*)C)[(size_t)(r0 + t2) * N + cc] = f2bf(acc[i][j][t2]);
                else         ((float*)C)[(size_t)(r0 + t2) * N + cc] = acc[i][j][t2];
            }
        }
}

// -------- gamma: loggam[row,h] = log(sigmoid(X[row]·Wg[:,h])^(1/20) + 1e-8) ----
__global__ __launch_bounds__(256) void gamma_kernel(const float* __restrict__ X,
                                                    const float* __restrict__ Wg,
                                                    float* __restrict__ loggam) {
    const int row = blockIdx.x;
    const int tid = threadIdx.x;
    const int h = tid & 15;
    const int g = tid >> 4;
    const float* x = X + (size_t)row * DM;
    float sum = 0.0f;
    for (int kk = g; kk < DM; kk += 16) sum += x[kk] * Wg[(size_t)kk * NH + h];
    __shared__ float red[256];
    red[tid] = sum;
    __syncthreads();
    for (int s = 128; s >= 16; s >>= 1) {
        if (tid < s) red[tid] += red[tid + s];
        __syncthreads();
    }
    if (tid < 16) {
        float d = red[tid];
        float sig = 1.0f / (1.0f + expf(-d));
        float gam = powf(sig, 1.0f / 20.0f);
        loggam[(size_t)row * NH + tid] = logf(gam + 1e-8f);
    }
}

// -------- parallel cumsum over n per (b,h) ----------
__global__ __launch_bounds__(256) void scan_kernel(float* __restrict__ lg) {
    const int wave = threadIdx.x >> 6;
    const int lane = threadIdx.x & 63;
    const int bh = blockIdx.x * 4 + wave;
    const int b = bh >> 4, h = bh & 15;
    float* p = lg + (size_t)b * NSEQ * NH + h;
    const int n0 = lane * 16;
    float v[16];
    float s = 0.0f;
#pragma unroll
    for (int j = 0; j < 16; ++j) { v[j] = p[(size_t)(n0 + j) * NH]; s += v[j]; }
    float sc = s;
#pragma unroll
    for (int off = 1; off < 64; off <<= 1) {
        float o = __shfl_up(sc, off, 64);
        if (lane >= off) sc += o;
    }
    float acc = sc - s;
#pragma unroll
    for (int j = 0; j < 16; ++j) { acc += v[j]; p[(size_t)(n0 + j) * NH] = acc; }
}

// ---- prep: qkvb bf16 -> RoPE'd Q/K + V^T as pre-swizzled 64x64 tiles per (bh,nt) ----
__global__ __launch_bounds__(256) void prep(const short* __restrict__ qkvb,
                                            const float* __restrict__ ts,
                                            short* __restrict__ Qb,
                                            short* __restrict__ Kb,
                                            short* __restrict__ Vtb) {
    __shared__ short vsm[64][72];
    const int tile = blockIdx.x, bh = blockIdx.y;
    const int b = bh >> 4, h = bh & 15;
    const int t = threadIdx.x;
    const int rloc = t >> 2, d0 = (t & 3) * 16;
    const int row = b * NSEQ + tile * 64 + rloc;
    const short* src = qkvb + (size_t)row * 3072 + h * HD;
    const size_t tb = ((size_t)bh * 16 + tile) * 4096;   // elements

    float qa[16], ka[16];
    {
        v8s q0 = *(const v8s*)(src + d0), q1 = *(const v8s*)(src + d0 + 8);
        v8s k0 = *(const v8s*)(src + 1024 + d0), k1 = *(const v8s*)(src + 1024 + d0 + 8);
#pragma unroll
        for (int j = 0; j < 8; ++j) {
            qa[j] = bf2f(q0[j]); qa[j + 8] = bf2f(q1[j]);
            ka[j] = bf2f(k0[j]); ka[j + 8] = bf2f(k1[j]);
        }
    }
    const float tv = ts[row];
    short qo[16] __attribute__((aligned(16)));
    short ko[16] __attribute__((aligned(16)));
#pragma unroll
    for (int j = 0; j < 8; ++j) {
        const int i = (d0 >> 1) + j;
        const float inv_freq = exp2f(-0.4152410119f * (float)i);
        const float ang = tv * inv_freq;
        const float s = sinf(ang), c = cosf(ang);
        const float sv = ((float)(2 * i) + 25.6f) * (1.0f / 89.6f);
        const float e = log2f(sv) * tv * (1.0f / 512.0f);
        const float sc = exp2f(e), isc = exp2f(-e);
        qo[2 * j]     = f2bf((qa[2 * j] * c - qa[2 * j + 1] * s) * sc);
        qo[2 * j + 1] = f2bf((qa[2 * j + 1] * c + qa[2 * j] * s) * sc);
        ko[2 * j]     = f2bf((ka[2 * j] * c - ka[2 * j + 1] * s) * isc);
        ko[2 * j + 1] = f2bf((ka[2 * j + 1] * c + ka[2 * j] * s) * isc);
    }
#pragma unroll
    for (int c = 0; c < 2; ++c) {
        *(v8s*)((char*)(Qb + tb) + aswz(rloc, d0 * 2 + c * 16)) = *(v8s*)&qo[c * 8];
        *(v8s*)((char*)(Kb + tb) + aswz(rloc, d0 * 2 + c * 16)) = *(v8s*)&ko[c * 8];
    }
    // V: already bf16, just transpose through LDS
    {
        v8s v0 = *(const v8s*)(src + 2048 + d0), v1 = *(const v8s*)(src + 2048 + d0 + 8);
        *(short4*)&vsm[rloc][d0]      = *(short4*)&v0;
        *(short4*)&vsm[rloc][d0 + 4]  = *((short4*)&v0 + 1);
        *(short4*)&vsm[rloc][d0 + 8]  = *(short4*)&v1;
        *(short4*)&vsm[rloc][d0 + 12] = *((short4*)&v1 + 1);
    }
    __syncthreads();
    {
        const int d = t >> 2, m0 = (t & 3) * 16;
        short vt[16] __attribute__((aligned(16)));
#pragma unroll
        for (int j = 0; j < 16; ++j) vt[j] = vsm[m0 + j][d];
#pragma unroll
        for (int c = 0; c < 2; ++c)
            *(v8s*)((char*)(Vtb + tb) + aswz(d, m0 * 2 + c * 16)) = *(v8s*)&vt[c * 8];
    }
}

// -- attn v2: QBLK=128, Q in regs, K/Vt via global_load_lds, P via LDS,
//    fused groupnorm partial reduction (sum,ssq) per block -> partial[bh*8+blk] --
__global__ __launch_bounds__(256) void attn2(const short* __restrict__ Qb,
                                             const short* __restrict__ Kb,
                                             const short* __restrict__ Vtb,
                                             const float* __restrict__ logb,
                                             float* __restrict__ O,
                                             float* __restrict__ partial) {
    __shared__ short Ks[4096];
    __shared__ short Vts[4096];
    __shared__ short Ps[8192];     // also Q staging at start (16KB)
    __shared__ float lbn[128], lbm[64];
    const int blk = blockIdx.x, bh = blockIdx.y;
    const int b = bh >> 4, h = bh & 15;
    const int tid = threadIdx.x;
    const int w = tid >> 6, l = tid & 63;
    const int n0 = blk * 128;
    const int NT = 2 * blk + 2;

    // stage the two Q tiles (16KB) into Ps
#pragma unroll
    for (int i = 0; i < 4; ++i) {
        const int c = w * 4 + i;
        gload16((const char*)Qb + ((size_t)bh * 16 + 2 * blk) * 8192 + c * 1024 + l * 16,
                (char*)Ps + c * 1024);
    }
    if (tid < 128) lbn[tid] = logb[(size_t)(b * NSEQ + n0 + tid) * NH + h];
    __syncthreads();

    v8s aq[2][2];
#pragma unroll
    for (int rg = 0; rg < 2; ++rg)
#pragma unroll
        for (int kc = 0; kc < 2; ++kc) {
            const int r = w * 32 + rg * 16 + (l & 15);
            aq[rg][kc] = *(const v8s*)((char*)Ps + (r >> 6) * 8192 +
                                       aswz(r & 63, kc * 64 + (l >> 4) * 16));
        }

    v4f oacc[2][4];
#pragma unroll
    for (int rg = 0; rg < 2; ++rg)
#pragma unroll
        for (int dt = 0; dt < 4; ++dt) oacc[rg][dt] = (v4f){0.f, 0.f, 0.f, 0.f};

    for (int mt = 0; mt < NT; ++mt) {
        const int m0 = mt * 64;
        __syncthreads();   // all waves done with prev tile compute (and Q frags read)
#pragma unroll
        for (int i = 0; i < 2; ++i) {
            const int c = w * 2 + i;
            gload16((const char*)Kb + ((size_t)bh * 16 + mt) * 8192 + c * 1024 + l * 16,
                    (char*)Ks + c * 1024);
            gload16((const char*)Vtb + ((size_t)bh * 16 + mt) * 8192 + c * 1024 + l * 16,
                    (char*)Vts + c * 1024);
        }
        if (tid < 64) lbm[tid] = logb[(size_t)(b * NSEQ + m0 + tid) * NH + h];
        __syncthreads();   // staging landed

        const bool active = (m0 <= n0 + w * 32 + 31);
        if (active) {
            // QK^T
            v4f sfr[2][4];
#pragma unroll
            for (int rg = 0; rg < 2; ++rg)
#pragma unroll
                for (int m4 = 0; m4 < 4; ++m4) sfr[rg][m4] = (v4f){0.f, 0.f, 0.f, 0.f};
#pragma unroll
            for (int m4 = 0; m4 < 4; ++m4) {
#pragma unroll
                for (int kc = 0; kc < 2; ++kc) {
                    const int m = m4 * 16 + (l & 15);
                    v8s bk = *(const v8s*)((char*)Ks + aswz(m, kc * 64 + (l >> 4) * 16));
#pragma unroll
                    for (int rg = 0; rg < 2; ++rg)
                        sfr[rg][m4] = __builtin_amdgcn_mfma_f32_16x16x32_bf16(aq[rg][kc], bk, sfr[rg][m4], 0, 0, 0);
                }
            }
            // decay + mask + store P
            const bool needMask = (m0 + 63) > (n0 + w * 32);
#pragma unroll
            for (int rg = 0; rg < 2; ++rg)
#pragma unroll
                for (int m4 = 0; m4 < 4; ++m4) {
                    const int m = m4 * 16 + (l & 15);
                    const float lm = lbm[m];
#pragma unroll
                    for (int t2 = 0; t2 < 4; ++t2) {
                        const int r = w * 32 + rg * 16 + (l >> 4) * 4 + t2;
                        float dec = __expf(fmaxf(lbn[r] - lm, -80.0f));
                        float sval = sfr[rg][m4][t2] * SCALE * dec;
                        if (needMask && (n0 + r) < (m0 + m)) sval = 0.0f;
                        *(short*)((char*)Ps + aswz(r, m * 2)) = f2bf(sval);
                    }
                }
            asm volatile("s_waitcnt lgkmcnt(0)" ::: "memory");
            __builtin_amdgcn_sched_barrier(0);
            // PV
#pragma unroll
            for (int kc = 0; kc < 2; ++kc) {
                v8s ap[2];
#pragma unroll
                for (int rg = 0; rg < 2; ++rg) {
                    const int r = w * 32 + rg * 16 + (l & 15);
                    ap[rg] = *(const v8s*)((char*)Ps + aswz(r, kc * 64 + (l >> 4) * 16));
                }
#pragma unroll
                for (int dt = 0; dt < 4; ++dt) {
                    const int d = dt * 16 + (l & 15);
                    v8s bv = *(const v8s*)((char*)Vts + aswz(d, kc * 64 + (l >> 4) * 16));
#pragma unroll
                    for (int rg = 0; rg < 2; ++rg)
                        oacc[rg][dt] = __builtin_amdgcn_mfma_f32_16x16x32_bf16(ap[rg], bv, oacc[rg][dt], 0, 0, 0);
                }
            }
        }
    }
    // epilogue: write O + fused groupnorm partial reduction
    float psum = 0.0f, pssq = 0.0f;
#pragma unroll
    for (int rg = 0; rg < 2; ++rg)
#pragma unroll
        for (int dt = 0; dt < 4; ++dt) {
            const int col = h * HD + dt * 16 + (l & 15);
            const int r0 = n0 + w * 32 + rg * 16 + (l >> 4) * 4;
#pragma unroll
            for (int t2 = 0; t2 < 4; ++t2) {
                const float v = oacc[rg][dt][t2];
                O[(size_t)(b * NSEQ + r0 + t2) * DM + col] = v;
                psum += v; pssq += v * v;
            }
        }
    __syncthreads();                       // safe to reuse Ks as f32 scratch
    float* red = (float*)Ks;               // 2048 floats available
    red[tid] = psum; red[256 + tid] = pssq;
    __syncthreads();
    for (int s = 128; s > 0; s >>= 1) {
        if (tid < s) { red[tid] += red[tid + s]; red[256 + tid] += red[256 + tid + s]; }
        __syncthreads();
    }
    if (tid == 0) {
        partial[(bh * 8 + blk) * 2]     = red[0];
        partial[(bh * 8 + blk) * 2 + 1] = red[256];
    }
}

// -------- finalize groupnorm stats from 8 partials per (b,h) ----------
__global__ __launch_bounds__(64) void gn_finalize(const float* __restrict__ partial,
                                                  float* __restrict__ stats) {
    const int bh = threadIdx.x;   // 64
    float s = 0.0f, q = 0.0f;
#pragma unroll
    for (int i = 0; i < 8; ++i) {
        s += partial[(bh * 8 + i) * 2];
        q += partial[(bh * 8 + i) * 2 + 1];
    }
    const float inv = 1.0f / (NSEQ * HD);
    const float mu = s * inv;
    const float var = q * inv - mu * mu;
    stats[bh * 2] = mu;
    stats[bh * 2 + 1] = rsqrtf(var + 1e-5f);
}

// -------- fused silu(Gfb) * groupnorm(O) -> Gb (tiled-swizzled bf16) ----------
__global__ __launch_bounds__(256) void gate_kernel(const short* __restrict__ Gfb,
                                                   const float* __restrict__ O,
                                                   const float* __restrict__ stats,
                                                   short* __restrict__ Gb) {
    const size_t i4 = ((size_t)blockIdx.x * 256 + threadIdx.x) * 4;
    const int row = (int)(i4 >> 10);
    const int col = (int)(i4 & 1023);
    const int h = col >> 6;
    const int b = row >> 10;
    const float mu = stats[(b * NH + h) * 2];
    const float rstd = stats[(b * NH + h) * 2 + 1];
    short4 gv = *(const short4*)(Gfb + i4);
    float4 ov = *(const float4*)(O + i4);
    const float gs[4] = {bf2f(gv.x), bf2f(gv.y), bf2f(gv.z), bf2f(gv.w)};
    const float os[4] = {ov.x, ov.y, ov.z, ov.w};
    short o[4];
#pragma unroll
    for (int j = 0; j < 4; ++j) {
        const float g = gs[j];
        const float silu = g / (1.0f + __expf(-g));
        o[j] = f2bf(silu * (os[j] - mu) * rstd);
    }
    const int rt = row >> 7, rloc = row & 127;
    const int kt = col >> 5, kloc = col & 31;
    char* base = (char*)(Gb + ((size_t)rt * 32 + kt) * 4096);
    *(short4*)(base + gswz(rloc, kloc * 2)) = *(short4*)o;
}

extern "C" void kernel_launch(void* const* d_in, const int* in_sizes, int n_in,
                              void* d_out, int out_size, void* d_ws, size_t ws_size,
                              hipStream_t stream) {
    const float* X       = (const float*)d_in[0];
    const float* ts      = (const float*)d_in[1];
    const float* W_qkv   = (const float*)d_in[2];
    const float* W_gamma = (const float*)d_in[3];
    const float* W_gated = (const float*)d_in[4];
    const float* W_out   = (const float*)d_in[5];
    float* out = (float*)d_out;

    char* ws = (char*)d_ws;
    short* qkvb = (short*)ws;                          // 12,582,912 sh (24MB)
    float* logb = (float*)(ws + 25165824);             // 65,536 f32
    float* Oatt = (float*)(ws + 25427968);             // 4,194,304 f32
    float* stats = (float*)(ws + 42205184);            // 128 f32
    short* Xb   = (short*)(ws + 42205696);             // 4,194,304 sh (tiled)
    short* Wtq  = (short*)(ws + 50594304);             // 3,145,728 sh
    short* Wtg  = (short*)(ws + 56885760);             // 1,048,576 sh
    short* Wto  = (short*)(ws + 58982912);             // 1,048,576 sh
    short* Qb   = (short*)(ws + 61080064);             // 4,194,304 sh
    short* Kb   = (short*)(ws + 69468672);             // 4,194,304 sh
    short* Vtb  = (short*)(ws + 77857280);             // 4,194,304 sh
    short* Gfb  = qkvb;                                // alias (dead after prep)
    short* Gb   = Xb;                                  // alias (dead after gemm#2)
    float* partial = (float*)Wtq;                      // alias (Wtq dead after gemm#1)

    convert_rows<<<dim3(32, 32), 256, 0, stream>>>(X, Xb, 1024);
    tconv<<<dim3(24, 32), 256, 0, stream>>>(W_qkv, Wtq, 1024, 3072);
    tconv<<<dim3(8, 32), 256, 0, stream>>>(W_gated, Wtg, 1024, 1024);
    tconv<<<dim3(8, 32), 256, 0, stream>>>(W_out, Wto, 1024, 1024);

    gemm_tt<true><<<dim3(24, 32), 256, 0, stream>>>(Xb, Wtq, qkvb, 3072);
    gamma_kernel<<<NB * NSEQ, 256, 0, stream>>>(X, W_gamma, logb);
    scan_kernel<<<16, 256, 0, stream>>>(logb);
    prep<<<dim3(16, 64), 256, 0, stream>>>(qkvb, ts, Qb, Kb, Vtb);
    attn2<<<dim3(8, 64), 256, 0, stream>>>(Qb, Kb, Vtb, logb, Oatt, partial);
    gn_finalize<<<1, 64, 0, stream>>>(partial, stats);
    gemm_tt<true><<<dim3(8, 32), 256, 0, stream>>>(Xb, Wtg, Gfb, 1024);
    gate_kernel<<<4096, 256, 0, stream>>>(Gfb, Oatt, stats, Gb);
    gemm_tt<false><<<dim3(8, 32), 256, 0, stream>>>(Gb, Wto, out, 1024);
}

// Round 7
// 201.956 us; speedup vs baseline: 9.9120x; 1.0368x over previous
//
#include <hip/hip_runtime.h>
#include <cstddef>
#include <cstdint>

#define NH 16
#define HD 64
#define NSEQ 1024
#define NB 4
#define DM 1024
#define SCALE 0.125f   // 64^-0.5 (folded into prep Q)

typedef __attribute__((ext_vector_type(8))) short v8s;   // 8 bf16
typedef __attribute__((ext_vector_type(4))) float v4f;   // 4 f32

__device__ __forceinline__ short f2bf(float x) {
    union { float f; unsigned u; } v; v.f = x;
    unsigned r = v.u + 0x7FFF + ((v.u >> 16) & 1);
    return (short)(r >> 16);
}
__device__ __forceinline__ float bf2f(short x) {
    union { unsigned u; float f; } v; v.u = ((unsigned)(unsigned short)x) << 16;
    return v.f;
}
__device__ __forceinline__ void gload16(const void* g, void* l) {
    __builtin_amdgcn_global_load_lds(
        (const __attribute__((address_space(1))) void*)g,
        (__attribute__((address_space(3))) void*)l, 16, 0, 0);
}
__device__ __forceinline__ int gswz(int r, int kbyte) {
    return (r * 64 + kbyte) ^ (((r >> 1) & 3) << 4);
}
__device__ __forceinline__ int aswz(int r, int byte) {
    return (r * 128 + byte) ^ ((r & 7) << 4);
}
#define SBAR() __builtin_amdgcn_s_barrier()
#define WAITV0() asm volatile("s_waitcnt vmcnt(0)" ::: "memory")
#define WAITV4() asm volatile("s_waitcnt vmcnt(4)" ::: "memory")
#define WAITL() asm volatile("s_waitcnt lgkmcnt(0)" ::: "memory")

// ---------- X f32 row-major -> Xb bf16 tiled-swizzled [rt][kt][128x32] ----------
__global__ __launch_bounds__(256) void convert_rows(const float* __restrict__ X,
                                                    short* __restrict__ Xb, int K) {
    const int kt = blockIdx.x, rt = blockIdx.y;
    const int t = threadIdx.x;
    const int rloc = t >> 1, kb0 = (t & 1) * 16;
    const float* src = X + (size_t)(rt * 128 + rloc) * K + kt * 32 + kb0;
    short o[16] __attribute__((aligned(16)));
#pragma unroll
    for (int j = 0; j < 16; j += 4) {
        float4 v = *(const float4*)(src + j);
        o[j] = f2bf(v.x); o[j + 1] = f2bf(v.y); o[j + 2] = f2bf(v.z); o[j + 3] = f2bf(v.w);
    }
    char* base = (char*)(Xb + ((size_t)rt * (K >> 5) + kt) * 4096);
#pragma unroll
    for (int c = 0; c < 2; ++c)
        *(v8s*)(base + gswz(rloc, kb0 * 2 + c * 16)) = *(v8s*)&o[c * 8];
}

// ---------- W f32 [K][N] -> Bt bf16 tiled-swizzled [ct][kt][128x32] (transposed) ----
__global__ __launch_bounds__(256) void tconv(const float* __restrict__ W,
                                             short* __restrict__ Bt,
                                             int K, int N) {
    __shared__ short lsm[32][136];
    const int ct = blockIdx.x, kt = blockIdx.y;
    const int t = threadIdx.x;
    {
        const int kk = t >> 3, nn0 = (t & 7) * 16;
        const float* src = W + (size_t)(kt * 32 + kk) * N + ct * 128 + nn0;
#pragma unroll
        for (int j = 0; j < 16; j += 4) {
            float4 v = *(const float4*)(src + j);
            lsm[kk][nn0 + j] = f2bf(v.x); lsm[kk][nn0 + j + 1] = f2bf(v.y);
            lsm[kk][nn0 + j + 2] = f2bf(v.z); lsm[kk][nn0 + j + 3] = f2bf(v.w);
        }
    }
    __syncthreads();
    const int rloc = t >> 1, kb0 = (t & 1) * 16;
    short o[16] __attribute__((aligned(16)));
#pragma unroll
    for (int j = 0; j < 16; ++j) o[j] = lsm[kb0 + j][rloc];
    char* base = (char*)(Bt + ((size_t)ct * (K >> 5) + kt) * 4096);
#pragma unroll
    for (int c = 0; c < 2; ++c)
        *(v8s*)(base + gswz(rloc, kb0 * 2 + c * 16)) = *(v8s*)&o[c * 8];
}

// ---------- bf16 MFMA GEMM on tiled inputs: C[M][N] = A @ B^T, K=1024 ----------
template<bool BF16OUT>
__global__ __launch_bounds__(256) void gemm_tt(const short* __restrict__ A,
                                               const short* __restrict__ B,
                                               void* __restrict__ C, int N) {
    __shared__ short As[4096];
    __shared__ short Bs[4096];
    const int tid = threadIdx.x;
    const int w = tid >> 6, l = tid & 63;
    const int wr = w >> 1, wc = w & 1;
    const int rt = blockIdx.y, ct = blockIdx.x;
    const char* Abase = (const char*)A + ((size_t)rt * 32) * 8192;
    const char* Bbase = (const char*)B + ((size_t)ct * 32) * 8192;

    v4f acc[4][4];
#pragma unroll
    for (int i = 0; i < 4; ++i)
#pragma unroll
        for (int j = 0; j < 4; ++j) acc[i][j] = (v4f){0.f, 0.f, 0.f, 0.f};

    for (int kt = 0; kt < 32; ++kt) {
        __syncthreads();
#pragma unroll
        for (int i = 0; i < 2; ++i) {
            const int c = w * 2 + i;
            gload16(Abase + (size_t)kt * 8192 + c * 1024 + l * 16, (char*)As + c * 1024);
            gload16(Bbase + (size_t)kt * 8192 + c * 1024 + l * 16, (char*)Bs + c * 1024);
        }
        __syncthreads();
        v8s af[4], bfr[4];
#pragma unroll
        for (int i = 0; i < 4; ++i) {
            const int ra = wr * 64 + i * 16 + (l & 15);
            af[i] = *(const v8s*)((char*)As + gswz(ra, (l >> 4) * 16));
            const int rb = wc * 64 + i * 16 + (l & 15);
            bfr[i] = *(const v8s*)((char*)Bs + gswz(rb, (l >> 4) * 16));
        }
#pragma unroll
        for (int i = 0; i < 4; ++i)
#pragma unroll
            for (int j = 0; j < 4; ++j)
                acc[i][j] = __builtin_amdgcn_mfma_f32_16x16x32_bf16(af[i], bfr[j], acc[i][j], 0, 0, 0);
    }
#pragma unroll
    for (int i = 0; i < 4; ++i)
#pragma unroll
        for (int j = 0; j < 4; ++j) {
            const int r0 = rt * 128 + wr * 64 + i * 16 + (l >> 4) * 4;
            const int cc = ct * 128 + wc * 64 + j * 16 + (l & 15);
#pragma unroll
            for (int t2 = 0; t2 < 4; ++t2) {
                if (BF16OUT) ((short*)C)[(size_t)(r0 + t2) * N + cc] = f2bf(acc[i][j][t2]);
                else         ((float*)C)[(size_t)(r0 + t2) * N + cc] = acc[i][j][t2];
            }
        }
}

// -------- gamma: loggam[row,h] = log(sigmoid(X[row]·Wg[:,h])^(1/20) + 1e-8) ----
__global__ __launch_bounds__(256) void gamma_kernel(const float* __restrict__ X,
                                                    const float* __restrict__ Wg,
                                                    float* __restrict__ loggam) {
    const int row = blockIdx.x;
    const int tid = threadIdx.x;
    const int h = tid & 15;
    const int g = tid >> 4;
    const float* x = X + (size_t)row * DM;
    float sum = 0.0f;
    for (int kk = g; kk < DM; kk += 16) sum += x[kk] * Wg[(size_t)kk * NH + h];
    __shared__ float red[256];
    red[tid] = sum;
    __syncthreads();
    for (int s = 128; s >= 16; s >>= 1) {
        if (tid < s) red[tid] += red[tid + s];
        __syncthreads();
    }
    if (tid < 16) {
        float d = red[tid];
        float sig = 1.0f / (1.0f + expf(-d));
        float gam = powf(sig, 1.0f / 20.0f);
        loggam[(size_t)row * NH + tid] = logf(gam + 1e-8f);
    }
}

// -------- parallel cumsum over n per (b,h) ----------
__global__ __launch_bounds__(256) void scan_kernel(float* __restrict__ lg) {
    const int wave = threadIdx.x >> 6;
    const int lane = threadIdx.x & 63;
    const int bh = blockIdx.x * 4 + wave;
    const int b = bh >> 4, h = bh & 15;
    float* p = lg + (size_t)b * NSEQ * NH + h;
    const int n0 = lane * 16;
    float v[16];
    float s = 0.0f;
#pragma unroll
    for (int j = 0; j < 16; ++j) { v[j] = p[(size_t)(n0 + j) * NH]; s += v[j]; }
    float sc = s;
#pragma unroll
    for (int off = 1; off < 64; off <<= 1) {
        float o = __shfl_up(sc, off, 64);
        if (lane >= off) sc += o;
    }
    float acc = sc - s;
#pragma unroll
    for (int j = 0; j < 16; ++j) { acc += v[j]; p[(size_t)(n0 + j) * NH] = acc; }
}

// ---- prep: qkvb bf16 -> RoPE'd Q(*SCALE)/K + V^T as pre-swizzled 64x64 tiles ----
__global__ __launch_bounds__(256) void prep(const short* __restrict__ qkvb,
                                            const float* __restrict__ ts,
                                            short* __restrict__ Qb,
                                            short* __restrict__ Kb,
                                            short* __restrict__ Vtb) {
    __shared__ short vsm[64][72];
    const int tile = blockIdx.x, bh = blockIdx.y;
    const int b = bh >> 4, h = bh & 15;
    const int t = threadIdx.x;
    const int rloc = t >> 2, d0 = (t & 3) * 16;
    const int row = b * NSEQ + tile * 64 + rloc;
    const short* src = qkvb + (size_t)row * 3072 + h * HD;
    const size_t tb = ((size_t)bh * 16 + tile) * 4096;

    float qa[16], ka[16];
    {
        v8s q0 = *(const v8s*)(src + d0), q1 = *(const v8s*)(src + d0 + 8);
        v8s k0 = *(const v8s*)(src + 1024 + d0), k1 = *(const v8s*)(src + 1024 + d0 + 8);
#pragma unroll
        for (int j = 0; j < 8; ++j) {
            qa[j] = bf2f(q0[j]); qa[j + 8] = bf2f(q1[j]);
            ka[j] = bf2f(k0[j]); ka[j + 8] = bf2f(k1[j]);
        }
    }
    const float tv = ts[row];
    short qo[16] __attribute__((aligned(16)));
    short ko[16] __attribute__((aligned(16)));
#pragma unroll
    for (int j = 0; j < 8; ++j) {
        const int i = (d0 >> 1) + j;
        const float inv_freq = exp2f(-0.4152410119f * (float)i);
        const float ang = tv * inv_freq;
        const float s = sinf(ang), c = cosf(ang);
        const float sv = ((float)(2 * i) + 25.6f) * (1.0f / 89.6f);
        const float e = log2f(sv) * tv * (1.0f / 512.0f);
        const float sc = exp2f(e) * SCALE, isc = exp2f(-e);
        qo[2 * j]     = f2bf((qa[2 * j] * c - qa[2 * j + 1] * s) * sc);
        qo[2 * j + 1] = f2bf((qa[2 * j + 1] * c + qa[2 * j] * s) * sc);
        ko[2 * j]     = f2bf((ka[2 * j] * c - ka[2 * j + 1] * s) * isc);
        ko[2 * j + 1] = f2bf((ka[2 * j + 1] * c + ka[2 * j] * s) * isc);
    }
#pragma unroll
    for (int c = 0; c < 2; ++c) {
        *(v8s*)((char*)(Qb + tb) + aswz(rloc, d0 * 2 + c * 16)) = *(v8s*)&qo[c * 8];
        *(v8s*)((char*)(Kb + tb) + aswz(rloc, d0 * 2 + c * 16)) = *(v8s*)&ko[c * 8];
    }
    {
        v8s v0 = *(const v8s*)(src + 2048 + d0), v1 = *(const v8s*)(src + 2048 + d0 + 8);
        *(short4*)&vsm[rloc][d0]      = *(short4*)&v0;
        *(short4*)&vsm[rloc][d0 + 4]  = *((short4*)&v0 + 1);
        *(short4*)&vsm[rloc][d0 + 8]  = *(short4*)&v1;
        *(short4*)&vsm[rloc][d0 + 12] = *((short4*)&v1 + 1);
    }
    __syncthreads();
    {
        const int d = t >> 2, m0 = (t & 3) * 16;
        short vt[16] __attribute__((aligned(16)));
#pragma unroll
        for (int j = 0; j < 16; ++j) vt[j] = vsm[m0 + j][d];
#pragma unroll
        for (int c = 0; c < 2; ++c)
            *(v8s*)((char*)(Vtb + tb) + aswz(d, m0 * 2 + c * 16)) = *(v8s*)&vt[c * 8];
    }
}

// -- attn v3: balanced q-block pairing (qa=blk+4, qb=3-blk), K/V double-buffer with
//    counted vmcnt, factorized decay en[r]*em[m], fused groupnorm partials --
__global__ __launch_bounds__(256) void attn3(const short* __restrict__ Qb,
                                             const short* __restrict__ Kb,
                                             const short* __restrict__ Vtb,
                                             const float* __restrict__ logb,
                                             float* __restrict__ O,
                                             float* __restrict__ partial) {
    __shared__ short Ks[2][4096];
    __shared__ short Vts[2][4096];
    __shared__ short Ps[8192];       // P tiles; also Q staging per job (16KB)
    __shared__ float lbAll[1024];
    __shared__ float emAll[1024];
    const int id = blockIdx.x;
    const int bh = ((id & 7) << 3) | ((id >> 3) & 7);   // XCD-local bh groups
    const int blk = id >> 6;                            // 0..3
    const int b = bh >> 4, h = bh & 15;
    const int tid = threadIdx.x;
    const int w = tid >> 6, l = tid & 63;

    float psum = 0.0f, pssq = 0.0f;

    for (int job = 0; job < 2; ++job) {
        const int qq = (job == 0) ? (blk + 4) : (3 - blk);
        const int n0 = qq * 128;
        const int NT = 2 * qq + 2;

        SBAR();   // Ps free (prev job's PV reads done)
        // stage Q tiles (16KB) into Ps
#pragma unroll
        for (int i = 0; i < 4; ++i) {
            const int c = w * 4 + i;
            gload16((const char*)Qb + ((size_t)bh * 16 + 2 * qq) * 8192 + c * 1024 + l * 16,
                    (char*)Ps + c * 1024);
        }
        if (job == 0) {
            for (int i = tid; i < 1024; i += 256)
                lbAll[i] = logb[(size_t)(b * NSEQ + i) * NH + h];
        }
        WAITV0(); WAITL();
        SBAR();

        const float base = lbAll[n0];
        for (int i = tid; i < NT * 64; i += 256) emAll[i] = __expf(base - lbAll[i]);
        float en[2][4];
#pragma unroll
        for (int rg = 0; rg < 2; ++rg)
#pragma unroll
            for (int t2 = 0; t2 < 4; ++t2)
                en[rg][t2] = __expf(lbAll[n0 + w * 32 + rg * 16 + (l >> 4) * 4 + t2] - base);
        v8s aq[2][2];
#pragma unroll
        for (int rg = 0; rg < 2; ++rg)
#pragma unroll
            for (int kc = 0; kc < 2; ++kc) {
                const int r = w * 32 + rg * 16 + (l & 15);
                aq[rg][kc] = *(const v8s*)((char*)Ps + (r >> 6) * 8192 +
                                           aswz(r & 63, kc * 64 + (l >> 4) * 16));
            }
        WAITL();
        SBAR();   // emAll visible; Ps free for P use

        v4f oacc[2][4];
#pragma unroll
        for (int rg = 0; rg < 2; ++rg)
#pragma unroll
            for (int dt = 0; dt < 4; ++dt) oacc[rg][dt] = (v4f){0.f, 0.f, 0.f, 0.f};

        // prefetch tile 0
#pragma unroll
        for (int i = 0; i < 2; ++i) {
            const int c = w * 2 + i;
            gload16((const char*)Kb + ((size_t)bh * 16 + 0) * 8192 + c * 1024 + l * 16,
                    (char*)Ks + c * 1024);
            gload16((const char*)Vtb + ((size_t)bh * 16 + 0) * 8192 + c * 1024 + l * 16,
                    (char*)Vts + c * 1024);
        }

        for (int t = 0; t < NT; ++t) {
            const int m0 = t * 64;
            const int buf = t & 1;
            SBAR();   // all waves done reading buf^1
            if (t + 1 < NT) {
                const int nb = (t + 1) & 1;
#pragma unroll
                for (int i = 0; i < 2; ++i) {
                    const int c = w * 2 + i;
                    gload16((const char*)Kb + ((size_t)bh * 16 + t + 1) * 8192 + c * 1024 + l * 16,
                            (char*)Ks + nb * 8192 + c * 1024);
                    gload16((const char*)Vtb + ((size_t)bh * 16 + t + 1) * 8192 + c * 1024 + l * 16,
                            (char*)Vts + nb * 8192 + c * 1024);
                }
                WAITV4();
            } else {
                WAITV0();
            }
            SBAR();   // tile t fully in LDS (t+1 still in flight)

            const bool active = (m0 <= n0 + w * 32 + 31);
            if (active) {
                const char* KsB = (const char*)Ks + buf * 8192;
                const char* VtsB = (const char*)Vts + buf * 8192;
                // QK^T
                v4f sfr[2][4];
#pragma unroll
                for (int rg = 0; rg < 2; ++rg)
#pragma unroll
                    for (int m4 = 0; m4 < 4; ++m4) sfr[rg][m4] = (v4f){0.f, 0.f, 0.f, 0.f};
#pragma unroll
                for (int m4 = 0; m4 < 4; ++m4) {
#pragma unroll
                    for (int kc = 0; kc < 2; ++kc) {
                        const int m = m4 * 16 + (l & 15);
                        v8s bk = *(const v8s*)(KsB + aswz(m, kc * 64 + (l >> 4) * 16));
#pragma unroll
                        for (int rg = 0; rg < 2; ++rg)
                            sfr[rg][m4] = __builtin_amdgcn_mfma_f32_16x16x32_bf16(aq[rg][kc], bk, sfr[rg][m4], 0, 0, 0);
                    }
                }
                // decay (factorized) + mask + store P
                const bool needMask = (m0 + 63) > (n0 + w * 32);
                float emv[4];
#pragma unroll
                for (int m4 = 0; m4 < 4; ++m4) emv[m4] = emAll[m0 + m4 * 16 + (l & 15)];
#pragma unroll
                for (int rg = 0; rg < 2; ++rg)
#pragma unroll
                    for (int m4 = 0; m4 < 4; ++m4) {
                        const int m = m4 * 16 + (l & 15);
#pragma unroll
                        for (int t2 = 0; t2 < 4; ++t2) {
                            const int r = w * 32 + rg * 16 + (l >> 4) * 4 + t2;
                            float sval = sfr[rg][m4][t2] * en[rg][t2] * emv[m4];
                            if (needMask && (n0 + r) < (m0 + m)) sval = 0.0f;
                            *(short*)((char*)Ps + aswz(r, m * 2)) = f2bf(sval);
                        }
                    }
                WAITL();
                __builtin_amdgcn_sched_barrier(0);
                // PV
#pragma unroll
                for (int kc = 0; kc < 2; ++kc) {
                    v8s ap[2];
#pragma unroll
                    for (int rg = 0; rg < 2; ++rg) {
                        const int r = w * 32 + rg * 16 + (l & 15);
                        ap[rg] = *(const v8s*)((char*)Ps + aswz(r, kc * 64 + (l >> 4) * 16));
                    }
#pragma unroll
                    for (int dt = 0; dt < 4; ++dt) {
                        const int d = dt * 16 + (l & 15);
                        v8s bv = *(const v8s*)(VtsB + aswz(d, kc * 64 + (l >> 4) * 16));
#pragma unroll
                        for (int rg = 0; rg < 2; ++rg)
                            oacc[rg][dt] = __builtin_amdgcn_mfma_f32_16x16x32_bf16(ap[rg], bv, oacc[rg][dt], 0, 0, 0);
                    }
                }
            }
        }
        // job epilogue: write O + accumulate groupnorm partials
#pragma unroll
        for (int rg = 0; rg < 2; ++rg)
#pragma unroll
            for (int dt = 0; dt < 4; ++dt) {
                const int col = h * HD + dt * 16 + (l & 15);
                const int r0 = n0 + w * 32 + rg * 16 + (l >> 4) * 4;
#pragma unroll
                for (int t2 = 0; t2 < 4; ++t2) {
                    const float v = oacc[rg][dt][t2];
                    O[(size_t)(b * NSEQ + r0 + t2) * DM + col] = v;
                    psum += v; pssq += v * v;
                }
            }
    }
    // block reduction (Ks scratch is free after final barrier)
    __syncthreads();
    float* red = (float*)Ks;
    red[tid] = psum; red[256 + tid] = pssq;
    __syncthreads();
    for (int s = 128; s > 0; s >>= 1) {
        if (tid < s) { red[tid] += red[tid + s]; red[256 + tid] += red[256 + tid + s]; }
        __syncthreads();
    }
    if (tid == 0) {
        partial[(bh * 4 + blk) * 2]     = red[0];
        partial[(bh * 4 + blk) * 2 + 1] = red[256];
    }
}

// -------- finalize groupnorm stats from 4 partials per (b,h) ----------
__global__ __launch_bounds__(64) void gn_finalize(const float* __restrict__ partial,
                                                  float* __restrict__ stats) {
    const int bh = threadIdx.x;
    float s = 0.0f, q = 0.0f;
#pragma unroll
    for (int i = 0; i < 4; ++i) {
        s += partial[(bh * 4 + i) * 2];
        q += partial[(bh * 4 + i) * 2 + 1];
    }
    const float inv = 1.0f / (NSEQ * HD);
    const float mu = s * inv;
    const float var = q * inv - mu * mu;
    stats[bh * 2] = mu;
    stats[bh * 2 + 1] = rsqrtf(var + 1e-5f);
}

// -------- fused silu(Gfb) * groupnorm(O) -> Gb (tiled-swizzled bf16) ----------
__global__ __launch_bounds__(256) void gate_kernel(const short* __restrict__ Gfb,
                                                   const float* __restrict__ O,
                                                   const float* __restrict__ stats,
                                                   short* __restrict__ Gb) {
    const size_t i4 = ((size_t)blockIdx.x * 256 + threadIdx.x) * 4;
    const int row = (int)(i4 >> 10);
    const int col = (int)(i4 & 1023);
    const int h = col >> 6;
    const int b = row >> 10;
    const float mu = stats[(b * NH + h) * 2];
    const float rstd = stats[(b * NH + h) * 2 + 1];
    short4 gv = *(const short4*)(Gfb + i4);
    float4 ov = *(const float4*)(O + i4);
    const float gs[4] = {bf2f(gv.x), bf2f(gv.y), bf2f(gv.z), bf2f(gv.w)};
    const float os[4] = {ov.x, ov.y, ov.z, ov.w};
    short o[4];
#pragma unroll
    for (int j = 0; j < 4; ++j) {
        const float g = gs[j];
        const float silu = g / (1.0f + __expf(-g));
        o[j] = f2bf(silu * (os[j] - mu) * rstd);
    }
    const int rt = row >> 7, rloc = row & 127;
    const int kt = col >> 5, kloc = col & 31;
    char* base = (char*)(Gb + ((size_t)rt * 32 + kt) * 4096);
    *(short4*)(base + gswz(rloc, kloc * 2)) = *(short4*)o;
}

extern "C" void kernel_launch(void* const* d_in, const int* in_sizes, int n_in,
                              void* d_out, int out_size, void* d_ws, size_t ws_size,
                              hipStream_t stream) {
    const float* X       = (const float*)d_in[0];
    const float* ts      = (const float*)d_in[1];
    const float* W_qkv   = (const float*)d_in[2];
    const float* W_gamma = (const float*)d_in[3];
    const float* W_gated = (const float*)d_in[4];
    const float* W_out   = (const float*)d_in[5];
    float* out = (float*)d_out;

    char* ws = (char*)d_ws;
    short* qkvb = (short*)ws;                          // 12,582,912 sh (24MB)
    float* logb = (float*)(ws + 25165824);             // 65,536 f32
    float* Oatt = (float*)(ws + 25427968);             // 4,194,304 f32
    float* stats = (float*)(ws + 42205184);            // 128 f32
    short* Xb   = (short*)(ws + 42205696);             // 4,194,304 sh (tiled)
    short* Wtq  = (short*)(ws + 50594304);             // 3,145,728 sh
    short* Wtg  = (short*)(ws + 56885760);             // 1,048,576 sh
    short* Wto  = (short*)(ws + 58982912);             // 1,048,576 sh
    short* Qb   = (short*)(ws + 61080064);             // 4,194,304 sh
    short* Kb   = (short*)(ws + 69468672);             // 4,194,304 sh
    short* Vtb  = (short*)(ws + 77857280);             // 4,194,304 sh
    short* Gfb  = qkvb;                                // alias (dead after prep)
    short* Gb   = Xb;                                  // alias (dead after gemm#2)
    float* partial = (float*)Wtq;                      // alias (Wtq dead after gemm#1)

    convert_rows<<<dim3(32, 32), 256, 0, stream>>>(X, Xb, 1024);
    tconv<<<dim3(24, 32), 256, 0, stream>>>(W_qkv, Wtq, 1024, 3072);
    tconv<<<dim3(8, 32), 256, 0, stream>>>(W_gated, Wtg, 1024, 1024);
    tconv<<<dim3(8, 32), 256, 0, stream>>>(W_out, Wto, 1024, 1024);

    gemm_tt<true><<<dim3(24, 32), 256, 0, stream>>>(Xb, Wtq, qkvb, 3072);
    gamma_kernel<<<NB * NSEQ, 256, 0, stream>>>(X, W_gamma, logb);
    scan_kernel<<<16, 256, 0, stream>>>(logb);
    prep<<<dim3(16, 64), 256, 0, stream>>>(qkvb, ts, Qb, Kb, Vtb);
    attn3<<<256, 256, 0, stream>>>(Qb, Kb, Vtb, logb, Oatt, partial);
    gn_finalize<<<1, 64, 0, stream>>>(partial, stats);
    gemm_tt<true><<<dim3(8, 32), 256, 0, stream>>>(Xb, Wtg, Gfb, 1024);
    gate_kernel<<<4096, 256, 0, stream>>>(Gfb, Oatt, stats, Gb);
    gemm_tt<false><<<dim3(8, 32), 256, 0, stream>>>(Gb, Wto, out, 1024);
}

// Round 8
// 173.672 us; speedup vs baseline: 11.5262x; 1.1629x over previous
//
#include <hip/hip_runtime.h>
#include <cstddef>
#include <cstdint>

#define NH 16
#define HD 64
#define NSEQ 1024
#define NB 4
#define DM 1024
#define SCALE 0.125f   // 64^-0.5 (folded into prep Q)

typedef __attribute__((ext_vector_type(8))) short v8s;   // 8 bf16
typedef __attribute__((ext_vector_type(4))) float v4f;   // 4 f32

__device__ __forceinline__ short f2bf(float x) {
    union { float f; unsigned u; } v; v.f = x;
    unsigned r = v.u + 0x7FFF + ((v.u >> 16) & 1);
    return (short)(r >> 16);
}
__device__ __forceinline__ float bf2f(short x) {
    union { unsigned u; float f; } v; v.u = ((unsigned)(unsigned short)x) << 16;
    return v.f;
}
__device__ __forceinline__ void gload16(const void* g, void* l) {
    __builtin_amdgcn_global_load_lds(
        (const __attribute__((address_space(1))) void*)g,
        (__attribute__((address_space(3))) void*)l, 16, 0, 0);
}
__device__ __forceinline__ int gswz(int r, int kbyte) {
    return (r * 64 + kbyte) ^ (((r >> 1) & 3) << 4);
}
__device__ __forceinline__ int aswz(int r, int byte) {
    return (r * 128 + byte) ^ ((r & 7) << 4);
}
#define SBAR() __builtin_amdgcn_s_barrier()
#define WAITV0() asm volatile("s_waitcnt vmcnt(0)" ::: "memory")
#define WAITV4() asm volatile("s_waitcnt vmcnt(4)" ::: "memory")
#define WAITL() asm volatile("s_waitcnt lgkmcnt(0)" ::: "memory")

// ---------- X f32 row-major -> Xb bf16 tiled-swizzled [rt][kt][128x32] ----------
__global__ __launch_bounds__(256) void convert_rows(const float* __restrict__ X,
                                                    short* __restrict__ Xb, int K) {
    const int kt = blockIdx.x, rt = blockIdx.y;
    const int t = threadIdx.x;
    const int rloc = t >> 1, kb0 = (t & 1) * 16;
    const float* src = X + (size_t)(rt * 128 + rloc) * K + kt * 32 + kb0;
    short o[16] __attribute__((aligned(16)));
#pragma unroll
    for (int j = 0; j < 16; j += 4) {
        float4 v = *(const float4*)(src + j);
        o[j] = f2bf(v.x); o[j + 1] = f2bf(v.y); o[j + 2] = f2bf(v.z); o[j + 3] = f2bf(v.w);
    }
    char* base = (char*)(Xb + ((size_t)rt * (K >> 5) + kt) * 4096);
#pragma unroll
    for (int c = 0; c < 2; ++c)
        *(v8s*)(base + gswz(rloc, kb0 * 2 + c * 16)) = *(v8s*)&o[c * 8];
}

// ---------- W f32 [K][N] -> Bt bf16 tiled-swizzled [ct][kt][128x32] (transposed) ----
__global__ __launch_bounds__(256) void tconv(const float* __restrict__ W,
                                             short* __restrict__ Bt,
                                             int K, int N) {
    __shared__ short lsm[32][136];
    const int ct = blockIdx.x, kt = blockIdx.y;
    const int t = threadIdx.x;
    {
        const int kk = t >> 3, nn0 = (t & 7) * 16;
        const float* src = W + (size_t)(kt * 32 + kk) * N + ct * 128 + nn0;
#pragma unroll
        for (int j = 0; j < 16; j += 4) {
            float4 v = *(const float4*)(src + j);
            lsm[kk][nn0 + j] = f2bf(v.x); lsm[kk][nn0 + j + 1] = f2bf(v.y);
            lsm[kk][nn0 + j + 2] = f2bf(v.z); lsm[kk][nn0 + j + 3] = f2bf(v.w);
        }
    }
    __syncthreads();
    const int rloc = t >> 1, kb0 = (t & 1) * 16;
    short o[16] __attribute__((aligned(16)));
#pragma unroll
    for (int j = 0; j < 16; ++j) o[j] = lsm[kb0 + j][rloc];
    char* base = (char*)(Bt + ((size_t)ct * (K >> 5) + kt) * 4096);
#pragma unroll
    for (int c = 0; c < 2; ++c)
        *(v8s*)(base + gswz(rloc, kb0 * 2 + c * 16)) = *(v8s*)&o[c * 8];
}

// ---------- bf16 MFMA GEMM on tiled inputs: C[M][N] = A @ B^T, K=1024 ----------
template<bool BF16OUT>
__global__ __launch_bounds__(256) void gemm_tt(const short* __restrict__ A,
                                               const short* __restrict__ B,
                                               void* __restrict__ C, int N) {
    __shared__ short As[4096];
    __shared__ short Bs[4096];
    const int tid = threadIdx.x;
    const int w = tid >> 6, l = tid & 63;
    const int wr = w >> 1, wc = w & 1;
    const int rt = blockIdx.y, ct = blockIdx.x;
    const char* Abase = (const char*)A + ((size_t)rt * 32) * 8192;
    const char* Bbase = (const char*)B + ((size_t)ct * 32) * 8192;

    v4f acc[4][4];
#pragma unroll
    for (int i = 0; i < 4; ++i)
#pragma unroll
        for (int j = 0; j < 4; ++j) acc[i][j] = (v4f){0.f, 0.f, 0.f, 0.f};

    for (int kt = 0; kt < 32; ++kt) {
        __syncthreads();
#pragma unroll
        for (int i = 0; i < 2; ++i) {
            const int c = w * 2 + i;
            gload16(Abase + (size_t)kt * 8192 + c * 1024 + l * 16, (char*)As + c * 1024);
            gload16(Bbase + (size_t)kt * 8192 + c * 1024 + l * 16, (char*)Bs + c * 1024);
        }
        __syncthreads();
        v8s af[4], bfr[4];
#pragma unroll
        for (int i = 0; i < 4; ++i) {
            const int ra = wr * 64 + i * 16 + (l & 15);
            af[i] = *(const v8s*)((char*)As + gswz(ra, (l >> 4) * 16));
            const int rb = wc * 64 + i * 16 + (l & 15);
            bfr[i] = *(const v8s*)((char*)Bs + gswz(rb, (l >> 4) * 16));
        }
#pragma unroll
        for (int i = 0; i < 4; ++i)
#pragma unroll
            for (int j = 0; j < 4; ++j)
                acc[i][j] = __builtin_amdgcn_mfma_f32_16x16x32_bf16(af[i], bfr[j], acc[i][j], 0, 0, 0);
    }
#pragma unroll
    for (int i = 0; i < 4; ++i)
#pragma unroll
        for (int j = 0; j < 4; ++j) {
            const int r0 = rt * 128 + wr * 64 + i * 16 + (l >> 4) * 4;
            const int cc = ct * 128 + wc * 64 + j * 16 + (l & 15);
#pragma unroll
            for (int t2 = 0; t2 < 4; ++t2) {
                if (BF16OUT) ((short*)C)[(size_t)(r0 + t2) * N + cc] = f2bf(acc[i][j][t2]);
                else         ((float*)C)[(size_t)(r0 + t2) * N + cc] = acc[i][j][t2];
            }
        }
}

// -------- gamma2: loggam[row,h] = log(sigmoid(X[row]·Wg[:,h])^(1/20) + 1e-8) ----
// 256 blocks x 16 rows. Wg staged in LDS (stride 17), float4 X loads,
// register accumulators, shfl-xor reduction. Same math fns as before.
__global__ __launch_bounds__(256) void gamma2(const float* __restrict__ X,
                                              const float* __restrict__ Wg,
                                              float* __restrict__ loggam) {
    __shared__ float wgs[1024 * 17];
    const int tid = threadIdx.x;
    // stage Wg [1024][16] -> wgs[k*17+h]
#pragma unroll
    for (int it = 0; it < 16; ++it) {
        const int idx = it * 1024 + tid * 4;
        float4 v = *(const float4*)(Wg + idx);
        const int k = idx >> 4, h0 = idx & 15;
        wgs[k * 17 + h0]     = v.x;
        wgs[k * 17 + h0 + 1] = v.y;
        wgs[k * 17 + h0 + 2] = v.z;
        wgs[k * 17 + h0 + 3] = v.w;
    }
    __syncthreads();

    const int r = tid >> 4, c = tid & 15;
    const int row = blockIdx.x * 16 + r;
    const float* xrow = X + (size_t)row * DM;
    float acc[16];
#pragma unroll
    for (int h = 0; h < 16; ++h) acc[h] = 0.0f;
#pragma unroll 4
    for (int i = 0; i < 16; ++i) {
        const int kb = i * 64 + c * 4;
        float4 xv = *(const float4*)(xrow + kb);
        const float xs[4] = {xv.x, xv.y, xv.z, xv.w};
#pragma unroll
        for (int j = 0; j < 4; ++j) {
            const float* wrow = &wgs[(kb + j) * 17];
#pragma unroll
            for (int h = 0; h < 16; ++h) acc[h] = fmaf(xs[j], wrow[h], acc[h]);
        }
    }
    // reduce across the 16 lanes (c) of each row group
#pragma unroll
    for (int h = 0; h < 16; ++h) {
#pragma unroll
        for (int off = 8; off >= 1; off >>= 1)
            acc[h] += __shfl_xor(acc[h], off, 16);
    }
    // lane c outputs head h == c
    const float d = acc[c];
    const float sig = 1.0f / (1.0f + expf(-d));
    const float gam = powf(sig, 1.0f / 20.0f);
    loggam[(size_t)row * NH + c] = logf(gam + 1e-8f);
}

// -------- parallel cumsum over n per (b,h) ----------
__global__ __launch_bounds__(256) void scan_kernel(float* __restrict__ lg) {
    const int wave = threadIdx.x >> 6;
    const int lane = threadIdx.x & 63;
    const int bh = blockIdx.x * 4 + wave;
    const int b = bh >> 4, h = bh & 15;
    float* p = lg + (size_t)b * NSEQ * NH + h;
    const int n0 = lane * 16;
    float v[16];
    float s = 0.0f;
#pragma unroll
    for (int j = 0; j < 16; ++j) { v[j] = p[(size_t)(n0 + j) * NH]; s += v[j]; }
    float sc = s;
#pragma unroll
    for (int off = 1; off < 64; off <<= 1) {
        float o = __shfl_up(sc, off, 64);
        if (lane >= off) sc += o;
    }
    float acc = sc - s;
#pragma unroll
    for (int j = 0; j < 16; ++j) { acc += v[j]; p[(size_t)(n0 + j) * NH] = acc; }
}

// ---- prep: qkvb bf16 -> RoPE'd Q(*SCALE)/K + V^T as pre-swizzled 64x64 tiles ----
__global__ __launch_bounds__(256) void prep(const short* __restrict__ qkvb,
                                            const float* __restrict__ ts,
                                            short* __restrict__ Qb,
                                            short* __restrict__ Kb,
                                            short* __restrict__ Vtb) {
    __shared__ short vsm[64][72];
    const int tile = blockIdx.x, bh = blockIdx.y;
    const int b = bh >> 4, h = bh & 15;
    const int t = threadIdx.x;
    const int rloc = t >> 2, d0 = (t & 3) * 16;
    const int row = b * NSEQ + tile * 64 + rloc;
    const short* src = qkvb + (size_t)row * 3072 + h * HD;
    const size_t tb = ((size_t)bh * 16 + tile) * 4096;

    float qa[16], ka[16];
    {
        v8s q0 = *(const v8s*)(src + d0), q1 = *(const v8s*)(src + d0 + 8);
        v8s k0 = *(const v8s*)(src + 1024 + d0), k1 = *(const v8s*)(src + 1024 + d0 + 8);
#pragma unroll
        for (int j = 0; j < 8; ++j) {
            qa[j] = bf2f(q0[j]); qa[j + 8] = bf2f(q1[j]);
            ka[j] = bf2f(k0[j]); ka[j + 8] = bf2f(k1[j]);
        }
    }
    const float tv = ts[row];
    short qo[16] __attribute__((aligned(16)));
    short ko[16] __attribute__((aligned(16)));
#pragma unroll
    for (int j = 0; j < 8; ++j) {
        const int i = (d0 >> 1) + j;
        const float inv_freq = exp2f(-0.4152410119f * (float)i);
        const float ang = tv * inv_freq;
        const float s = sinf(ang), c = cosf(ang);
        const float sv = ((float)(2 * i) + 25.6f) * (1.0f / 89.6f);
        const float e = log2f(sv) * tv * (1.0f / 512.0f);
        const float sc = exp2f(e) * SCALE, isc = exp2f(-e);
        qo[2 * j]     = f2bf((qa[2 * j] * c - qa[2 * j + 1] * s) * sc);
        qo[2 * j + 1] = f2bf((qa[2 * j + 1] * c + qa[2 * j] * s) * sc);
        ko[2 * j]     = f2bf((ka[2 * j] * c - ka[2 * j + 1] * s) * isc);
        ko[2 * j + 1] = f2bf((ka[2 * j + 1] * c + ka[2 * j] * s) * isc);
    }
#pragma unroll
    for (int c = 0; c < 2; ++c) {
        *(v8s*)((char*)(Qb + tb) + aswz(rloc, d0 * 2 + c * 16)) = *(v8s*)&qo[c * 8];
        *(v8s*)((char*)(Kb + tb) + aswz(rloc, d0 * 2 + c * 16)) = *(v8s*)&ko[c * 8];
    }
    {
        v8s v0 = *(const v8s*)(src + 2048 + d0), v1 = *(const v8s*)(src + 2048 + d0 + 8);
        *(short4*)&vsm[rloc][d0]      = *(short4*)&v0;
        *(short4*)&vsm[rloc][d0 + 4]  = *((short4*)&v0 + 1);
        *(short4*)&vsm[rloc][d0 + 8]  = *(short4*)&v1;
        *(short4*)&vsm[rloc][d0 + 12] = *((short4*)&v1 + 1);
    }
    __syncthreads();
    {
        const int d = t >> 2, m0 = (t & 3) * 16;
        short vt[16] __attribute__((aligned(16)));
#pragma unroll
        for (int j = 0; j < 16; ++j) vt[j] = vsm[m0 + j][d];
#pragma unroll
        for (int c = 0; c < 2; ++c)
            *(v8s*)((char*)(Vtb + tb) + aswz(d, m0 * 2 + c * 16)) = *(v8s*)&vt[c * 8];
    }
}

// -- attn v3: balanced q-block pairing (qa=blk+4, qb=3-blk), K/V double-buffer with
//    counted vmcnt, factorized decay en[r]*em[m], fused groupnorm partials --
__global__ __launch_bounds__(256) void attn3(const short* __restrict__ Qb,
                                             const short* __restrict__ Kb,
                                             const short* __restrict__ Vtb,
                                             const float* __restrict__ logb,
                                             float* __restrict__ O,
                                             float* __restrict__ partial) {
    __shared__ short Ks[2][4096];
    __shared__ short Vts[2][4096];
    __shared__ short Ps[8192];       // P tiles; also Q staging per job (16KB)
    __shared__ float lbAll[1024];
    __shared__ float emAll[1024];
    const int id = blockIdx.x;
    const int bh = ((id & 7) << 3) | ((id >> 3) & 7);   // XCD-local bh groups
    const int blk = id >> 6;                            // 0..3
    const int b = bh >> 4, h = bh & 15;
    const int tid = threadIdx.x;
    const int w = tid >> 6, l = tid & 63;

    float psum = 0.0f, pssq = 0.0f;

    for (int job = 0; job < 2; ++job) {
        const int qq = (job == 0) ? (blk + 4) : (3 - blk);
        const int n0 = qq * 128;
        const int NT = 2 * qq + 2;

        SBAR();   // Ps free (prev job's PV reads done)
        // stage Q tiles (16KB) into Ps
#pragma unroll
        for (int i = 0; i < 4; ++i) {
            const int c = w * 4 + i;
            gload16((const char*)Qb + ((size_t)bh * 16 + 2 * qq) * 8192 + c * 1024 + l * 16,
                    (char*)Ps + c * 1024);
        }
        if (job == 0) {
            for (int i = tid; i < 1024; i += 256)
                lbAll[i] = logb[(size_t)(b * NSEQ + i) * NH + h];
        }
        WAITV0(); WAITL();
        SBAR();

        const float base = lbAll[n0];
        for (int i = tid; i < NT * 64; i += 256) emAll[i] = __expf(base - lbAll[i]);
        float en[2][4];
#pragma unroll
        for (int rg = 0; rg < 2; ++rg)
#pragma unroll
            for (int t2 = 0; t2 < 4; ++t2)
                en[rg][t2] = __expf(lbAll[n0 + w * 32 + rg * 16 + (l >> 4) * 4 + t2] - base);
        v8s aq[2][2];
#pragma unroll
        for (int rg = 0; rg < 2; ++rg)
#pragma unroll
            for (int kc = 0; kc < 2; ++kc) {
                const int r = w * 32 + rg * 16 + (l & 15);
                aq[rg][kc] = *(const v8s*)((char*)Ps + (r >> 6) * 8192 +
                                           aswz(r & 63, kc * 64 + (l >> 4) * 16));
            }
        WAITL();
        SBAR();   // emAll visible; Ps free for P use

        v4f oacc[2][4];
#pragma unroll
        for (int rg = 0; rg < 2; ++rg)
#pragma unroll
            for (int dt = 0; dt < 4; ++dt) oacc[rg][dt] = (v4f){0.f, 0.f, 0.f, 0.f};

        // prefetch tile 0
#pragma unroll
        for (int i = 0; i < 2; ++i) {
            const int c = w * 2 + i;
            gload16((const char*)Kb + ((size_t)bh * 16 + 0) * 8192 + c * 1024 + l * 16,
                    (char*)Ks + c * 1024);
            gload16((const char*)Vtb + ((size_t)bh * 16 + 0) * 8192 + c * 1024 + l * 16,
                    (char*)Vts + c * 1024);
        }

        for (int t = 0; t < NT; ++t) {
            const int m0 = t * 64;
            const int buf = t & 1;
            SBAR();   // all waves done reading buf^1
            if (t + 1 < NT) {
                const int nb = (t + 1) & 1;
#pragma unroll
                for (int i = 0; i < 2; ++i) {
                    const int c = w * 2 + i;
                    gload16((const char*)Kb + ((size_t)bh * 16 + t + 1) * 8192 + c * 1024 + l * 16,
                            (char*)Ks + nb * 8192 + c * 1024);
                    gload16((const char*)Vtb + ((size_t)bh * 16 + t + 1) * 8192 + c * 1024 + l * 16,
                            (char*)Vts + nb * 8192 + c * 1024);
                }
                WAITV4();
            } else {
                WAITV0();
            }
            SBAR();   // tile t fully in LDS (t+1 still in flight)

            const bool active = (m0 <= n0 + w * 32 + 31);
            if (active) {
                const char* KsB = (const char*)Ks + buf * 8192;
                const char* VtsB = (const char*)Vts + buf * 8192;
                // QK^T
                v4f sfr[2][4];
#pragma unroll
                for (int rg = 0; rg < 2; ++rg)
#pragma unroll
                    for (int m4 = 0; m4 < 4; ++m4) sfr[rg][m4] = (v4f){0.f, 0.f, 0.f, 0.f};
#pragma unroll
                for (int m4 = 0; m4 < 4; ++m4) {
#pragma unroll
                    for (int kc = 0; kc < 2; ++kc) {
                        const int m = m4 * 16 + (l & 15);
                        v8s bk = *(const v8s*)(KsB + aswz(m, kc * 64 + (l >> 4) * 16));
#pragma unroll
                        for (int rg = 0; rg < 2; ++rg)
                            sfr[rg][m4] = __builtin_amdgcn_mfma_f32_16x16x32_bf16(aq[rg][kc], bk, sfr[rg][m4], 0, 0, 0);
                    }
                }
                // decay (factorized) + mask + store P
                const bool needMask = (m0 + 63) > (n0 + w * 32);
                float emv[4];
#pragma unroll
                for (int m4 = 0; m4 < 4; ++m4) emv[m4] = emAll[m0 + m4 * 16 + (l & 15)];
#pragma unroll
                for (int rg = 0; rg < 2; ++rg)
#pragma unroll
                    for (int m4 = 0; m4 < 4; ++m4) {
                        const int m = m4 * 16 + (l & 15);
#pragma unroll
                        for (int t2 = 0; t2 < 4; ++t2) {
                            const int r = w * 32 + rg * 16 + (l >> 4) * 4 + t2;
                            float sval = sfr[rg][m4][t2] * en[rg][t2] * emv[m4];
                            if (needMask && (n0 + r) < (m0 + m)) sval = 0.0f;
                            *(short*)((char*)Ps + aswz(r, m * 2)) = f2bf(sval);
                        }
                    }
                WAITL();
                __builtin_amdgcn_sched_barrier(0);
                // PV
#pragma unroll
                for (int kc = 0; kc < 2; ++kc) {
                    v8s ap[2];
#pragma unroll
                    for (int rg = 0; rg < 2; ++rg) {
                        const int r = w * 32 + rg * 16 + (l & 15);
                        ap[rg] = *(const v8s*)((char*)Ps + aswz(r, kc * 64 + (l >> 4) * 16));
                    }
#pragma unroll
                    for (int dt = 0; dt < 4; ++dt) {
                        const int d = dt * 16 + (l & 15);
                        v8s bv = *(const v8s*)(VtsB + aswz(d, kc * 64 + (l >> 4) * 16));
#pragma unroll
                        for (int rg = 0; rg < 2; ++rg)
                            oacc[rg][dt] = __builtin_amdgcn_mfma_f32_16x16x32_bf16(ap[rg], bv, oacc[rg][dt], 0, 0, 0);
                    }
                }
            }
        }
        // job epilogue: write O + accumulate groupnorm partials
#pragma unroll
        for (int rg = 0; rg < 2; ++rg)
#pragma unroll
            for (int dt = 0; dt < 4; ++dt) {
                const int col = h * HD + dt * 16 + (l & 15);
                const int r0 = n0 + w * 32 + rg * 16 + (l >> 4) * 4;
#pragma unroll
                for (int t2 = 0; t2 < 4; ++t2) {
                    const float v = oacc[rg][dt][t2];
                    O[(size_t)(b * NSEQ + r0 + t2) * DM + col] = v;
                    psum += v; pssq += v * v;
                }
            }
    }
    // block reduction (Ks scratch is free after final barrier)
    __syncthreads();
    float* red = (float*)Ks;
    red[tid] = psum; red[256 + tid] = pssq;
    __syncthreads();
    for (int s = 128; s > 0; s >>= 1) {
        if (tid < s) { red[tid] += red[tid + s]; red[256 + tid] += red[256 + tid + s]; }
        __syncthreads();
    }
    if (tid == 0) {
        partial[(bh * 4 + blk) * 2]     = red[0];
        partial[(bh * 4 + blk) * 2 + 1] = red[256];
    }
}

// -------- finalize groupnorm stats from 4 partials per (b,h) ----------
__global__ __launch_bounds__(64) void gn_finalize(const float* __restrict__ partial,
                                                  float* __restrict__ stats) {
    const int bh = threadIdx.x;
    float s = 0.0f, q = 0.0f;
#pragma unroll
    for (int i = 0; i < 4; ++i) {
        s += partial[(bh * 4 + i) * 2];
        q += partial[(bh * 4 + i) * 2 + 1];
    }
    const float inv = 1.0f / (NSEQ * HD);
    const float mu = s * inv;
    const float var = q * inv - mu * mu;
    stats[bh * 2] = mu;
    stats[bh * 2 + 1] = rsqrtf(var + 1e-5f);
}

// -------- fused silu(Gfb) * groupnorm(O) -> Gb (tiled-swizzled bf16) ----------
__global__ __launch_bounds__(256) void gate_kernel(const short* __restrict__ Gfb,
                                                   const float* __restrict__ O,
                                                   const float* __restrict__ stats,
                                                   short* __restrict__ Gb) {
    const size_t i4 = ((size_t)blockIdx.x * 256 + threadIdx.x) * 4;
    const int row = (int)(i4 >> 10);
    const int col = (int)(i4 & 1023);
    const int h = col >> 6;
    const int b = row >> 10;
    const float mu = stats[(b * NH + h) * 2];
    const float rstd = stats[(b * NH + h) * 2 + 1];
    short4 gv = *(const short4*)(Gfb + i4);
    float4 ov = *(const float4*)(O + i4);
    const float gs[4] = {bf2f(gv.x), bf2f(gv.y), bf2f(gv.z), bf2f(gv.w)};
    const float os[4] = {ov.x, ov.y, ov.z, ov.w};
    short o[4];
#pragma unroll
    for (int j = 0; j < 4; ++j) {
        const float g = gs[j];
        const float silu = g / (1.0f + __expf(-g));
        o[j] = f2bf(silu * (os[j] - mu) * rstd);
    }
    const int rt = row >> 7, rloc = row & 127;
    const int kt = col >> 5, kloc = col & 31;
    char* base = (char*)(Gb + ((size_t)rt * 32 + kt) * 4096);
    *(short4*)(base + gswz(rloc, kloc * 2)) = *(short4*)o;
}

extern "C" void kernel_launch(void* const* d_in, const int* in_sizes, int n_in,
                              void* d_out, int out_size, void* d_ws, size_t ws_size,
                              hipStream_t stream) {
    const float* X       = (const float*)d_in[0];
    const float* ts      = (const float*)d_in[1];
    const float* W_qkv   = (const float*)d_in[2];
    const float* W_gamma = (const float*)d_in[3];
    const float* W_gated = (const float*)d_in[4];
    const float* W_out   = (const float*)d_in[5];
    float* out = (float*)d_out;

    char* ws = (char*)d_ws;
    short* qkvb = (short*)ws;                          // 12,582,912 sh (24MB)
    float* logb = (float*)(ws + 25165824);             // 65,536 f32
    float* Oatt = (float*)(ws + 25427968);             // 4,194,304 f32
    float* stats = (float*)(ws + 42205184);            // 128 f32
    short* Xb   = (short*)(ws + 42205696);             // 4,194,304 sh (tiled)
    short* Wtq  = (short*)(ws + 50594304);             // 3,145,728 sh
    short* Wtg  = (short*)(ws + 56885760);             // 1,048,576 sh
    short* Wto  = (short*)(ws + 58982912);             // 1,048,576 sh
    short* Qb   = (short*)(ws + 61080064);             // 4,194,304 sh
    short* Kb   = (short*)(ws + 69468672);             // 4,194,304 sh
    short* Vtb  = (short*)(ws + 77857280);             // 4,194,304 sh
    short* Gfb  = qkvb;                                // alias (dead after prep)
    short* Gb   = Xb;                                  // alias (dead after gemm#2)
    float* partial = (float*)Wtq;                      // alias (Wtq dead after gemm#1)

    convert_rows<<<dim3(32, 32), 256, 0, stream>>>(X, Xb, 1024);
    tconv<<<dim3(24, 32), 256, 0, stream>>>(W_qkv, Wtq, 1024, 3072);
    tconv<<<dim3(8, 32), 256, 0, stream>>>(W_gated, Wtg, 1024, 1024);
    tconv<<<dim3(8, 32), 256, 0, stream>>>(W_out, Wto, 1024, 1024);

    gemm_tt<true><<<dim3(24, 32), 256, 0, stream>>>(Xb, Wtq, qkvb, 3072);
    gamma2<<<256, 256, 0, stream>>>(X, W_gamma, logb);
    scan_kernel<<<16, 256, 0, stream>>>(logb);
    prep<<<dim3(16, 64), 256, 0, stream>>>(qkvb, ts, Qb, Kb, Vtb);
    attn3<<<256, 256, 0, stream>>>(Qb, Kb, Vtb, logb, Oatt, partial);
    gn_finalize<<<1, 64, 0, stream>>>(partial, stats);
    gemm_tt<true><<<dim3(8, 32), 256, 0, stream>>>(Xb, Wtg, Gfb, 1024);
    gate_kernel<<<4096, 256, 0, stream>>>(Gfb, Oatt, stats, Gb);
    gemm_tt<false><<<dim3(8, 32), 256, 0, stream>>>(Gb, Wto, out, 1024);
}

// Round 9
// 168.292 us; speedup vs baseline: 11.8947x; 1.0320x over previous
//
#include <hip/hip_runtime.h>
#include <cstddef>
#include <cstdint>

#define NH 16
#define HD 64
#define NSEQ 1024
#define NB 4
#define DM 1024
#define SCALE 0.125f   // 64^-0.5 (folded into prep Q)

typedef __attribute__((ext_vector_type(8))) short v8s;   // 8 bf16
typedef __attribute__((ext_vector_type(4))) float v4f;   // 4 f32

__device__ __forceinline__ short f2bf(float x) {
    union { float f; unsigned u; } v; v.f = x;
    unsigned r = v.u + 0x7FFF + ((v.u >> 16) & 1);
    return (short)(r >> 16);
}
__device__ __forceinline__ float bf2f(short x) {
    union { unsigned u; float f; } v; v.u = ((unsigned)(unsigned short)x) << 16;
    return v.f;
}
__device__ __forceinline__ void gload16(const void* g, void* l) {
    __builtin_amdgcn_global_load_lds(
        (const __attribute__((address_space(1))) void*)g,
        (__attribute__((address_space(3))) void*)l, 16, 0, 0);
}
__device__ __forceinline__ int gswz(int r, int kbyte) {
    return (r * 64 + kbyte) ^ (((r >> 1) & 3) << 4);
}
__device__ __forceinline__ int aswz(int r, int byte) {
    return (r * 128 + byte) ^ ((r & 7) << 4);
}
#define SBAR() __builtin_amdgcn_s_barrier()
#define WAITV0() asm volatile("s_waitcnt vmcnt(0)" ::: "memory")
#define WAITV4() asm volatile("s_waitcnt vmcnt(4)" ::: "memory")
#define WAITL() asm volatile("s_waitcnt lgkmcnt(0)" ::: "memory")

// ---------- X f32 row-major -> Xb bf16 tiled-swizzled [rt][kt][128x32] ----------
__global__ __launch_bounds__(256) void convert_rows(const float* __restrict__ X,
                                                    short* __restrict__ Xb, int K) {
    const int kt = blockIdx.x, rt = blockIdx.y;
    const int t = threadIdx.x;
    const int rloc = t >> 1, kb0 = (t & 1) * 16;
    const float* src = X + (size_t)(rt * 128 + rloc) * K + kt * 32 + kb0;
    short o[16] __attribute__((aligned(16)));
#pragma unroll
    for (int j = 0; j < 16; j += 4) {
        float4 v = *(const float4*)(src + j);
        o[j] = f2bf(v.x); o[j + 1] = f2bf(v.y); o[j + 2] = f2bf(v.z); o[j + 3] = f2bf(v.w);
    }
    char* base = (char*)(Xb + ((size_t)rt * (K >> 5) + kt) * 4096);
#pragma unroll
    for (int c = 0; c < 2; ++c)
        *(v8s*)(base + gswz(rloc, kb0 * 2 + c * 16)) = *(v8s*)&o[c * 8];
}

// ---------- W f32 [K][N] -> Bt bf16 tiled-swizzled [ct][kt][128x32] (transposed) ----
__global__ __launch_bounds__(256) void tconv(const float* __restrict__ W,
                                             short* __restrict__ Bt,
                                             int K, int N) {
    __shared__ short lsm[32][136];
    const int ct = blockIdx.x, kt = blockIdx.y;
    const int t = threadIdx.x;
    {
        const int kk = t >> 3, nn0 = (t & 7) * 16;
        const float* src = W + (size_t)(kt * 32 + kk) * N + ct * 128 + nn0;
#pragma unroll
        for (int j = 0; j < 16; j += 4) {
            float4 v = *(const float4*)(src + j);
            lsm[kk][nn0 + j] = f2bf(v.x); lsm[kk][nn0 + j + 1] = f2bf(v.y);
            lsm[kk][nn0 + j + 2] = f2bf(v.z); lsm[kk][nn0 + j + 3] = f2bf(v.w);
        }
    }
    __syncthreads();
    const int rloc = t >> 1, kb0 = (t & 1) * 16;
    short o[16] __attribute__((aligned(16)));
#pragma unroll
    for (int j = 0; j < 16; ++j) o[j] = lsm[kb0 + j][rloc];
    char* base = (char*)(Bt + ((size_t)ct * (K >> 5) + kt) * 4096);
#pragma unroll
    for (int c = 0; c < 2; ++c)
        *(v8s*)(base + gswz(rloc, kb0 * 2 + c * 16)) = *(v8s*)&o[c * 8];
}

// ---------- bf16 MFMA GEMM on tiled inputs: C[M][N] = A @ B^T, K=1024 ----------
template<bool BF16OUT>
__global__ __launch_bounds__(256) void gemm_tt(const short* __restrict__ A,
                                               const short* __restrict__ B,
                                               void* __restrict__ C, int N) {
    __shared__ short As[4096];
    __shared__ short Bs[4096];
    const int tid = threadIdx.x;
    const int w = tid >> 6, l = tid & 63;
    const int wr = w >> 1, wc = w & 1;
    const int rt = blockIdx.y, ct = blockIdx.x;
    const char* Abase = (const char*)A + ((size_t)rt * 32) * 8192;
    const char* Bbase = (const char*)B + ((size_t)ct * 32) * 8192;

    v4f acc[4][4];
#pragma unroll
    for (int i = 0; i < 4; ++i)
#pragma unroll
        for (int j = 0; j < 4; ++j) acc[i][j] = (v4f){0.f, 0.f, 0.f, 0.f};

    for (int kt = 0; kt < 32; ++kt) {
        __syncthreads();
#pragma unroll
        for (int i = 0; i < 2; ++i) {
            const int c = w * 2 + i;
            gload16(Abase + (size_t)kt * 8192 + c * 1024 + l * 16, (char*)As + c * 1024);
            gload16(Bbase + (size_t)kt * 8192 + c * 1024 + l * 16, (char*)Bs + c * 1024);
        }
        __syncthreads();
        v8s af[4], bfr[4];
#pragma unroll
        for (int i = 0; i < 4; ++i) {
            const int ra = wr * 64 + i * 16 + (l & 15);
            af[i] = *(const v8s*)((char*)As + gswz(ra, (l >> 4) * 16));
            const int rb = wc * 64 + i * 16 + (l & 15);
            bfr[i] = *(const v8s*)((char*)Bs + gswz(rb, (l >> 4) * 16));
        }
#pragma unroll
        for (int i = 0; i < 4; ++i)
#pragma unroll
            for (int j = 0; j < 4; ++j)
                acc[i][j] = __builtin_amdgcn_mfma_f32_16x16x32_bf16(af[i], bfr[j], acc[i][j], 0, 0, 0);
    }
#pragma unroll
    for (int i = 0; i < 4; ++i)
#pragma unroll
        for (int j = 0; j < 4; ++j) {
            const int r0 = rt * 128 + wr * 64 + i * 16 + (l >> 4) * 4;
            const int cc = ct * 128 + wc * 64 + j * 16 + (l & 15);
#pragma unroll
            for (int t2 = 0; t2 < 4; ++t2) {
                if (BF16OUT) ((short*)C)[(size_t)(r0 + t2) * N + cc] = f2bf(acc[i][j][t2]);
                else         ((float*)C)[(size_t)(r0 + t2) * N + cc] = acc[i][j][t2];
            }
        }
}

// -------- gamma2: loggam[row,h] = log(sigmoid(X[row]·Wg[:,h])^(1/20) + 1e-8) ----
__global__ __launch_bounds__(256) void gamma2(const float* __restrict__ X,
                                              const float* __restrict__ Wg,
                                              float* __restrict__ loggam) {
    __shared__ float wgs[1024 * 17];
    const int tid = threadIdx.x;
#pragma unroll
    for (int it = 0; it < 16; ++it) {
        const int idx = it * 1024 + tid * 4;
        float4 v = *(const float4*)(Wg + idx);
        const int k = idx >> 4, h0 = idx & 15;
        wgs[k * 17 + h0]     = v.x;
        wgs[k * 17 + h0 + 1] = v.y;
        wgs[k * 17 + h0 + 2] = v.z;
        wgs[k * 17 + h0 + 3] = v.w;
    }
    __syncthreads();

    const int r = tid >> 4, c = tid & 15;
    const int row = blockIdx.x * 16 + r;
    const float* xrow = X + (size_t)row * DM;
    float acc[16];
#pragma unroll
    for (int h = 0; h < 16; ++h) acc[h] = 0.0f;
#pragma unroll 4
    for (int i = 0; i < 16; ++i) {
        const int kb = i * 64 + c * 4;
        float4 xv = *(const float4*)(xrow + kb);
        const float xs[4] = {xv.x, xv.y, xv.z, xv.w};
#pragma unroll
        for (int j = 0; j < 4; ++j) {
            const float* wrow = &wgs[(kb + j) * 17];
#pragma unroll
            for (int h = 0; h < 16; ++h) acc[h] = fmaf(xs[j], wrow[h], acc[h]);
        }
    }
#pragma unroll
    for (int h = 0; h < 16; ++h) {
#pragma unroll
        for (int off = 8; off >= 1; off >>= 1)
            acc[h] += __shfl_xor(acc[h], off, 16);
    }
    const float d = acc[c];
    const float sig = 1.0f / (1.0f + expf(-d));
    const float gam = powf(sig, 1.0f / 20.0f);
    loggam[(size_t)row * NH + c] = logf(gam + 1e-8f);
}

// -------- parallel cumsum over n per (b,h) ----------
__global__ __launch_bounds__(256) void scan_kernel(float* __restrict__ lg) {
    const int wave = threadIdx.x >> 6;
    const int lane = threadIdx.x & 63;
    const int bh = blockIdx.x * 4 + wave;
    const int b = bh >> 4, h = bh & 15;
    float* p = lg + (size_t)b * NSEQ * NH + h;
    const int n0 = lane * 16;
    float v[16];
    float s = 0.0f;
#pragma unroll
    for (int j = 0; j < 16; ++j) { v[j] = p[(size_t)(n0 + j) * NH]; s += v[j]; }
    float sc = s;
#pragma unroll
    for (int off = 1; off < 64; off <<= 1) {
        float o = __shfl_up(sc, off, 64);
        if (lane >= off) sc += o;
    }
    float acc = sc - s;
#pragma unroll
    for (int j = 0; j < 16; ++j) { acc += v[j]; p[(size_t)(n0 + j) * NH] = acc; }
}

// ---- prep: qkvb bf16 -> RoPE'd Q(*SCALE)/K + V^T as pre-swizzled 64x64 tiles ----
__global__ __launch_bounds__(256) void prep(const short* __restrict__ qkvb,
                                            const float* __restrict__ ts,
                                            short* __restrict__ Qb,
                                            short* __restrict__ Kb,
                                            short* __restrict__ Vtb) {
    __shared__ short vsm[64][72];
    const int tile = blockIdx.x, bh = blockIdx.y;
    const int b = bh >> 4, h = bh & 15;
    const int t = threadIdx.x;
    const int rloc = t >> 2, d0 = (t & 3) * 16;
    const int row = b * NSEQ + tile * 64 + rloc;
    const short* src = qkvb + (size_t)row * 3072 + h * HD;
    const size_t tb = ((size_t)bh * 16 + tile) * 4096;

    float qa[16], ka[16];
    {
        v8s q0 = *(const v8s*)(src + d0), q1 = *(const v8s*)(src + d0 + 8);
        v8s k0 = *(const v8s*)(src + 1024 + d0), k1 = *(const v8s*)(src + 1024 + d0 + 8);
#pragma unroll
        for (int j = 0; j < 8; ++j) {
            qa[j] = bf2f(q0[j]); qa[j + 8] = bf2f(q1[j]);
            ka[j] = bf2f(k0[j]); ka[j + 8] = bf2f(k1[j]);
        }
    }
    const float tv = ts[row];
    short qo[16] __attribute__((aligned(16)));
    short ko[16] __attribute__((aligned(16)));
#pragma unroll
    for (int j = 0; j < 8; ++j) {
        const int i = (d0 >> 1) + j;
        const float inv_freq = exp2f(-0.4152410119f * (float)i);
        const float ang = tv * inv_freq;
        const float s = sinf(ang), c = cosf(ang);
        const float sv = ((float)(2 * i) + 25.6f) * (1.0f / 89.6f);
        const float e = log2f(sv) * tv * (1.0f / 512.0f);
        const float sc = exp2f(e) * SCALE, isc = exp2f(-e);
        qo[2 * j]     = f2bf((qa[2 * j] * c - qa[2 * j + 1] * s) * sc);
        qo[2 * j + 1] = f2bf((qa[2 * j + 1] * c + qa[2 * j] * s) * sc);
        ko[2 * j]     = f2bf((ka[2 * j] * c - ka[2 * j + 1] * s) * isc);
        ko[2 * j + 1] = f2bf((ka[2 * j + 1] * c + ka[2 * j] * s) * isc);
    }
#pragma unroll
    for (int c = 0; c < 2; ++c) {
        *(v8s*)((char*)(Qb + tb) + aswz(rloc, d0 * 2 + c * 16)) = *(v8s*)&qo[c * 8];
        *(v8s*)((char*)(Kb + tb) + aswz(rloc, d0 * 2 + c * 16)) = *(v8s*)&ko[c * 8];
    }
    {
        v8s v0 = *(const v8s*)(src + 2048 + d0), v1 = *(const v8s*)(src + 2048 + d0 + 8);
        *(short4*)&vsm[rloc][d0]      = *(short4*)&v0;
        *(short4*)&vsm[rloc][d0 + 4]  = *((short4*)&v0 + 1);
        *(short4*)&vsm[rloc][d0 + 8]  = *(short4*)&v1;
        *(short4*)&vsm[rloc][d0 + 12] = *((short4*)&v1 + 1);
    }
    __syncthreads();
    {
        const int d = t >> 2, m0 = (t & 3) * 16;
        short vt[16] __attribute__((aligned(16)));
#pragma unroll
        for (int j = 0; j < 16; ++j) vt[j] = vsm[m0 + j][d];
#pragma unroll
        for (int c = 0; c < 2; ++c)
            *(v8s*)((char*)(Vtb + tb) + aswz(d, m0 * 2 + c * 16)) = *(v8s*)&vt[c * 8];
    }
}

// -- attn v4: 512 one-job blocks (2/CU), heavy+light pairing on same CU/XCD,
//    K/V double-buffer with counted vmcnt, factorized decay, fused GN partials --
__global__ __launch_bounds__(256) void attn4(const short* __restrict__ Qb,
                                             const short* __restrict__ Kb,
                                             const short* __restrict__ Vtb,
                                             const float* __restrict__ logb,
                                             float* __restrict__ O,
                                             float* __restrict__ partial) {
    __shared__ short Ks[2][4096];
    __shared__ short Vts[2][4096];
    __shared__ short Ps[8192];       // P tiles; also Q staging (16KB)
    __shared__ float lbAll[1024];
    __shared__ float emAll[1024];
    const int id = blockIdx.x;
    const int half = id >> 8;                            // 0 = heavy, 1 = light
    const int idx = id & 255;
    const int bh = ((idx & 7) << 3) | ((idx >> 3) & 7);  // same bh & XCD for (i, i+256)
    const int qq = half == 0 ? (4 + (idx >> 6)) : (3 - (idx >> 6));
    const int b = bh >> 4, h = bh & 15;
    const int tid = threadIdx.x;
    const int w = tid >> 6, l = tid & 63;
    const int n0 = qq * 128;
    const int NT = 2 * qq + 2;

    // stage Q tiles (16KB) into Ps; load logb row
#pragma unroll
    for (int i = 0; i < 4; ++i) {
        const int c = w * 4 + i;
        gload16((const char*)Qb + ((size_t)bh * 16 + 2 * qq) * 8192 + c * 1024 + l * 16,
                (char*)Ps + c * 1024);
    }
    for (int i = tid; i < 1024; i += 256)
        lbAll[i] = logb[(size_t)(b * NSEQ + i) * NH + h];
    WAITV0(); WAITL();
    SBAR();

    const float base = lbAll[n0];
    for (int i = tid; i < NT * 64; i += 256) emAll[i] = __expf(base - lbAll[i]);
    float en[2][4];
#pragma unroll
    for (int rg = 0; rg < 2; ++rg)
#pragma unroll
        for (int t2 = 0; t2 < 4; ++t2)
            en[rg][t2] = __expf(lbAll[n0 + w * 32 + rg * 16 + (l >> 4) * 4 + t2] - base);
    v8s aq[2][2];
#pragma unroll
    for (int rg = 0; rg < 2; ++rg)
#pragma unroll
        for (int kc = 0; kc < 2; ++kc) {
            const int r = w * 32 + rg * 16 + (l & 15);
            aq[rg][kc] = *(const v8s*)((char*)Ps + (r >> 6) * 8192 +
                                       aswz(r & 63, kc * 64 + (l >> 4) * 16));
        }
    WAITL();
    SBAR();   // emAll visible; Ps free for P use

    v4f oacc[2][4];
#pragma unroll
    for (int rg = 0; rg < 2; ++rg)
#pragma unroll
        for (int dt = 0; dt < 4; ++dt) oacc[rg][dt] = (v4f){0.f, 0.f, 0.f, 0.f};

    // prefetch tile 0
#pragma unroll
    for (int i = 0; i < 2; ++i) {
        const int c = w * 2 + i;
        gload16((const char*)Kb + ((size_t)bh * 16 + 0) * 8192 + c * 1024 + l * 16,
                (char*)Ks + c * 1024);
        gload16((const char*)Vtb + ((size_t)bh * 16 + 0) * 8192 + c * 1024 + l * 16,
                (char*)Vts + c * 1024);
    }

    for (int t = 0; t < NT; ++t) {
        const int m0 = t * 64;
        const int buf = t & 1;
        SBAR();   // all waves done reading buf^1
        if (t + 1 < NT) {
            const int nb = (t + 1) & 1;
#pragma unroll
            for (int i = 0; i < 2; ++i) {
                const int c = w * 2 + i;
                gload16((const char*)Kb + ((size_t)bh * 16 + t + 1) * 8192 + c * 1024 + l * 16,
                        (char*)Ks + nb * 8192 + c * 1024);
                gload16((const char*)Vtb + ((size_t)bh * 16 + t + 1) * 8192 + c * 1024 + l * 16,
                        (char*)Vts + nb * 8192 + c * 1024);
            }
            WAITV4();
        } else {
            WAITV0();
        }
        SBAR();   // tile t fully in LDS (t+1 still in flight)

        const bool active = (m0 <= n0 + w * 32 + 31);
        if (active) {
            const char* KsB = (const char*)Ks + buf * 8192;
            const char* VtsB = (const char*)Vts + buf * 8192;
            // QK^T
            v4f sfr[2][4];
#pragma unroll
            for (int rg = 0; rg < 2; ++rg)
#pragma unroll
                for (int m4 = 0; m4 < 4; ++m4) sfr[rg][m4] = (v4f){0.f, 0.f, 0.f, 0.f};
#pragma unroll
            for (int m4 = 0; m4 < 4; ++m4) {
#pragma unroll
                for (int kc = 0; kc < 2; ++kc) {
                    const int m = m4 * 16 + (l & 15);
                    v8s bk = *(const v8s*)(KsB + aswz(m, kc * 64 + (l >> 4) * 16));
#pragma unroll
                    for (int rg = 0; rg < 2; ++rg)
                        sfr[rg][m4] = __builtin_amdgcn_mfma_f32_16x16x32_bf16(aq[rg][kc], bk, sfr[rg][m4], 0, 0, 0);
                }
            }
            // decay (factorized) + mask + store P
            const bool needMask = (m0 + 63) > (n0 + w * 32);
            float emv[4];
#pragma unroll
            for (int m4 = 0; m4 < 4; ++m4) emv[m4] = emAll[m0 + m4 * 16 + (l & 15)];
#pragma unroll
            for (int rg = 0; rg < 2; ++rg)
#pragma unroll
                for (int m4 = 0; m4 < 4; ++m4) {
                    const int m = m4 * 16 + (l & 15);
#pragma unroll
                    for (int t2 = 0; t2 < 4; ++t2) {
                        const int r = w * 32 + rg * 16 + (l >> 4) * 4 + t2;
                        float sval = sfr[rg][m4][t2] * en[rg][t2] * emv[m4];
                        if (needMask && (n0 + r) < (m0 + m)) sval = 0.0f;
                        *(short*)((char*)Ps + aswz(r, m * 2)) = f2bf(sval);
                    }
                }
            WAITL();
            __builtin_amdgcn_sched_barrier(0);
            // PV
#pragma unroll
            for (int kc = 0; kc < 2; ++kc) {
                v8s ap[2];
#pragma unroll
                for (int rg = 0; rg < 2; ++rg) {
                    const int r = w * 32 + rg * 16 + (l & 15);
                    ap[rg] = *(const v8s*)((char*)Ps + aswz(r, kc * 64 + (l >> 4) * 16));
                }
#pragma unroll
                for (int dt = 0; dt < 4; ++dt) {
                    const int d = dt * 16 + (l & 15);
                    v8s bv = *(const v8s*)(VtsB + aswz(d, kc * 64 + (l >> 4) * 16));
#pragma unroll
                    for (int rg = 0; rg < 2; ++rg)
                        oacc[rg][dt] = __builtin_amdgcn_mfma_f32_16x16x32_bf16(ap[rg], bv, oacc[rg][dt], 0, 0, 0);
                }
            }
        }
    }
    // epilogue: write O + groupnorm partials
    float psum = 0.0f, pssq = 0.0f;
#pragma unroll
    for (int rg = 0; rg < 2; ++rg)
#pragma unroll
        for (int dt = 0; dt < 4; ++dt) {
            const int col = h * HD + dt * 16 + (l & 15);
            const int r0 = n0 + w * 32 + rg * 16 + (l >> 4) * 4;
#pragma unroll
            for (int t2 = 0; t2 < 4; ++t2) {
                const float v = oacc[rg][dt][t2];
                O[(size_t)(b * NSEQ + r0 + t2) * DM + col] = v;
                psum += v; pssq += v * v;
            }
        }
    __syncthreads();
    float* red = (float*)Ks;
    red[tid] = psum; red[256 + tid] = pssq;
    __syncthreads();
    for (int s = 128; s > 0; s >>= 1) {
        if (tid < s) { red[tid] += red[tid + s]; red[256 + tid] += red[256 + tid + s]; }
        __syncthreads();
    }
    if (tid == 0) {
        partial[(bh * 8 + qq) * 2]     = red[0];
        partial[(bh * 8 + qq) * 2 + 1] = red[256];
    }
}

// -------- finalize groupnorm stats from 8 partials per (b,h) ----------
__global__ __launch_bounds__(64) void gn_finalize(const float* __restrict__ partial,
                                                  float* __restrict__ stats) {
    const int bh = threadIdx.x;
    float s = 0.0f, q = 0.0f;
#pragma unroll
    for (int i = 0; i < 8; ++i) {
        s += partial[(bh * 8 + i) * 2];
        q += partial[(bh * 8 + i) * 2 + 1];
    }
    const float inv = 1.0f / (NSEQ * HD);
    const float mu = s * inv;
    const float var = q * inv - mu * mu;
    stats[bh * 2] = mu;
    stats[bh * 2 + 1] = rsqrtf(var + 1e-5f);
}

// -------- fused silu(Gfb) * groupnorm(O) -> Gb (tiled-swizzled bf16) ----------
__global__ __launch_bounds__(256) void gate_kernel(const short* __restrict__ Gfb,
                                                   const float* __restrict__ O,
                                                   const float* __restrict__ stats,
                                                   short* __restrict__ Gb) {
    const size_t i4 = ((size_t)blockIdx.x * 256 + threadIdx.x) * 4;
    const int row = (int)(i4 >> 10);
    const int col = (int)(i4 & 1023);
    const int h = col >> 6;
    const int b = row >> 10;
    const float mu = stats[(b * NH + h) * 2];
    const float rstd = stats[(b * NH + h) * 2 + 1];
    short4 gv = *(const short4*)(Gfb + i4);
    float4 ov = *(const float4*)(O + i4);
    const float gs[4] = {bf2f(gv.x), bf2f(gv.y), bf2f(gv.z), bf2f(gv.w)};
    const float os[4] = {ov.x, ov.y, ov.z, ov.w};
    short o[4];
#pragma unroll
    for (int j = 0; j < 4; ++j) {
        const float g = gs[j];
        const float silu = g / (1.0f + __expf(-g));
        o[j] = f2bf(silu * (os[j] - mu) * rstd);
    }
    const int rt = row >> 7, rloc = row & 127;
    const int kt = col >> 5, kloc = col & 31;
    char* base = (char*)(Gb + ((size_t)rt * 32 + kt) * 4096);
    *(short4*)(base + gswz(rloc, kloc * 2)) = *(short4*)o;
}

extern "C" void kernel_launch(void* const* d_in, const int* in_sizes, int n_in,
                              void* d_out, int out_size, void* d_ws, size_t ws_size,
                              hipStream_t stream) {
    const float* X       = (const float*)d_in[0];
    const float* ts      = (const float*)d_in[1];
    const float* W_qkv   = (const float*)d_in[2];
    const float* W_gamma = (const float*)d_in[3];
    const float* W_gated = (const float*)d_in[4];
    const float* W_out   = (const float*)d_in[5];
    float* out = (float*)d_out;

    char* ws = (char*)d_ws;
    short* qkvb = (short*)ws;                          // 12,582,912 sh (24MB)
    float* logb = (float*)(ws + 25165824);             // 65,536 f32
    float* Oatt = (float*)(ws + 25427968);             // 4,194,304 f32
    float* stats = (float*)(ws + 42205184);            // 128 f32
    short* Xb   = (short*)(ws + 42205696);             // 4,194,304 sh (tiled)
    short* Wtq  = (short*)(ws + 50594304);             // 3,145,728 sh
    short* Wtg  = (short*)(ws + 56885760);             // 1,048,576 sh
    short* Wto  = (short*)(ws + 58982912);             // 1,048,576 sh
    short* Qb   = (short*)(ws + 61080064);             // 4,194,304 sh
    short* Kb   = (short*)(ws + 69468672);             // 4,194,304 sh
    short* Vtb  = (short*)(ws + 77857280);             // 4,194,304 sh
    short* Gfb  = qkvb;                                // alias (dead after prep)
    short* Gb   = Xb;                                  // alias (dead after gemm#2)
    float* partial = (float*)Wtq;                      // alias (Wtq dead after gemm#1)

    convert_rows<<<dim3(32, 32), 256, 0, stream>>>(X, Xb, 1024);
    tconv<<<dim3(24, 32), 256, 0, stream>>>(W_qkv, Wtq, 1024, 3072);
    tconv<<<dim3(8, 32), 256, 0, stream>>>(W_gated, Wtg, 1024, 1024);
    tconv<<<dim3(8, 32), 256, 0, stream>>>(W_out, Wto, 1024, 1024);

    gemm_tt<true><<<dim3(24, 32), 256, 0, stream>>>(Xb, Wtq, qkvb, 3072);
    gamma2<<<256, 256, 0, stream>>>(X, W_gamma, logb);
    scan_kernel<<<16, 256, 0, stream>>>(logb);
    prep<<<dim3(16, 64), 256, 0, stream>>>(qkvb, ts, Qb, Kb, Vtb);
    attn4<<<512, 256, 0, stream>>>(Qb, Kb, Vtb, logb, Oatt, partial);
    gn_finalize<<<1, 64, 0, stream>>>(partial, stats);
    gemm_tt<true><<<dim3(8, 32), 256, 0, stream>>>(Xb, Wtg, Gfb, 1024);
    gate_kernel<<<4096, 256, 0, stream>>>(Gfb, Oatt, stats, Gb);
    gemm_tt<false><<<dim3(8, 32), 256, 0, stream>>>(Gb, Wto, out, 1024);
}

// Round 10
// 164.621 us; speedup vs baseline: 12.1600x; 1.0223x over previous
//
#include <hip/hip_runtime.h>
#include <cstddef>
#include <cstdint>

#define NH 16
#define HD 64
#define NSEQ 1024
#define NB 4
#define DM 1024
#define SCALE 0.125f   // 64^-0.5 (folded into prep Q)

typedef __attribute__((ext_vector_type(8))) short v8s;   // 8 bf16
typedef __attribute__((ext_vector_type(4))) float v4f;   // 4 f32

__device__ __forceinline__ short f2bf(float x) {
    union { float f; unsigned u; } v; v.f = x;
    unsigned r = v.u + 0x7FFF + ((v.u >> 16) & 1);
    return (short)(r >> 16);
}
__device__ __forceinline__ float bf2f(short x) {
    union { unsigned u; float f; } v; v.u = ((unsigned)(unsigned short)x) << 16;
    return v.f;
}
__device__ __forceinline__ void gload16(const void* g, void* l) {
    __builtin_amdgcn_global_load_lds(
        (const __attribute__((address_space(1))) void*)g,
        (__attribute__((address_space(3))) void*)l, 16, 0, 0);
}
__device__ __forceinline__ int gswz(int r, int kbyte) {
    return (r * 64 + kbyte) ^ (((r >> 1) & 3) << 4);
}
__device__ __forceinline__ int aswz(int r, int byte) {
    return (r * 128 + byte) ^ ((r & 7) << 4);
}
#define SBAR() __builtin_amdgcn_s_barrier()
#define WAITV0() asm volatile("s_waitcnt vmcnt(0)" ::: "memory")
#define WAITV4() asm volatile("s_waitcnt vmcnt(4)" ::: "memory")
#define WAITL() asm volatile("s_waitcnt lgkmcnt(0)" ::: "memory")

// ---------- X f32 row-major -> Xb bf16 tiled-swizzled [rt][kt][128x32] ----------
__global__ __launch_bounds__(256) void convert_rows(const float* __restrict__ X,
                                                    short* __restrict__ Xb, int K) {
    const int kt = blockIdx.x, rt = blockIdx.y;
    const int t = threadIdx.x;
    const int rloc = t >> 1, kb0 = (t & 1) * 16;
    const float* src = X + (size_t)(rt * 128 + rloc) * K + kt * 32 + kb0;
    short o[16] __attribute__((aligned(16)));
#pragma unroll
    for (int j = 0; j < 16; j += 4) {
        float4 v = *(const float4*)(src + j);
        o[j] = f2bf(v.x); o[j + 1] = f2bf(v.y); o[j + 2] = f2bf(v.z); o[j + 3] = f2bf(v.w);
    }
    char* base = (char*)(Xb + ((size_t)rt * (K >> 5) + kt) * 4096);
#pragma unroll
    for (int c = 0; c < 2; ++c)
        *(v8s*)(base + gswz(rloc, kb0 * 2 + c * 16)) = *(v8s*)&o[c * 8];
}

// ---------- W f32 [K][N] -> Bt bf16 tiled-swizzled [ct][kt][128x32] (transposed) ----
__global__ __launch_bounds__(256) void tconv(const float* __restrict__ W,
                                             short* __restrict__ Bt,
                                             int K, int N) {
    __shared__ short lsm[32][136];
    const int ct = blockIdx.x, kt = blockIdx.y;
    const int t = threadIdx.x;
    {
        const int kk = t >> 3, nn0 = (t & 7) * 16;
        const float* src = W + (size_t)(kt * 32 + kk) * N + ct * 128 + nn0;
#pragma unroll
        for (int j = 0; j < 16; j += 4) {
            float4 v = *(const float4*)(src + j);
            lsm[kk][nn0 + j] = f2bf(v.x); lsm[kk][nn0 + j + 1] = f2bf(v.y);
            lsm[kk][nn0 + j + 2] = f2bf(v.z); lsm[kk][nn0 + j + 3] = f2bf(v.w);
        }
    }
    __syncthreads();
    const int rloc = t >> 1, kb0 = (t & 1) * 16;
    short o[16] __attribute__((aligned(16)));
#pragma unroll
    for (int j = 0; j < 16; ++j) o[j] = lsm[kb0 + j][rloc];
    char* base = (char*)(Bt + ((size_t)ct * (K >> 5) + kt) * 4096);
#pragma unroll
    for (int c = 0; c < 2; ++c)
        *(v8s*)(base + gswz(rloc, kb0 * 2 + c * 16)) = *(v8s*)&o[c * 8];
}

// ---------- bf16 MFMA GEMM on tiled inputs: C = A @ B^T, K=1024 ----------
// MODE 0: f32 row-major out. MODE 1: bf16 row-major out.
// MODE 2: fused silu(acc)*groupnorm(O) -> bf16 tiled-swizzled out (N must be 1024).
template<int MODE>
__global__ __launch_bounds__(256) void gemm_tt(const short* __restrict__ A,
                                               const short* __restrict__ B,
                                               void* __restrict__ C, int N,
                                               const float* __restrict__ O,
                                               const float* __restrict__ stats) {
    __shared__ short As[4096];
    __shared__ short Bs[4096];
    const int tid = threadIdx.x;
    const int w = tid >> 6, l = tid & 63;
    const int wr = w >> 1, wc = w & 1;
    const int rt = blockIdx.y, ct = blockIdx.x;
    const char* Abase = (const char*)A + ((size_t)rt * 32) * 8192;
    const char* Bbase = (const char*)B + ((size_t)ct * 32) * 8192;

    v4f acc[4][4];
#pragma unroll
    for (int i = 0; i < 4; ++i)
#pragma unroll
        for (int j = 0; j < 4; ++j) acc[i][j] = (v4f){0.f, 0.f, 0.f, 0.f};

    for (int kt = 0; kt < 32; ++kt) {
        __syncthreads();
#pragma unroll
        for (int i = 0; i < 2; ++i) {
            const int c = w * 2 + i;
            gload16(Abase + (size_t)kt * 8192 + c * 1024 + l * 16, (char*)As + c * 1024);
            gload16(Bbase + (size_t)kt * 8192 + c * 1024 + l * 16, (char*)Bs + c * 1024);
        }
        __syncthreads();
        v8s af[4], bfr[4];
#pragma unroll
        for (int i = 0; i < 4; ++i) {
            const int ra = wr * 64 + i * 16 + (l & 15);
            af[i] = *(const v8s*)((char*)As + gswz(ra, (l >> 4) * 16));
            const int rb = wc * 64 + i * 16 + (l & 15);
            bfr[i] = *(const v8s*)((char*)Bs + gswz(rb, (l >> 4) * 16));
        }
#pragma unroll
        for (int i = 0; i < 4; ++i)
#pragma unroll
            for (int j = 0; j < 4; ++j)
                acc[i][j] = __builtin_amdgcn_mfma_f32_16x16x32_bf16(af[i], bfr[j], acc[i][j], 0, 0, 0);
    }
    float mu = 0.f, rstd = 0.f;
    if (MODE == 2) {
        const int hh = ct * 2 + wc;           // head is wave-constant
        mu   = stats[((rt >> 3) * NH + hh) * 2];
        rstd = stats[((rt >> 3) * NH + hh) * 2 + 1];
    }
#pragma unroll
    for (int i = 0; i < 4; ++i)
#pragma unroll
        for (int j = 0; j < 4; ++j) {
            const int r0 = rt * 128 + wr * 64 + i * 16 + (l >> 4) * 4;
            const int cc = ct * 128 + wc * 64 + j * 16 + (l & 15);
#pragma unroll
            for (int t2 = 0; t2 < 4; ++t2) {
                if (MODE == 1) ((short*)C)[(size_t)(r0 + t2) * N + cc] = f2bf(acc[i][j][t2]);
                else if (MODE == 0) ((float*)C)[(size_t)(r0 + t2) * N + cc] = acc[i][j][t2];
                else {
                    const int row = r0 + t2;
                    const float g = acc[i][j][t2];
                    const float silu = g / (1.0f + __expf(-g));
                    const float ov = O[(size_t)row * DM + cc];
                    const float val = silu * (ov - mu) * rstd;
                    const int rloc = row - rt * 128;
                    char* base = (char*)((short*)C + ((size_t)rt * 32 + (cc >> 5)) * 4096);
                    *(short*)(base + gswz(rloc, (cc & 31) * 2)) = f2bf(val);
                }
            }
        }
}

// -------- gamma2: loggam[row,h] = log(sigmoid(X[row]·Wg[:,h])^(1/20) + 1e-8) ----
__global__ __launch_bounds__(256) void gamma2(const float* __restrict__ X,
                                              const float* __restrict__ Wg,
                                              float* __restrict__ loggam) {
    __shared__ float wgs[1024 * 17];
    const int tid = threadIdx.x;
#pragma unroll
    for (int it = 0; it < 16; ++it) {
        const int idx = it * 1024 + tid * 4;
        float4 v = *(const float4*)(Wg + idx);
        const int k = idx >> 4, h0 = idx & 15;
        wgs[k * 17 + h0]     = v.x;
        wgs[k * 17 + h0 + 1] = v.y;
        wgs[k * 17 + h0 + 2] = v.z;
        wgs[k * 17 + h0 + 3] = v.w;
    }
    __syncthreads();

    const int r = tid >> 4, c = tid & 15;
    const int row = blockIdx.x * 16 + r;
    const float* xrow = X + (size_t)row * DM;
    float acc[16];
#pragma unroll
    for (int h = 0; h < 16; ++h) acc[h] = 0.0f;
#pragma unroll 4
    for (int i = 0; i < 16; ++i) {
        const int kb = i * 64 + c * 4;
        float4 xv = *(const float4*)(xrow + kb);
        const float xs[4] = {xv.x, xv.y, xv.z, xv.w};
#pragma unroll
        for (int j = 0; j < 4; ++j) {
            const float* wrow = &wgs[(kb + j) * 17];
#pragma unroll
            for (int h = 0; h < 16; ++h) acc[h] = fmaf(xs[j], wrow[h], acc[h]);
        }
    }
#pragma unroll
    for (int h = 0; h < 16; ++h) {
#pragma unroll
        for (int off = 8; off >= 1; off >>= 1)
            acc[h] += __shfl_xor(acc[h], off, 16);
    }
    const float d = acc[c];
    const float sig = 1.0f / (1.0f + expf(-d));
    const float gam = powf(sig, 1.0f / 20.0f);
    loggam[(size_t)row * NH + c] = logf(gam + 1e-8f);
}

// -------- parallel cumsum over n per (b,h); writes TRANSPOSED [bh][n] ----------
__global__ __launch_bounds__(256) void scan_kernel(const float* __restrict__ lg,
                                                   float* __restrict__ lgT) {
    const int wave = threadIdx.x >> 6;
    const int lane = threadIdx.x & 63;
    const int bh = blockIdx.x * 4 + wave;
    const int b = bh >> 4, h = bh & 15;
    const float* p = lg + (size_t)b * NSEQ * NH + h;
    const int n0 = lane * 16;
    float v[16];
    float s = 0.0f;
#pragma unroll
    for (int j = 0; j < 16; ++j) { v[j] = p[(size_t)(n0 + j) * NH]; s += v[j]; }
    float sc = s;
#pragma unroll
    for (int off = 1; off < 64; off <<= 1) {
        float o = __shfl_up(sc, off, 64);
        if (lane >= off) sc += o;
    }
    float acc = sc - s;
    float* q = lgT + (size_t)bh * NSEQ + n0;
#pragma unroll
    for (int j = 0; j < 16; ++j) { acc += v[j]; q[j] = acc; }
}

// ---- prep: qkvb bf16 -> RoPE'd Q(*SCALE)/K + V^T as pre-swizzled 64x64 tiles ----
__global__ __launch_bounds__(256) void prep(const short* __restrict__ qkvb,
                                            const float* __restrict__ ts,
                                            short* __restrict__ Qb,
                                            short* __restrict__ Kb,
                                            short* __restrict__ Vtb) {
    __shared__ short vsm[64][72];
    const int tile = blockIdx.x, bh = blockIdx.y;
    const int b = bh >> 4, h = bh & 15;
    const int t = threadIdx.x;
    const int rloc = t >> 2, d0 = (t & 3) * 16;
    const int row = b * NSEQ + tile * 64 + rloc;
    const short* src = qkvb + (size_t)row * 3072 + h * HD;
    const size_t tb = ((size_t)bh * 16 + tile) * 4096;

    float qa[16], ka[16];
    {
        v8s q0 = *(const v8s*)(src + d0), q1 = *(const v8s*)(src + d0 + 8);
        v8s k0 = *(const v8s*)(src + 1024 + d0), k1 = *(const v8s*)(src + 1024 + d0 + 8);
#pragma unroll
        for (int j = 0; j < 8; ++j) {
            qa[j] = bf2f(q0[j]); qa[j + 8] = bf2f(q1[j]);
            ka[j] = bf2f(k0[j]); ka[j + 8] = bf2f(k1[j]);
        }
    }
    const float tv = ts[row];
    short qo[16] __attribute__((aligned(16)));
    short ko[16] __attribute__((aligned(16)));
#pragma unroll
    for (int j = 0; j < 8; ++j) {
        const int i = (d0 >> 1) + j;
        const float inv_freq = exp2f(-0.4152410119f * (float)i);
        const float ang = tv * inv_freq;
        const float s = sinf(ang), c = cosf(ang);
        const float sv = ((float)(2 * i) + 25.6f) * (1.0f / 89.6f);
        const float e = log2f(sv) * tv * (1.0f / 512.0f);
        const float sc = exp2f(e) * SCALE, isc = exp2f(-e);
        qo[2 * j]     = f2bf((qa[2 * j] * c - qa[2 * j + 1] * s) * sc);
        qo[2 * j + 1] = f2bf((qa[2 * j + 1] * c + qa[2 * j] * s) * sc);
        ko[2 * j]     = f2bf((ka[2 * j] * c - ka[2 * j + 1] * s) * isc);
        ko[2 * j + 1] = f2bf((ka[2 * j + 1] * c + ka[2 * j] * s) * isc);
    }
#pragma unroll
    for (int c = 0; c < 2; ++c) {
        *(v8s*)((char*)(Qb + tb) + aswz(rloc, d0 * 2 + c * 16)) = *(v8s*)&qo[c * 8];
        *(v8s*)((char*)(Kb + tb) + aswz(rloc, d0 * 2 + c * 16)) = *(v8s*)&ko[c * 8];
    }
    {
        v8s v0 = *(const v8s*)(src + 2048 + d0), v1 = *(const v8s*)(src + 2048 + d0 + 8);
        *(short4*)&vsm[rloc][d0]      = *(short4*)&v0;
        *(short4*)&vsm[rloc][d0 + 4]  = *((short4*)&v0 + 1);
        *(short4*)&vsm[rloc][d0 + 8]  = *(short4*)&v1;
        *(short4*)&vsm[rloc][d0 + 12] = *((short4*)&v1 + 1);
    }
    __syncthreads();
    {
        const int d = t >> 2, m0 = (t & 3) * 16;
        short vt[16] __attribute__((aligned(16)));
#pragma unroll
        for (int j = 0; j < 16; ++j) vt[j] = vsm[m0 + j][d];
#pragma unroll
        for (int c = 0; c < 2; ++c)
            *(v8s*)((char*)(Vtb + tb) + aswz(d, m0 * 2 + c * 16)) = *(v8s*)&vt[c * 8];
    }
}

// -- attn5: swapped-operand MFMA (S^T / O^T), packed P stores, float4 O writes.
//    512 one-job blocks (2/CU), K/V dbuf + counted vmcnt, factorized decay. --
__global__ __launch_bounds__(256) void attn5(const short* __restrict__ Qb,
                                             const short* __restrict__ Kb,
                                             const short* __restrict__ Vtb,
                                             const float* __restrict__ logbT,
                                             float* __restrict__ O,
                                             float* __restrict__ partial) {
    __shared__ short Ks[2][4096];
    __shared__ short Vts[2][4096];
    __shared__ short Ps[8192];       // P tiles; also Q staging (16KB)
    __shared__ float lbAll[1024];
    __shared__ float emAll[1024];
    const int id = blockIdx.x;
    const int half = id >> 8;                            // 0 = heavy, 1 = light
    const int idx = id & 255;
    const int bh = ((idx & 7) << 3) | ((idx >> 3) & 7);  // same bh & XCD for (i, i+256)
    const int qq = half == 0 ? (4 + (idx >> 6)) : (3 - (idx >> 6));
    const int b = bh >> 4, h = bh & 15;
    const int tid = threadIdx.x;
    const int w = tid >> 6, l = tid & 63;
    const int n0 = qq * 128;
    const int NT = 2 * qq + 2;

    // stage Q tiles (16KB) into Ps; load logbT row (coalesced)
#pragma unroll
    for (int i = 0; i < 4; ++i) {
        const int c = w * 4 + i;
        gload16((const char*)Qb + ((size_t)bh * 16 + 2 * qq) * 8192 + c * 1024 + l * 16,
                (char*)Ps + c * 1024);
    }
    for (int i = tid; i < 1024; i += 256)
        lbAll[i] = logbT[(size_t)bh * NSEQ + i];
    WAITV0(); WAITL();
    SBAR();

    const float base = lbAll[n0];
    for (int i = tid; i < NT * 64; i += 256) emAll[i] = __expf(base - lbAll[i]);
    float en[2];
#pragma unroll
    for (int rg = 0; rg < 2; ++rg)
        en[rg] = __expf(lbAll[n0 + w * 32 + rg * 16 + (l & 15)] - base);
    v8s aq[2][2];
#pragma unroll
    for (int rg = 0; rg < 2; ++rg)
#pragma unroll
        for (int kc = 0; kc < 2; ++kc) {
            const int r = w * 32 + rg * 16 + (l & 15);
            aq[rg][kc] = *(const v8s*)((char*)Ps + (r >> 6) * 8192 +
                                       aswz(r & 63, kc * 64 + (l >> 4) * 16));
        }
    WAITL();
    SBAR();   // emAll visible; Ps free for P use

    v4f oacc[2][4];   // O^T: [rg][dt], row d = dt*16+(l>>4)*4+t2, col q = rg*16+(l&15)+w*32
#pragma unroll
    for (int rg = 0; rg < 2; ++rg)
#pragma unroll
        for (int dt = 0; dt < 4; ++dt) oacc[rg][dt] = (v4f){0.f, 0.f, 0.f, 0.f};

    // prefetch tile 0
#pragma unroll
    for (int i = 0; i < 2; ++i) {
        const int c = w * 2 + i;
        gload16((const char*)Kb + ((size_t)bh * 16 + 0) * 8192 + c * 1024 + l * 16,
                (char*)Ks + c * 1024);
        gload16((const char*)Vtb + ((size_t)bh * 16 + 0) * 8192 + c * 1024 + l * 16,
                (char*)Vts + c * 1024);
    }

    for (int t = 0; t < NT; ++t) {
        const int m0 = t * 64;
        const int buf = t & 1;
        SBAR();   // all waves done reading buf^1
        if (t + 1 < NT) {
            const int nb = (t + 1) & 1;
#pragma unroll
            for (int i = 0; i < 2; ++i) {
                const int c = w * 2 + i;
                gload16((const char*)Kb + ((size_t)bh * 16 + t + 1) * 8192 + c * 1024 + l * 16,
                        (char*)Ks + nb * 8192 + c * 1024);
                gload16((const char*)Vtb + ((size_t)bh * 16 + t + 1) * 8192 + c * 1024 + l * 16,
                        (char*)Vts + nb * 8192 + c * 1024);
            }
            WAITV4();
        } else {
            WAITV0();
        }
        SBAR();   // tile t fully in LDS (t+1 still in flight)

        const bool active = (m0 <= n0 + w * 32 + 31);
        if (active) {
            const char* KsB = (const char*)Ks + buf * 8192;
            const char* VtsB = (const char*)Vts + buf * 8192;
            // S^T = mfma(K, Q): rows m, cols q
            v4f sfr[2][4];
#pragma unroll
            for (int rg = 0; rg < 2; ++rg)
#pragma unroll
                for (int m4 = 0; m4 < 4; ++m4) sfr[rg][m4] = (v4f){0.f, 0.f, 0.f, 0.f};
#pragma unroll
            for (int m4 = 0; m4 < 4; ++m4) {
#pragma unroll
                for (int kc = 0; kc < 2; ++kc) {
                    const int m = m4 * 16 + (l & 15);
                    v8s bk = *(const v8s*)(KsB + aswz(m, kc * 64 + (l >> 4) * 16));
#pragma unroll
                    for (int rg = 0; rg < 2; ++rg)
                        sfr[rg][m4] = __builtin_amdgcn_mfma_f32_16x16x32_bf16(bk, aq[rg][kc], sfr[rg][m4], 0, 0, 0);
                }
            }
            // decay (factorized) + mask + packed P store (row q, 4 consecutive m)
            const bool needMask = (m0 + 63) > (n0 + w * 32);
#pragma unroll
            for (int rg = 0; rg < 2; ++rg) {
                const int r = w * 32 + rg * 16 + (l & 15);
                const float enr = en[rg];
#pragma unroll
                for (int m4 = 0; m4 < 4; ++m4) {
                    const int mbase = m0 + m4 * 16 + (l >> 4) * 4;
                    float4 emv = *(const float4*)&emAll[mbase];
                    const float ems[4] = {emv.x, emv.y, emv.z, emv.w};
                    union { short s[4]; uint2 u; } pk;
#pragma unroll
                    for (int t2 = 0; t2 < 4; ++t2) {
                        float sval = sfr[rg][m4][t2] * enr * ems[t2];
                        if (needMask && (n0 + r) < (mbase + t2)) sval = 0.0f;
                        pk.s[t2] = f2bf(sval);
                    }
                    *(uint2*)((char*)Ps + aswz(r, (m4 * 16 + (l >> 4) * 4) * 2)) = pk.u;
                }
            }
            WAITL();
            __builtin_amdgcn_sched_barrier(0);
            // O^T += mfma(V^T, P): rows d, cols q
#pragma unroll
            for (int kc = 0; kc < 2; ++kc) {
                v8s ap[2];
#pragma unroll
                for (int rg = 0; rg < 2; ++rg) {
                    const int r = w * 32 + rg * 16 + (l & 15);
                    ap[rg] = *(const v8s*)((char*)Ps + aswz(r, kc * 64 + (l >> 4) * 16));
                }
#pragma unroll
                for (int dt = 0; dt < 4; ++dt) {
                    const int d = dt * 16 + (l & 15);
                    v8s bv = *(const v8s*)(VtsB + aswz(d, kc * 64 + (l >> 4) * 16));
#pragma unroll
                    for (int rg = 0; rg < 2; ++rg)
                        oacc[rg][dt] = __builtin_amdgcn_mfma_f32_16x16x32_bf16(bv, ap[rg], oacc[rg][dt], 0, 0, 0);
                }
            }
        }
    }
    // epilogue: float4 O writes + groupnorm partials
    float psum = 0.0f, pssq = 0.0f;
#pragma unroll
    for (int rg = 0; rg < 2; ++rg) {
        const int row = n0 + w * 32 + rg * 16 + (l & 15);
#pragma unroll
        for (int dt = 0; dt < 4; ++dt) {
            const float4 v = {oacc[rg][dt][0], oacc[rg][dt][1], oacc[rg][dt][2], oacc[rg][dt][3]};
            *(float4*)(O + (size_t)(b * NSEQ + row) * DM + h * HD + dt * 16 + (l >> 4) * 4) = v;
            psum += v.x + v.y + v.z + v.w;
            pssq += v.x * v.x + v.y * v.y + v.z * v.z + v.w * v.w;
        }
    }
    __syncthreads();
    float* red = (float*)Ks;
    red[tid] = psum; red[256 + tid] = pssq;
    __syncthreads();
    for (int s = 128; s > 0; s >>= 1) {
        if (tid < s) { red[tid] += red[tid + s]; red[256 + tid] += red[256 + tid + s]; }
        __syncthreads();
    }
    if (tid == 0) {
        partial[(bh * 8 + qq) * 2]     = red[0];
        partial[(bh * 8 + qq) * 2 + 1] = red[256];
    }
}

// -------- finalize groupnorm stats from 8 partials per (b,h) ----------
__global__ __launch_bounds__(64) void gn_finalize(const float* __restrict__ partial,
                                                  float* __restrict__ stats) {
    const int bh = threadIdx.x;
    float s = 0.0f, q = 0.0f;
#pragma unroll
    for (int i = 0; i < 8; ++i) {
        s += partial[(bh * 8 + i) * 2];
        q += partial[(bh * 8 + i) * 2 + 1];
    }
    const float inv = 1.0f / (NSEQ * HD);
    const float mu = s * inv;
    const float var = q * inv - mu * mu;
    stats[bh * 2] = mu;
    stats[bh * 2 + 1] = rsqrtf(var + 1e-5f);
}

extern "C" void kernel_launch(void* const* d_in, const int* in_sizes, int n_in,
                              void* d_out, int out_size, void* d_ws, size_t ws_size,
                              hipStream_t stream) {
    const float* X       = (const float*)d_in[0];
    const float* ts      = (const float*)d_in[1];
    const float* W_qkv   = (const float*)d_in[2];
    const float* W_gamma = (const float*)d_in[3];
    const float* W_gated = (const float*)d_in[4];
    const float* W_out   = (const float*)d_in[5];
    float* out = (float*)d_out;

    char* ws = (char*)d_ws;
    short* qkvb = (short*)ws;                          // 12,582,912 sh (24MB)
    float* logb = (float*)(ws + 25165824);             // 65,536 f32
    float* Oatt = (float*)(ws + 25427968);             // 4,194,304 f32
    float* stats = (float*)(ws + 42205184);            // 128 f32
    short* Xb   = (short*)(ws + 42205696);             // 4,194,304 sh (tiled)
    short* Wtq  = (short*)(ws + 50594304);             // 3,145,728 sh
    short* Wtg  = (short*)(ws + 56885760);             // 1,048,576 sh
    short* Wto  = (short*)(ws + 58982912);             // 1,048,576 sh
    short* Qb   = (short*)(ws + 61080064);             // 4,194,304 sh
    short* Kb   = (short*)(ws + 69468672);             // 4,194,304 sh
    short* Vtb  = (short*)(ws + 77857280);             // 4,194,304 sh
    float* logbT = (float*)(ws + 86245888);            // 65,536 f32
    short* Gb   = Xb;                                  // alias (Xb dead after gemm#2)
    float* partial = (float*)Wtq;                      // alias (Wtq dead after gemm#1)

    convert_rows<<<dim3(32, 32), 256, 0, stream>>>(X, Xb, 1024);
    tconv<<<dim3(24, 32), 256, 0, stream>>>(W_qkv, Wtq, 1024, 3072);
    tconv<<<dim3(8, 32), 256, 0, stream>>>(W_gated, Wtg, 1024, 1024);
    tconv<<<dim3(8, 32), 256, 0, stream>>>(W_out, Wto, 1024, 1024);

    gemm_tt<1><<<dim3(24, 32), 256, 0, stream>>>(Xb, Wtq, qkvb, 3072, nullptr, nullptr);
    gamma2<<<256, 256, 0, stream>>>(X, W_gamma, logb);
    scan_kernel<<<16, 256, 0, stream>>>(logb, logbT);
    prep<<<dim3(16, 64), 256, 0, stream>>>(qkvb, ts, Qb, Kb, Vtb);
    attn5<<<512, 256, 0, stream>>>(Qb, Kb, Vtb, logbT, Oatt, partial);
    gn_finalize<<<1, 64, 0, stream>>>(partial, stats);
    gemm_tt<2><<<dim3(8, 32), 256, 0, stream>>>(Xb, Wtg, Gb, 1024, Oatt, stats);
    gemm_tt<0><<<dim3(8, 32), 256, 0, stream>>>(Gb, Wto, out, 1024, nullptr, nullptr);
}

// Round 11
// 154.134 us; speedup vs baseline: 12.9873x; 1.0680x over previous
//
#include <hip/hip_runtime.h>
#include <cstddef>
#include <cstdint>

#define NH 16
#define HD 64
#define NSEQ 1024
#define NB 4
#define DM 1024
#define SCALE 0.125f   // 64^-0.5 (folded into prep Q)

typedef __attribute__((ext_vector_type(8))) short v8s;   // 8 bf16
typedef __attribute__((ext_vector_type(4))) float v4f;   // 4 f32

__device__ __forceinline__ short f2bf(float x) {
    union { float f; unsigned u; } v; v.f = x;
    unsigned r = v.u + 0x7FFF + ((v.u >> 16) & 1);
    return (short)(r >> 16);
}
__device__ __forceinline__ float bf2f(short x) {
    union { unsigned u; float f; } v; v.u = ((unsigned)(unsigned short)x) << 16;
    return v.f;
}
__device__ __forceinline__ void gload16(const void* g, void* l) {
    __builtin_amdgcn_global_load_lds(
        (const __attribute__((address_space(1))) void*)g,
        (__attribute__((address_space(3))) void*)l, 16, 0, 0);
}
__device__ __forceinline__ int gswz(int r, int kbyte) {
    return (r * 64 + kbyte) ^ (((r >> 1) & 3) << 4);
}
__device__ __forceinline__ int aswz(int r, int byte) {
    return (r * 128 + byte) ^ ((r & 7) << 4);
}
#define SBAR() __builtin_amdgcn_s_barrier()
#define WAITV0() asm volatile("s_waitcnt vmcnt(0)" ::: "memory")
#define WAITV4() asm volatile("s_waitcnt vmcnt(4)" ::: "memory")
#define WAITL() asm volatile("s_waitcnt lgkmcnt(0)" ::: "memory")

// ---------- merged tconv x3: W f32 [K][N] -> bf16 tiled-swizzled [ct][kt][128x32] ----
__global__ __launch_bounds__(256) void tconv3(const float* __restrict__ Wq,
                                              const float* __restrict__ Wgt,
                                              const float* __restrict__ Wo,
                                              short* __restrict__ Wtq,
                                              short* __restrict__ Wtg,
                                              short* __restrict__ Wto) {
    __shared__ short lsm[32][136];
    int ct = blockIdx.x;
    const int kt = blockIdx.y;
    const float* W; short* Bt; int N;
    if (ct < 24)      { W = Wq;  Bt = Wtq; N = 3072; }
    else if (ct < 32) { W = Wgt; Bt = Wtg; N = 1024; ct -= 24; }
    else              { W = Wo;  Bt = Wto; N = 1024; ct -= 32; }
    const int t = threadIdx.x;
    {
        const int kk = t >> 3, nn0 = (t & 7) * 16;
        const float* src = W + (size_t)(kt * 32 + kk) * N + ct * 128 + nn0;
#pragma unroll
        for (int j = 0; j < 16; j += 4) {
            float4 v = *(const float4*)(src + j);
            lsm[kk][nn0 + j] = f2bf(v.x); lsm[kk][nn0 + j + 1] = f2bf(v.y);
            lsm[kk][nn0 + j + 2] = f2bf(v.z); lsm[kk][nn0 + j + 3] = f2bf(v.w);
        }
    }
    __syncthreads();
    const int rloc = t >> 1, kb0 = (t & 1) * 16;
    short o[16] __attribute__((aligned(16)));
#pragma unroll
    for (int j = 0; j < 16; ++j) o[j] = lsm[kb0 + j][rloc];
    char* base = (char*)(Bt + ((size_t)ct * 32 + kt) * 4096);
#pragma unroll
    for (int c = 0; c < 2; ++c)
        *(v8s*)(base + gswz(rloc, kb0 * 2 + c * 16)) = *(v8s*)&o[c * 8];
}

// ---------- bf16 MFMA GEMM on tiled inputs: C = A @ B^T, K=1024 ----------
// MODE 0: f32 row-major out. MODE 1: bf16 row-major out.
// MODE 2: fused gn-stats + silu(acc)*groupnorm(Obf16) -> bf16 tiled-swizzled (N=1024).
template<int MODE>
__global__ __launch_bounds__(256) void gemm_tt(const short* __restrict__ A,
                                               const short* __restrict__ B,
                                               void* __restrict__ C, int N,
                                               const short* __restrict__ O,
                                               const float* __restrict__ partial) {
    __shared__ short As[4096];
    __shared__ short Bs[4096];
    const int tid = threadIdx.x;
    const int w = tid >> 6, l = tid & 63;
    const int wr = w >> 1, wc = w & 1;
    const int rt = blockIdx.y, ct = blockIdx.x;
    const char* Abase = (const char*)A + ((size_t)rt * 32) * 8192;
    const char* Bbase = (const char*)B + ((size_t)ct * 32) * 8192;

    v4f acc[4][4];
#pragma unroll
    for (int i = 0; i < 4; ++i)
#pragma unroll
        for (int j = 0; j < 4; ++j) acc[i][j] = (v4f){0.f, 0.f, 0.f, 0.f};

    for (int kt = 0; kt < 32; ++kt) {
        __syncthreads();
#pragma unroll
        for (int i = 0; i < 2; ++i) {
            const int c = w * 2 + i;
            gload16(Abase + (size_t)kt * 8192 + c * 1024 + l * 16, (char*)As + c * 1024);
            gload16(Bbase + (size_t)kt * 8192 + c * 1024 + l * 16, (char*)Bs + c * 1024);
        }
        __syncthreads();
        v8s af[4], bfr[4];
#pragma unroll
        for (int i = 0; i < 4; ++i) {
            const int ra = wr * 64 + i * 16 + (l & 15);
            af[i] = *(const v8s*)((char*)As + gswz(ra, (l >> 4) * 16));
            const int rb = wc * 64 + i * 16 + (l & 15);
            bfr[i] = *(const v8s*)((char*)Bs + gswz(rb, (l >> 4) * 16));
        }
#pragma unroll
        for (int i = 0; i < 4; ++i)
#pragma unroll
            for (int j = 0; j < 4; ++j)
                acc[i][j] = __builtin_amdgcn_mfma_f32_16x16x32_bf16(af[i], bfr[j], acc[i][j], 0, 0, 0);
    }
    float mu = 0.f, rstd = 0.f;
    if (MODE == 2) {
        const int hh = ct * 2 + wc;           // head is wave-constant
        const int bh = (rt >> 3) * NH + hh;
        float s = 0.f, q = 0.f;
#pragma unroll
        for (int i = 0; i < 8; ++i) {
            s += partial[(bh * 8 + i) * 2];
            q += partial[(bh * 8 + i) * 2 + 1];
        }
        const float inv = 1.0f / (NSEQ * HD);
        mu = s * inv;
        rstd = rsqrtf(q * inv - mu * mu + 1e-5f);
    }
#pragma unroll
    for (int i = 0; i < 4; ++i)
#pragma unroll
        for (int j = 0; j < 4; ++j) {
            const int r0 = rt * 128 + wr * 64 + i * 16 + (l >> 4) * 4;
            const int cc = ct * 128 + wc * 64 + j * 16 + (l & 15);
#pragma unroll
            for (int t2 = 0; t2 < 4; ++t2) {
                if (MODE == 1) ((short*)C)[(size_t)(r0 + t2) * N + cc] = f2bf(acc[i][j][t2]);
                else if (MODE == 0) ((float*)C)[(size_t)(r0 + t2) * N + cc] = acc[i][j][t2];
                else {
                    const int row = r0 + t2;
                    const float g = acc[i][j][t2];
                    const float silu = g / (1.0f + __expf(-g));
                    const float ov = bf2f(O[(size_t)row * DM + cc]);
                    const float val = silu * (ov - mu) * rstd;
                    const int rloc = row - rt * 128;
                    char* base = (char*)((short*)C + ((size_t)rt * 32 + (cc >> 5)) * 4096);
                    *(short*)(base + gswz(rloc, (cc & 31) * 2)) = f2bf(val);
                }
            }
        }
}

// -------- gamma_conv: loggam[row,h] + X -> Xb bf16 tiled (fused, one X read) ----
__global__ __launch_bounds__(256) void gamma_conv(const float* __restrict__ X,
                                                  const float* __restrict__ Wg,
                                                  float* __restrict__ loggam,
                                                  short* __restrict__ Xb) {
    __shared__ float wgs[1024 * 17];
    const int tid = threadIdx.x;
#pragma unroll
    for (int it = 0; it < 16; ++it) {
        const int idx = it * 1024 + tid * 4;
        float4 v = *(const float4*)(Wg + idx);
        const int k = idx >> 4, h0 = idx & 15;
        wgs[k * 17 + h0]     = v.x;
        wgs[k * 17 + h0 + 1] = v.y;
        wgs[k * 17 + h0 + 2] = v.z;
        wgs[k * 17 + h0 + 3] = v.w;
    }
    __syncthreads();

    const int r = tid >> 4, c = tid & 15;
    const int row = blockIdx.x * 16 + r;
    const int rt = row >> 7, rloc = row & 127;
    char* xtile = (char*)(Xb + (size_t)rt * 32 * 4096);
    const float* xrow = X + (size_t)row * DM;
    float acc[16];
#pragma unroll
    for (int h = 0; h < 16; ++h) acc[h] = 0.0f;
#pragma unroll 4
    for (int i = 0; i < 16; ++i) {
        const int kb = i * 64 + c * 4;
        float4 xv = *(const float4*)(xrow + kb);
        // fused bf16 tile write
        short4 o4 = make_short4(f2bf(xv.x), f2bf(xv.y), f2bf(xv.z), f2bf(xv.w));
        *(short4*)(xtile + (size_t)(kb >> 5) * 8192 + gswz(rloc, (kb & 31) * 2)) = o4;
        const float xs[4] = {xv.x, xv.y, xv.z, xv.w};
#pragma unroll
        for (int j = 0; j < 4; ++j) {
            const float* wrow = &wgs[(kb + j) * 17];
#pragma unroll
            for (int h = 0; h < 16; ++h) acc[h] = fmaf(xs[j], wrow[h], acc[h]);
        }
    }
#pragma unroll
    for (int h = 0; h < 16; ++h) {
#pragma unroll
        for (int off = 8; off >= 1; off >>= 1)
            acc[h] += __shfl_xor(acc[h], off, 16);
    }
    const float d = acc[c];
    const float sig = 1.0f / (1.0f + expf(-d));
    const float gam = powf(sig, 1.0f / 20.0f);
    loggam[(size_t)row * NH + c] = logf(gam + 1e-8f);
}

// -------- parallel cumsum over n per (b,h); writes TRANSPOSED [bh][n] ----------
__global__ __launch_bounds__(256) void scan_kernel(const float* __restrict__ lg,
                                                   float* __restrict__ lgT) {
    const int wave = threadIdx.x >> 6;
    const int lane = threadIdx.x & 63;
    const int bh = blockIdx.x * 4 + wave;
    const int b = bh >> 4, h = bh & 15;
    const float* p = lg + (size_t)b * NSEQ * NH + h;
    const int n0 = lane * 16;
    float v[16];
    float s = 0.0f;
#pragma unroll
    for (int j = 0; j < 16; ++j) { v[j] = p[(size_t)(n0 + j) * NH]; s += v[j]; }
    float sc = s;
#pragma unroll
    for (int off = 1; off < 64; off <<= 1) {
        float o = __shfl_up(sc, off, 64);
        if (lane >= off) sc += o;
    }
    float acc = sc - s;
    float* q = lgT + (size_t)bh * NSEQ + n0;
#pragma unroll
    for (int j = 0; j < 16; ++j) { acc += v[j]; q[j] = acc; }
}

// ---- prep: qkvb bf16 -> RoPE'd Q(*SCALE)/K + V^T as pre-swizzled 64x64 tiles ----
__global__ __launch_bounds__(256) void prep(const short* __restrict__ qkvb,
                                            const float* __restrict__ ts,
                                            short* __restrict__ Qb,
                                            short* __restrict__ Kb,
                                            short* __restrict__ Vtb) {
    __shared__ short vsm[64][72];
    const int tile = blockIdx.x, bh = blockIdx.y;
    const int b = bh >> 4, h = bh & 15;
    const int t = threadIdx.x;
    const int rloc = t >> 2, d0 = (t & 3) * 16;
    const int row = b * NSEQ + tile * 64 + rloc;
    const short* src = qkvb + (size_t)row * 3072 + h * HD;
    const size_t tb = ((size_t)bh * 16 + tile) * 4096;

    float qa[16], ka[16];
    {
        v8s q0 = *(const v8s*)(src + d0), q1 = *(const v8s*)(src + d0 + 8);
        v8s k0 = *(const v8s*)(src + 1024 + d0), k1 = *(const v8s*)(src + 1024 + d0 + 8);
#pragma unroll
        for (int j = 0; j < 8; ++j) {
            qa[j] = bf2f(q0[j]); qa[j + 8] = bf2f(q1[j]);
            ka[j] = bf2f(k0[j]); ka[j + 8] = bf2f(k1[j]);
        }
    }
    const float tv = ts[row];
    short qo[16] __attribute__((aligned(16)));
    short ko[16] __attribute__((aligned(16)));
#pragma unroll
    for (int j = 0; j < 8; ++j) {
        const int i = (d0 >> 1) + j;
        const float inv_freq = exp2f(-0.4152410119f * (float)i);
        const float ang = tv * inv_freq;
        const float s = sinf(ang), c = cosf(ang);
        const float sv = ((float)(2 * i) + 25.6f) * (1.0f / 89.6f);
        const float e = log2f(sv) * tv * (1.0f / 512.0f);
        const float sc = exp2f(e) * SCALE, isc = exp2f(-e);
        qo[2 * j]     = f2bf((qa[2 * j] * c - qa[2 * j + 1] * s) * sc);
        qo[2 * j + 1] = f2bf((qa[2 * j + 1] * c + qa[2 * j] * s) * sc);
        ko[2 * j]     = f2bf((ka[2 * j] * c - ka[2 * j + 1] * s) * isc);
        ko[2 * j + 1] = f2bf((ka[2 * j + 1] * c + ka[2 * j] * s) * isc);
    }
#pragma unroll
    for (int c = 0; c < 2; ++c) {
        *(v8s*)((char*)(Qb + tb) + aswz(rloc, d0 * 2 + c * 16)) = *(v8s*)&qo[c * 8];
        *(v8s*)((char*)(Kb + tb) + aswz(rloc, d0 * 2 + c * 16)) = *(v8s*)&ko[c * 8];
    }
    {
        v8s v0 = *(const v8s*)(src + 2048 + d0), v1 = *(const v8s*)(src + 2048 + d0 + 8);
        *(short4*)&vsm[rloc][d0]      = *(short4*)&v0;
        *(short4*)&vsm[rloc][d0 + 4]  = *((short4*)&v0 + 1);
        *(short4*)&vsm[rloc][d0 + 8]  = *(short4*)&v1;
        *(short4*)&vsm[rloc][d0 + 12] = *((short4*)&v1 + 1);
    }
    __syncthreads();
    {
        const int d = t >> 2, m0 = (t & 3) * 16;
        short vt[16] __attribute__((aligned(16)));
#pragma unroll
        for (int j = 0; j < 16; ++j) vt[j] = vsm[m0 + j][d];
#pragma unroll
        for (int c = 0; c < 2; ++c)
            *(v8s*)((char*)(Vtb + tb) + aswz(d, m0 * 2 + c * 16)) = *(v8s*)&vt[c * 8];
    }
}

// -- attn6: attn5 + setprio(T5) + bf16 O output --
__global__ __launch_bounds__(256) void attn6(const short* __restrict__ Qb,
                                             const short* __restrict__ Kb,
                                             const short* __restrict__ Vtb,
                                             const float* __restrict__ logbT,
                                             short* __restrict__ O,
                                             float* __restrict__ partial) {
    __shared__ short Ks[2][4096];
    __shared__ short Vts[2][4096];
    __shared__ short Ps[8192];       // P tiles; also Q staging (16KB)
    __shared__ float lbAll[1024];
    __shared__ float emAll[1024];
    const int id = blockIdx.x;
    const int half = id >> 8;                            // 0 = heavy, 1 = light
    const int idx = id & 255;
    const int bh = ((idx & 7) << 3) | ((idx >> 3) & 7);  // same bh & XCD for (i, i+256)
    const int qq = half == 0 ? (4 + (idx >> 6)) : (3 - (idx >> 6));
    const int b = bh >> 4, h = bh & 15;
    const int tid = threadIdx.x;
    const int w = tid >> 6, l = tid & 63;
    const int n0 = qq * 128;
    const int NT = 2 * qq + 2;

    // stage Q tiles (16KB) into Ps; load logbT row (coalesced)
#pragma unroll
    for (int i = 0; i < 4; ++i) {
        const int c = w * 4 + i;
        gload16((const char*)Qb + ((size_t)bh * 16 + 2 * qq) * 8192 + c * 1024 + l * 16,
                (char*)Ps + c * 1024);
    }
    for (int i = tid; i < 1024; i += 256)
        lbAll[i] = logbT[(size_t)bh * NSEQ + i];
    WAITV0(); WAITL();
    SBAR();

    const float base = lbAll[n0];
    for (int i = tid; i < NT * 64; i += 256) emAll[i] = __expf(base - lbAll[i]);
    float en[2];
#pragma unroll
    for (int rg = 0; rg < 2; ++rg)
        en[rg] = __expf(lbAll[n0 + w * 32 + rg * 16 + (l & 15)] - base);
    v8s aq[2][2];
#pragma unroll
    for (int rg = 0; rg < 2; ++rg)
#pragma unroll
        for (int kc = 0; kc < 2; ++kc) {
            const int r = w * 32 + rg * 16 + (l & 15);
            aq[rg][kc] = *(const v8s*)((char*)Ps + (r >> 6) * 8192 +
                                       aswz(r & 63, kc * 64 + (l >> 4) * 16));
        }
    WAITL();
    SBAR();   // emAll visible; Ps free for P use

    v4f oacc[2][4];   // O^T: [rg][dt]
#pragma unroll
    for (int rg = 0; rg < 2; ++rg)
#pragma unroll
        for (int dt = 0; dt < 4; ++dt) oacc[rg][dt] = (v4f){0.f, 0.f, 0.f, 0.f};

    // prefetch tile 0
#pragma unroll
    for (int i = 0; i < 2; ++i) {
        const int c = w * 2 + i;
        gload16((const char*)Kb + ((size_t)bh * 16 + 0) * 8192 + c * 1024 + l * 16,
                (char*)Ks + c * 1024);
        gload16((const char*)Vtb + ((size_t)bh * 16 + 0) * 8192 + c * 1024 + l * 16,
                (char*)Vts + c * 1024);
    }

    for (int t = 0; t < NT; ++t) {
        const int m0 = t * 64;
        const int buf = t & 1;
        SBAR();   // all waves done reading buf^1
        if (t + 1 < NT) {
            const int nb = (t + 1) & 1;
#pragma unroll
            for (int i = 0; i < 2; ++i) {
                const int c = w * 2 + i;
                gload16((const char*)Kb + ((size_t)bh * 16 + t + 1) * 8192 + c * 1024 + l * 16,
                        (char*)Ks + nb * 8192 + c * 1024);
                gload16((const char*)Vtb + ((size_t)bh * 16 + t + 1) * 8192 + c * 1024 + l * 16,
                        (char*)Vts + nb * 8192 + c * 1024);
            }
            WAITV4();
        } else {
            WAITV0();
        }
        SBAR();   // tile t fully in LDS (t+1 still in flight)

        const bool active = (m0 <= n0 + w * 32 + 31);
        if (active) {
            const char* KsB = (const char*)Ks + buf * 8192;
            const char* VtsB = (const char*)Vts + buf * 8192;
            // S^T = mfma(K, Q): rows m, cols q
            v4f sfr[2][4];
#pragma unroll
            for (int rg = 0; rg < 2; ++rg)
#pragma unroll
                for (int m4 = 0; m4 < 4; ++m4) sfr[rg][m4] = (v4f){0.f, 0.f, 0.f, 0.f};
            __builtin_amdgcn_s_setprio(1);
#pragma unroll
            for (int m4 = 0; m4 < 4; ++m4) {
#pragma unroll
                for (int kc = 0; kc < 2; ++kc) {
                    const int m = m4 * 16 + (l & 15);
                    v8s bk = *(const v8s*)(KsB + aswz(m, kc * 64 + (l >> 4) * 16));
#pragma unroll
                    for (int rg = 0; rg < 2; ++rg)
                        sfr[rg][m4] = __builtin_amdgcn_mfma_f32_16x16x32_bf16(bk, aq[rg][kc], sfr[rg][m4], 0, 0, 0);
                }
            }
            __builtin_amdgcn_s_setprio(0);
            // decay (factorized) + mask + packed P store
            const bool needMask = (m0 + 63) > (n0 + w * 32);
#pragma unroll
            for (int rg = 0; rg < 2; ++rg) {
                const int r = w * 32 + rg * 16 + (l & 15);
                const float enr = en[rg];
#pragma unroll
                for (int m4 = 0; m4 < 4; ++m4) {
                    const int mbase = m0 + m4 * 16 + (l >> 4) * 4;
                    float4 emv = *(const float4*)&emAll[mbase];
                    const float ems[4] = {emv.x, emv.y, emv.z, emv.w};
                    union { short s[4]; uint2 u; } pk;
#pragma unroll
                    for (int t2 = 0; t2 < 4; ++t2) {
                        float sval = sfr[rg][m4][t2] * enr * ems[t2];
                        if (needMask && (n0 + r) < (mbase + t2)) sval = 0.0f;
                        pk.s[t2] = f2bf(sval);
                    }
                    *(uint2*)((char*)Ps + aswz(r, (m4 * 16 + (l >> 4) * 4) * 2)) = pk.u;
                }
            }
            WAITL();
            __builtin_amdgcn_sched_barrier(0);
            // O^T += mfma(V^T, P): rows d, cols q
            __builtin_amdgcn_s_setprio(1);
#pragma unroll
            for (int kc = 0; kc < 2; ++kc) {
                v8s ap[2];
#pragma unroll
                for (int rg = 0; rg < 2; ++rg) {
                    const int r = w * 32 + rg * 16 + (l & 15);
                    ap[rg] = *(const v8s*)((char*)Ps + aswz(r, kc * 64 + (l >> 4) * 16));
                }
#pragma unroll
                for (int dt = 0; dt < 4; ++dt) {
                    const int d = dt * 16 + (l & 15);
                    v8s bv = *(const v8s*)(VtsB + aswz(d, kc * 64 + (l >> 4) * 16));
#pragma unroll
                    for (int rg = 0; rg < 2; ++rg)
                        oacc[rg][dt] = __builtin_amdgcn_mfma_f32_16x16x32_bf16(bv, ap[rg], oacc[rg][dt], 0, 0, 0);
                }
            }
            __builtin_amdgcn_s_setprio(0);
        }
    }
    // epilogue: bf16 O writes (short4) + groupnorm partials from f32
    float psum = 0.0f, pssq = 0.0f;
#pragma unroll
    for (int rg = 0; rg < 2; ++rg) {
        const int row = n0 + w * 32 + rg * 16 + (l & 15);
#pragma unroll
        for (int dt = 0; dt < 4; ++dt) {
            const float a0 = oacc[rg][dt][0], a1 = oacc[rg][dt][1];
            const float a2 = oacc[rg][dt][2], a3 = oacc[rg][dt][3];
            short4 o4 = make_short4(f2bf(a0), f2bf(a1), f2bf(a2), f2bf(a3));
            *(short4*)(O + (size_t)(b * NSEQ + row) * DM + h * HD + dt * 16 + (l >> 4) * 4) = o4;
            psum += a0 + a1 + a2 + a3;
            pssq += a0 * a0 + a1 * a1 + a2 * a2 + a3 * a3;
        }
    }
    __syncthreads();
    float* red = (float*)Ks;
    red[tid] = psum; red[256 + tid] = pssq;
    __syncthreads();
    for (int s = 128; s > 0; s >>= 1) {
        if (tid < s) { red[tid] += red[tid + s]; red[256 + tid] += red[256 + tid + s]; }
        __syncthreads();
    }
    if (tid == 0) {
        partial[(bh * 8 + qq) * 2]     = red[0];
        partial[(bh * 8 + qq) * 2 + 1] = red[256];
    }
}

extern "C" void kernel_launch(void* const* d_in, const int* in_sizes, int n_in,
                              void* d_out, int out_size, void* d_ws, size_t ws_size,
                              hipStream_t stream) {
    const float* X       = (const float*)d_in[0];
    const float* ts      = (const float*)d_in[1];
    const float* W_qkv   = (const float*)d_in[2];
    const float* W_gamma = (const float*)d_in[3];
    const float* W_gated = (const float*)d_in[4];
    const float* W_out   = (const float*)d_in[5];
    float* out = (float*)d_out;

    char* ws = (char*)d_ws;
    short* qkvb = (short*)ws;                          // 12,582,912 sh (24MB)
    float* logb = (float*)(ws + 25165824);             // 65,536 f32
    short* Oatt = (short*)(ws + 25427968);             // 4,194,304 bf16 (8MB)
    short* Xb   = (short*)(ws + 42205696);             // 4,194,304 sh (tiled)
    short* Wtq  = (short*)(ws + 50594304);             // 3,145,728 sh
    short* Wtg  = (short*)(ws + 56885760);             // 1,048,576 sh
    short* Wto  = (short*)(ws + 58982912);             // 1,048,576 sh
    short* Qb   = (short*)(ws + 61080064);             // 4,194,304 sh
    short* Kb   = (short*)(ws + 69468672);             // 4,194,304 sh
    short* Vtb  = (short*)(ws + 77857280);             // 4,194,304 sh
    float* logbT = (float*)(ws + 86245888);            // 65,536 f32
    short* Gb   = Xb;                                  // alias (Xb dead after gemm#2)
    float* partial = (float*)Wtq;                      // alias (Wtq dead after gemm#1)

    tconv3<<<dim3(40, 32), 256, 0, stream>>>(W_qkv, W_gated, W_out, Wtq, Wtg, Wto);
    gamma_conv<<<256, 256, 0, stream>>>(X, W_gamma, logb, Xb);
    gemm_tt<1><<<dim3(24, 32), 256, 0, stream>>>(Xb, Wtq, qkvb, 3072, nullptr, nullptr);
    scan_kernel<<<16, 256, 0, stream>>>(logb, logbT);
    prep<<<dim3(16, 64), 256, 0, stream>>>(qkvb, ts, Qb, Kb, Vtb);
    attn6<<<512, 256, 0, stream>>>(Qb, Kb, Vtb, logbT, Oatt, partial);
    gemm_tt<2><<<dim3(8, 32), 256, 0, stream>>>(Xb, Wtg, Gb, 1024, Oatt, partial);
    gemm_tt<0><<<dim3(8, 32), 256, 0, stream>>>(Gb, Wto, out, 1024, nullptr, nullptr);
}